// Round 2
// baseline (14893.736 us; speedup 1.0000x reference)
//
#include <hip/hip_runtime.h>

// HigherOrderGINLayer — round 2: f32, workspace shrunk to 5 slots (+scores)
// with d_out reused as hidden/q/keys/combined scratch. ws_size guard added:
// if workspace is too small we launch nothing (graceful validation failure
// instead of a GPU memory fault) to diagnose the round-1 crash.

#define DO 256      // DOUT
#define PD 128      // attention projection dim

constexpr int BM = 64, BN = 64, BK = 16;

// C[N,M] = act(A[N,256] @ W[256,M] + bias) (+ add), act = relu if relu!=0.
// Safe to alias C with `add` (add read only in epilogue by the writing thread).
__global__ __launch_bounds__(256) void gemm_kernel(
    const float* __restrict__ A, const float* __restrict__ W,
    const float* __restrict__ bias, const float* __restrict__ add,
    float* __restrict__ C, int N, int M, int relu)
{
    __shared__ float As[BK][BM + 4];   // [k][m]
    __shared__ float Ws[BK][BN + 4];   // [k][n]
    const int tid = threadIdx.x;
    const int bm = blockIdx.x * BM;
    const int bn = blockIdx.y * BN;
    const int tx = tid & 15;           // col group 0..15
    const int ty = tid >> 4;           // row group 0..15

    const int ar = tid >> 2;           // A-tile row 0..63
    const int ac = (tid & 3) * 4;      // A-tile k 0,4,8,12
    const int wr = tid >> 4;           // W-tile k 0..15
    const int wc = (tid & 15) * 4;     // W-tile col 0..60

    float acc[4][4] = {};

    for (int k0 = 0; k0 < 256; k0 += BK) {
        {
            int arow = bm + ar;
            float4 v = make_float4(0.f, 0.f, 0.f, 0.f);
            if (arow < N) v = *(const float4*)&A[(size_t)arow * 256 + k0 + ac];
            As[ac + 0][ar] = v.x; As[ac + 1][ar] = v.y;
            As[ac + 2][ar] = v.z; As[ac + 3][ar] = v.w;
        }
        {
            float4 v = *(const float4*)&W[(size_t)(k0 + wr) * M + bn + wc];
            Ws[wr][wc + 0] = v.x; Ws[wr][wc + 1] = v.y;
            Ws[wr][wc + 2] = v.z; Ws[wr][wc + 3] = v.w;
        }
        __syncthreads();
        #pragma unroll
        for (int kk = 0; kk < BK; ++kk) {
            float4 a4 = *(const float4*)&As[kk][ty * 4];
            float4 w4 = *(const float4*)&Ws[kk][tx * 4];
            float av[4] = {a4.x, a4.y, a4.z, a4.w};
            float wv[4] = {w4.x, w4.y, w4.z, w4.w};
            #pragma unroll
            for (int i = 0; i < 4; ++i)
                #pragma unroll
                for (int j = 0; j < 4; ++j)
                    acc[i][j] = fmaf(av[i], wv[j], acc[i][j]);
        }
        __syncthreads();
    }

    const int col = bn + tx * 4;
    float4 b4 = *(const float4*)&bias[col];
    #pragma unroll
    for (int i = 0; i < 4; ++i) {
        int row = bm + ty * 4 + i;
        if (row >= N) continue;
        float4 c;
        c.x = acc[i][0] + b4.x; c.y = acc[i][1] + b4.y;
        c.z = acc[i][2] + b4.z; c.w = acc[i][3] + b4.w;
        if (relu) {
            c.x = fmaxf(c.x, 0.f); c.y = fmaxf(c.y, 0.f);
            c.z = fmaxf(c.z, 0.f); c.w = fmaxf(c.w, 0.f);
        }
        if (add) {
            float4 ad = *(const float4*)&add[(size_t)row * M + col];
            c.x += ad.x; c.y += ad.y; c.z += ad.z; c.w += ad.w;
        }
        *(float4*)&C[(size_t)row * M + col] = c;
    }
}

// Y[row[e]] += val[e] * X[col[e]] — one wave per edge, 4 f32 atomics/lane.
__global__ __launch_bounds__(256) void spmm_kernel(
    const int* __restrict__ rows, const int* __restrict__ cols,
    const float* __restrict__ vals, const float* __restrict__ X,
    float* __restrict__ Y, int E)
{
    int e = blockIdx.x * 4 + (threadIdx.x >> 6);
    if (e >= E) return;
    int lane = threadIdx.x & 63;
    int r = rows[e];
    int c = cols[e];
    float v = vals[e];
    float4 x = *(const float4*)&X[(size_t)c * DO + lane * 4];
    float* y = &Y[(size_t)r * DO + lane * 4];
    atomicAdd(y + 0, v * x.x);
    atomicAdd(y + 1, v * x.y);
    atomicAdd(y + 2, v * x.z);
    atomicAdd(y + 3, v * x.w);
}

// scores[n*5+kidx] = dot(q[n,:], key[n,:]) over 128 dims — one wave per node.
__global__ __launch_bounds__(256) void scores_kernel(
    const float* __restrict__ q, const float* __restrict__ key,
    float* __restrict__ scores, int N, int kidx)
{
    int n = blockIdx.x * 4 + (threadIdx.x >> 6);
    if (n >= N) return;
    int lane = threadIdx.x & 63;
    float2 qa = *(const float2*)&q[(size_t)n * PD + lane * 2];
    float2 ka = *(const float2*)&key[(size_t)n * PD + lane * 2];
    float p = qa.x * ka.x + qa.y * ka.y;
    #pragma unroll
    for (int off = 32; off > 0; off >>= 1) p += __shfl_xor(p, off, 64);
    if (lane == 0) scores[(size_t)n * 5 + kidx] = p;
}

// combined[n,:] = sum_k softmax(scores[n,:])[k] * f_k[n,:] — one wave per node.
__global__ __launch_bounds__(256) void combine_kernel(
    const float* __restrict__ f0, const float* __restrict__ f1,
    const float* __restrict__ f2, const float* __restrict__ f3,
    const float* __restrict__ f4, const float* __restrict__ scores,
    float* __restrict__ out, int N)
{
    int n = blockIdx.x * 4 + (threadIdx.x >> 6);
    if (n >= N) return;
    int lane = threadIdx.x & 63;
    float s[5];
    #pragma unroll
    for (int k = 0; k < 5; ++k) s[k] = scores[(size_t)n * 5 + k];
    float m = fmaxf(fmaxf(fmaxf(s[0], s[1]), fmaxf(s[2], s[3])), s[4]);
    float sum = 0.f;
    #pragma unroll
    for (int k = 0; k < 5; ++k) { s[k] = expf(s[k] - m); sum += s[k]; }
    float inv = 1.f / sum;
    #pragma unroll
    for (int k = 0; k < 5; ++k) s[k] *= inv;
    size_t off = (size_t)n * DO + lane * 4;
    float4 a0 = *(const float4*)&f0[off];
    float4 a1 = *(const float4*)&f1[off];
    float4 a2 = *(const float4*)&f2[off];
    float4 a3 = *(const float4*)&f3[off];
    float4 a4 = *(const float4*)&f4[off];
    float4 r;
    r.x = s[0]*a0.x + s[1]*a1.x + s[2]*a2.x + s[3]*a3.x + s[4]*a4.x;
    r.y = s[0]*a0.y + s[1]*a1.y + s[2]*a2.y + s[3]*a3.y + s[4]*a4.y;
    r.z = s[0]*a0.z + s[1]*a1.z + s[2]*a2.z + s[3]*a3.z + s[4]*a4.z;
    r.w = s[0]*a0.w + s[1]*a1.w + s[2]*a2.w + s[3]*a3.w + s[4]*a4.w;
    *(float4*)&out[off] = r;
}

extern "C" void kernel_launch(void* const* d_in, const int* in_sizes, int n_in,
                              void* d_out, int out_size, void* d_ws, size_t ws_size,
                              hipStream_t stream)
{
    const float* features      = (const float*)d_in[0];
    const float* edge_features = (const float*)d_in[1];
    const int*   adj_idx[4] = {(const int*)d_in[2], (const int*)d_in[4],
                               (const int*)d_in[6], (const int*)d_in[8]};
    const float* adj_val[4] = {(const float*)d_in[3], (const float*)d_in[5],
                               (const float*)d_in[7], (const float*)d_in[9]};
    const int E[4] = {in_sizes[3], in_sizes[5], in_sizes[7], in_sizes[9]};

    const float* ft_W = (const float*)d_in[10]; const float* ft_b = (const float*)d_in[11];
    const float* fo_W1 = (const float*)d_in[12]; const float* fo_b1 = (const float*)d_in[13];
    const float* fo_W2 = (const float*)d_in[14]; const float* fo_b2 = (const float*)d_in[15];
    const float* em_W1 = (const float*)d_in[16]; const float* em_b1 = (const float*)d_in[17];
    const float* em_W2 = (const float*)d_in[18]; const float* em_b2 = (const float*)d_in[19];
    const float* so_W1 = (const float*)d_in[20]; const float* so_b1 = (const float*)d_in[21];
    const float* so_W2 = (const float*)d_in[22]; const float* so_b2 = (const float*)d_in[23];
    const float* to_W1 = (const float*)d_in[24]; const float* to_b1 = (const float*)d_in[25];
    const float* to_W2 = (const float*)d_in[26]; const float* to_b2 = (const float*)d_in[27];
    const float* qo_W1 = (const float*)d_in[28]; const float* qo_b1 = (const float*)d_in[29];
    const float* qo_W2 = (const float*)d_in[30]; const float* qo_b2 = (const float*)d_in[31];
    const float* m_W1  = (const float*)d_in[32]; const float* m_b1  = (const float*)d_in[33];
    const float* m_W2  = (const float*)d_in[34]; const float* m_b2  = (const float*)d_in[35];
    const float* q_W   = (const float*)d_in[36]; const float* q_b   = (const float*)d_in[37];
    const float* k_W   = (const float*)d_in[38]; const float* k_b   = (const float*)d_in[39];

    const int N = in_sizes[0] / 256;
    const size_t NS = (size_t)N * DO;

    // Workspace: exactly 5 x [N,256] f32 slots + [N,5] scores.
    const size_t need = (5 * NS + 5 * (size_t)N) * sizeof(float);
    if (ws_size < need) return;   // graceful diagnostic failure, no OOB crash

    float* ws = (float*)d_ws;
    float* F  = ws + 0 * NS;   // feats (live to combine)
    float* S1 = ws + 1 * NS;   // agg1 -> fo
    float* S2 = ws + 2 * NS;   // ef -> agg2/so
    float* S3 = ws + 3 * NS;   // aggef -> agg3/to
    float* S4 = ws + 4 * NS;   // agg4/qo
    float* scores = ws + 5 * NS;           // [N,5]
    float* OUT = (float*)d_out;            // scratch: hidden / q+keys / combined
    float* qbuf = OUT;                     // [N,128]
    float* keys = OUT + (size_t)N * PD;    // [N,128]

    dim3 blk(256);
    auto gemm = [&](const float* A, const float* W, const float* b,
                    const float* add, float* C, int M_, int relu) {
        dim3 grd((N + BM - 1) / BM, M_ / BN);
        hipLaunchKernelGGL(gemm_kernel, grd, blk, 0, stream, A, W, b, add, C, N, M_, relu);
    };
    auto spmm = [&](int i, const float* X, float* Y) {
        hipMemsetAsync(Y, 0, NS * sizeof(float), stream);
        dim3 grd((E[i] + 3) / 4);
        hipLaunchKernelGGL(spmm_kernel, grd, blk, 0, stream,
                           adj_idx[i], adj_idx[i] + E[i], adj_val[i], X, Y, E[i]);
    };

    // 1. feats
    gemm(features, ft_W, ft_b, nullptr, F, DO, 0);
    // 2. ef = MLP2(edge_features, em): hidden in OUT, ef in S2
    gemm(edge_features, em_W1, em_b1, nullptr, OUT, DO, 1);
    gemm(OUT, em_W2, em_b2, nullptr, S2, DO, 0);
    // 3. agg1 = spmm(adj1, feats) -> S1;  aggef = spmm(adj1, ef) -> S3
    spmm(0, F, S1);
    spmm(0, S2, S3);
    // 4. fo = MLP2(agg1) + aggef  -> S1  (S1's agg1 dead once hidden computed)
    gemm(S1, fo_W1, fo_b1, nullptr, OUT, DO, 1);
    gemm(OUT, fo_W2, fo_b2, S3, S1, DO, 0);
    // 5. so = MLP2(agg2) + agg2 -> S2 (in-place epilogue alias, safe)
    spmm(1, F, S2);
    gemm(S2, so_W1, so_b1, nullptr, OUT, DO, 1);
    gemm(OUT, so_W2, so_b2, S2, S2, DO, 0);
    // 6. to -> S3
    spmm(2, F, S3);
    gemm(S3, to_W1, to_b1, nullptr, OUT, DO, 1);
    gemm(OUT, to_W2, to_b2, S3, S3, DO, 0);
    // 7. qo -> S4
    spmm(3, F, S4);
    gemm(S4, qo_W1, qo_b1, nullptr, OUT, DO, 1);
    gemm(OUT, qo_W2, qo_b2, S4, S4, DO, 0);

    // 8. attention: q in OUT[:N*128], keys per set in OUT[N*128:], scores in ws
    gemm(F, q_W, q_b, nullptr, qbuf, PD, 0);
    const float* fsets[5] = {F, S1, S2, S3, S4};
    dim3 ngrd((N + 3) / 4);
    for (int k = 0; k < 5; ++k) {
        gemm(fsets[k], k_W, k_b, nullptr, keys, PD, 0);
        hipLaunchKernelGGL(scores_kernel, ngrd, blk, 0, stream, qbuf, keys, scores, N, k);
    }
    // 9. combined -> OUT (q/keys dead)
    hipLaunchKernelGGL(combine_kernel, ngrd, blk, 0, stream,
                       F, S1, S2, S3, S4, scores, OUT, N);
    // 10. out = MLP2(combined, m): hidden -> S1, final -> OUT
    gemm(OUT, m_W1, m_b1, nullptr, S1, DO, 1);
    gemm(S1, m_W2, m_b2, nullptr, OUT, DO, 0);
}

// Round 3
// 2897.375 us; speedup vs baseline: 5.1404x; 5.1404x over previous
//
#include <hip/hip_runtime.h>

// HigherOrderGINLayer — round 3: atomic-free SpMM via on-device CSR build
// (count -> 1-block scan -> scatter) + row-per-wave gather/accumulate.
// Round-2 profile: 5 atomic spmm dispatches = 89% of 14.9ms (3.2GB atomic
// write traffic each). This round removes all f32 atomics from the hot path.

#define DO 256      // DOUT
#define PD 128      // attention projection dim

constexpr int BM = 64, BN = 64, BK = 16;

// ---------------- GEMM (unchanged from round 2) ----------------
__global__ __launch_bounds__(256) void gemm_kernel(
    const float* __restrict__ A, const float* __restrict__ W,
    const float* __restrict__ bias, const float* __restrict__ add,
    float* __restrict__ C, int N, int M, int relu)
{
    __shared__ float As[BK][BM + 4];
    __shared__ float Ws[BK][BN + 4];
    const int tid = threadIdx.x;
    const int bm = blockIdx.x * BM;
    const int bn = blockIdx.y * BN;
    const int tx = tid & 15;
    const int ty = tid >> 4;

    const int ar = tid >> 2;
    const int ac = (tid & 3) * 4;
    const int wr = tid >> 4;
    const int wc = (tid & 15) * 4;

    float acc[4][4] = {};

    for (int k0 = 0; k0 < 256; k0 += BK) {
        {
            int arow = bm + ar;
            float4 v = make_float4(0.f, 0.f, 0.f, 0.f);
            if (arow < N) v = *(const float4*)&A[(size_t)arow * 256 + k0 + ac];
            As[ac + 0][ar] = v.x; As[ac + 1][ar] = v.y;
            As[ac + 2][ar] = v.z; As[ac + 3][ar] = v.w;
        }
        {
            float4 v = *(const float4*)&W[(size_t)(k0 + wr) * M + bn + wc];
            Ws[wr][wc + 0] = v.x; Ws[wr][wc + 1] = v.y;
            Ws[wr][wc + 2] = v.z; Ws[wr][wc + 3] = v.w;
        }
        __syncthreads();
        #pragma unroll
        for (int kk = 0; kk < BK; ++kk) {
            float4 a4 = *(const float4*)&As[kk][ty * 4];
            float4 w4 = *(const float4*)&Ws[kk][tx * 4];
            float av[4] = {a4.x, a4.y, a4.z, a4.w};
            float wv[4] = {w4.x, w4.y, w4.z, w4.w};
            #pragma unroll
            for (int i = 0; i < 4; ++i)
                #pragma unroll
                for (int j = 0; j < 4; ++j)
                    acc[i][j] = fmaf(av[i], wv[j], acc[i][j]);
        }
        __syncthreads();
    }

    const int col = bn + tx * 4;
    float4 b4 = *(const float4*)&bias[col];
    #pragma unroll
    for (int i = 0; i < 4; ++i) {
        int row = bm + ty * 4 + i;
        if (row >= N) continue;
        float4 c;
        c.x = acc[i][0] + b4.x; c.y = acc[i][1] + b4.y;
        c.z = acc[i][2] + b4.z; c.w = acc[i][3] + b4.w;
        if (relu) {
            c.x = fmaxf(c.x, 0.f); c.y = fmaxf(c.y, 0.f);
            c.z = fmaxf(c.z, 0.f); c.w = fmaxf(c.w, 0.f);
        }
        if (add) {
            float4 ad = *(const float4*)&add[(size_t)row * M + col];
            c.x += ad.x; c.y += ad.y; c.z += ad.z; c.w += ad.w;
        }
        *(float4*)&C[(size_t)row * M + col] = c;
    }
}

// ---------------- CSR build ----------------
__global__ __launch_bounds__(256) void count_kernel(
    const int* __restrict__ rows, int* __restrict__ cnt, int E)
{
    int e = blockIdx.x * 256 + threadIdx.x;
    if (e < E) atomicAdd(&cnt[rows[e]], 1);
}

// Exclusive scan of cnt[0..N) -> off[0..N], single block of 1024 threads.
__global__ __launch_bounds__(1024) void scan_kernel(
    const int* __restrict__ cnt, int* __restrict__ off, int N)
{
    __shared__ int part[1024];
    const int t = threadIdx.x;
    const int chunk = (N + 1023) / 1024;
    const int lo = t * chunk;
    const int hi = min(lo + chunk, N);
    int s = 0;
    for (int i = lo; i < hi; ++i) s += cnt[i];
    part[t] = s;
    __syncthreads();
    // Hillis-Steele inclusive scan (read-all / barrier / write-all)
    for (int d = 1; d < 1024; d <<= 1) {
        int u = (t >= d) ? part[t - d] : 0;
        __syncthreads();
        part[t] += u;
        __syncthreads();
    }
    int running = part[t] - s;   // exclusive base for this chunk
    for (int i = lo; i < hi; ++i) { off[i] = running; running += cnt[i]; }
    if (t == 1023) off[N] = part[1023];
}

__global__ __launch_bounds__(256) void scatter_kernel(
    const int* __restrict__ rows, const int* __restrict__ cols,
    const float* __restrict__ vals, const int* __restrict__ off,
    int* __restrict__ cur, int* __restrict__ scol, float* __restrict__ sval,
    int E)
{
    int e = blockIdx.x * 256 + threadIdx.x;
    if (e >= E) return;
    int r = rows[e];
    int p = off[r] + atomicAdd(&cur[r], 1);
    scol[p] = cols[e];
    sval[p] = vals[e];
}

// ---------------- SpMM: one wave per row, register accumulate ----------------
__global__ __launch_bounds__(256) void spmm_csr_kernel(
    const int* __restrict__ off, const int* __restrict__ scol,
    const float* __restrict__ sval, const float* __restrict__ X,
    float* __restrict__ Y, int N)
{
    int r = blockIdx.x * 4 + (threadIdx.x >> 6);
    if (r >= N) return;
    int lane = threadIdx.x & 63;
    int e0 = off[r], e1 = off[r + 1];
    float4 acc = make_float4(0.f, 0.f, 0.f, 0.f);
    int e = e0;
    for (; e + 1 < e1; e += 2) {   // 2-way unroll: 2 outstanding gathers
        int   c0 = scol[e],     c1 = scol[e + 1];
        float v0 = sval[e],     v1 = sval[e + 1];
        float4 x0 = *(const float4*)&X[(size_t)c0 * DO + lane * 4];
        float4 x1 = *(const float4*)&X[(size_t)c1 * DO + lane * 4];
        acc.x = fmaf(v0, x0.x, acc.x); acc.y = fmaf(v0, x0.y, acc.y);
        acc.z = fmaf(v0, x0.z, acc.z); acc.w = fmaf(v0, x0.w, acc.w);
        acc.x = fmaf(v1, x1.x, acc.x); acc.y = fmaf(v1, x1.y, acc.y);
        acc.z = fmaf(v1, x1.z, acc.z); acc.w = fmaf(v1, x1.w, acc.w);
    }
    if (e < e1) {
        int c0 = scol[e]; float v0 = sval[e];
        float4 x0 = *(const float4*)&X[(size_t)c0 * DO + lane * 4];
        acc.x = fmaf(v0, x0.x, acc.x); acc.y = fmaf(v0, x0.y, acc.y);
        acc.z = fmaf(v0, x0.z, acc.z); acc.w = fmaf(v0, x0.w, acc.w);
    }
    *(float4*)&Y[(size_t)r * DO + lane * 4] = acc;
}

// Dual: two inputs share one edge-list walk (adj1 needs feats AND ef).
__global__ __launch_bounds__(256) void spmm_csr_dual_kernel(
    const int* __restrict__ off, const int* __restrict__ scol,
    const float* __restrict__ sval,
    const float* __restrict__ X1, const float* __restrict__ X2,
    float* __restrict__ Y1, float* __restrict__ Y2, int N)
{
    int r = blockIdx.x * 4 + (threadIdx.x >> 6);
    if (r >= N) return;
    int lane = threadIdx.x & 63;
    int e0 = off[r], e1 = off[r + 1];
    float4 a1 = make_float4(0.f, 0.f, 0.f, 0.f);
    float4 a2 = make_float4(0.f, 0.f, 0.f, 0.f);
    for (int e = e0; e < e1; ++e) {
        int c = scol[e]; float v = sval[e];
        float4 x1 = *(const float4*)&X1[(size_t)c * DO + lane * 4];
        float4 x2 = *(const float4*)&X2[(size_t)c * DO + lane * 4];
        a1.x = fmaf(v, x1.x, a1.x); a1.y = fmaf(v, x1.y, a1.y);
        a1.z = fmaf(v, x1.z, a1.z); a1.w = fmaf(v, x1.w, a1.w);
        a2.x = fmaf(v, x2.x, a2.x); a2.y = fmaf(v, x2.y, a2.y);
        a2.z = fmaf(v, x2.z, a2.z); a2.w = fmaf(v, x2.w, a2.w);
    }
    *(float4*)&Y1[(size_t)r * DO + lane * 4] = a1;
    *(float4*)&Y2[(size_t)r * DO + lane * 4] = a2;
}

// ---------------- attention (unchanged) ----------------
__global__ __launch_bounds__(256) void scores_kernel(
    const float* __restrict__ q, const float* __restrict__ key,
    float* __restrict__ scores, int N, int kidx)
{
    int n = blockIdx.x * 4 + (threadIdx.x >> 6);
    if (n >= N) return;
    int lane = threadIdx.x & 63;
    float2 qa = *(const float2*)&q[(size_t)n * PD + lane * 2];
    float2 ka = *(const float2*)&key[(size_t)n * PD + lane * 2];
    float p = qa.x * ka.x + qa.y * ka.y;
    #pragma unroll
    for (int off = 32; off > 0; off >>= 1) p += __shfl_xor(p, off, 64);
    if (lane == 0) scores[(size_t)n * 5 + kidx] = p;
}

__global__ __launch_bounds__(256) void combine_kernel(
    const float* __restrict__ f0, const float* __restrict__ f1,
    const float* __restrict__ f2, const float* __restrict__ f3,
    const float* __restrict__ f4, const float* __restrict__ scores,
    float* __restrict__ out, int N)
{
    int n = blockIdx.x * 4 + (threadIdx.x >> 6);
    if (n >= N) return;
    int lane = threadIdx.x & 63;
    float s[5];
    #pragma unroll
    for (int k = 0; k < 5; ++k) s[k] = scores[(size_t)n * 5 + k];
    float m = fmaxf(fmaxf(fmaxf(s[0], s[1]), fmaxf(s[2], s[3])), s[4]);
    float sum = 0.f;
    #pragma unroll
    for (int k = 0; k < 5; ++k) { s[k] = expf(s[k] - m); sum += s[k]; }
    float inv = 1.f / sum;
    #pragma unroll
    for (int k = 0; k < 5; ++k) s[k] *= inv;
    size_t off = (size_t)n * DO + lane * 4;
    float4 a0 = *(const float4*)&f0[off];
    float4 a1 = *(const float4*)&f1[off];
    float4 a2 = *(const float4*)&f2[off];
    float4 a3 = *(const float4*)&f3[off];
    float4 a4 = *(const float4*)&f4[off];
    float4 r;
    r.x = s[0]*a0.x + s[1]*a1.x + s[2]*a2.x + s[3]*a3.x + s[4]*a4.x;
    r.y = s[0]*a0.y + s[1]*a1.y + s[2]*a2.y + s[3]*a3.y + s[4]*a4.y;
    r.z = s[0]*a0.z + s[1]*a1.z + s[2]*a2.z + s[3]*a3.z + s[4]*a4.z;
    r.w = s[0]*a0.w + s[1]*a1.w + s[2]*a2.w + s[3]*a3.w + s[4]*a4.w;
    *(float4*)&out[off] = r;
}

extern "C" void kernel_launch(void* const* d_in, const int* in_sizes, int n_in,
                              void* d_out, int out_size, void* d_ws, size_t ws_size,
                              hipStream_t stream)
{
    const float* features      = (const float*)d_in[0];
    const float* edge_features = (const float*)d_in[1];
    const int*   adj_idx[4] = {(const int*)d_in[2], (const int*)d_in[4],
                               (const int*)d_in[6], (const int*)d_in[8]};
    const float* adj_val[4] = {(const float*)d_in[3], (const float*)d_in[5],
                               (const float*)d_in[7], (const float*)d_in[9]};
    const int E[4] = {in_sizes[3], in_sizes[5], in_sizes[7], in_sizes[9]};

    const float* ft_W = (const float*)d_in[10]; const float* ft_b = (const float*)d_in[11];
    const float* fo_W1 = (const float*)d_in[12]; const float* fo_b1 = (const float*)d_in[13];
    const float* fo_W2 = (const float*)d_in[14]; const float* fo_b2 = (const float*)d_in[15];
    const float* em_W1 = (const float*)d_in[16]; const float* em_b1 = (const float*)d_in[17];
    const float* em_W2 = (const float*)d_in[18]; const float* em_b2 = (const float*)d_in[19];
    const float* so_W1 = (const float*)d_in[20]; const float* so_b1 = (const float*)d_in[21];
    const float* so_W2 = (const float*)d_in[22]; const float* so_b2 = (const float*)d_in[23];
    const float* to_W1 = (const float*)d_in[24]; const float* to_b1 = (const float*)d_in[25];
    const float* to_W2 = (const float*)d_in[26]; const float* to_b2 = (const float*)d_in[27];
    const float* qo_W1 = (const float*)d_in[28]; const float* qo_b1 = (const float*)d_in[29];
    const float* qo_W2 = (const float*)d_in[30]; const float* qo_b2 = (const float*)d_in[31];
    const float* m_W1  = (const float*)d_in[32]; const float* m_b1  = (const float*)d_in[33];
    const float* m_W2  = (const float*)d_in[34]; const float* m_b2  = (const float*)d_in[35];
    const float* q_W   = (const float*)d_in[36]; const float* q_b   = (const float*)d_in[37];
    const float* k_W   = (const float*)d_in[38]; const float* k_b   = (const float*)d_in[39];

    const int N = in_sizes[0] / 256;
    const size_t NS = (size_t)N * DO;

    const size_t need = (5 * NS + 5 * (size_t)N) * sizeof(float);
    if (ws_size < need) return;

    float* ws = (float*)d_ws;
    float* F  = ws + 0 * NS;
    float* S1 = ws + 1 * NS;
    float* S2 = ws + 2 * NS;
    float* S3 = ws + 3 * NS;
    float* S4 = ws + 4 * NS;
    float* scores = ws + 5 * NS;
    float* OUT = (float*)d_out;
    float* qbuf = OUT;
    float* keys = OUT + (size_t)N * PD;

    // CSR scratch inside d_out (dead intervals verified against OUT's use as
    // MLP hidden): cnt/cur/off + sorted (col,val). ~7MB of OUT's 51MB.
    const int NP = (N + 64) & ~63;     // padded, >= N+1
    int*   ip   = (int*)OUT;
    int*   cnt  = ip;
    int*   cur  = ip + NP;
    int*   off  = ip + 2 * NP;         // N+1 entries
    int*   scol = ip + 3 * NP + 64;
    // sval placed after the largest E among adjacencies (they're equal here);
    // computed per-build below.

    dim3 blk(256);
    auto gemm = [&](const float* A, const float* W, const float* b,
                    const float* add, float* C, int M_, int relu) {
        dim3 grd((N + BM - 1) / BM, M_ / BN);
        hipLaunchKernelGGL(gemm_kernel, grd, blk, 0, stream, A, W, b, add, C, N, M_, relu);
    };
    auto build_csr = [&](int i) -> float* {
        int Ei = E[i];
        float* sval = (float*)(scol + Ei);
        hipMemsetAsync(cnt, 0, (size_t)N * sizeof(int), stream);
        hipMemsetAsync(cur, 0, (size_t)N * sizeof(int), stream);
        dim3 egrd((Ei + 255) / 256);
        hipLaunchKernelGGL(count_kernel, egrd, blk, 0, stream, adj_idx[i], cnt, Ei);
        hipLaunchKernelGGL(scan_kernel, dim3(1), dim3(1024), 0, stream, cnt, off, N);
        hipLaunchKernelGGL(scatter_kernel, egrd, blk, 0, stream,
                           adj_idx[i], adj_idx[i] + Ei, adj_val[i], off, cur, scol, sval, Ei);
        return sval;
    };
    dim3 rgrd((N + 3) / 4);
    auto spmm = [&](float* sval, const float* X, float* Y) {
        hipLaunchKernelGGL(spmm_csr_kernel, rgrd, blk, 0, stream, off, scol, sval, X, Y, N);
    };

    // 1. feats
    gemm(features, ft_W, ft_b, nullptr, F, DO, 0);
    // 2. ef = MLP2(edge_features, em): hidden in S3 (OUT reserved for CSR)
    gemm(edge_features, em_W1, em_b1, nullptr, S3, DO, 1);
    gemm(S3, em_W2, em_b2, nullptr, S2, DO, 0);
    // 3. adj1: agg1 -> S1, aggef -> S3 (dual pass shares edge walk)
    {
        float* sval = build_csr(0);
        hipLaunchKernelGGL(spmm_csr_dual_kernel, rgrd, blk, 0, stream,
                           off, scol, sval, F, S2, S1, S3, N);
    }
    // 4. fo = MLP2(agg1) + aggef -> S1   (hidden in S2; ef dead)
    gemm(S1, fo_W1, fo_b1, nullptr, S2, DO, 1);
    gemm(S2, fo_W2, fo_b2, S3, S1, DO, 0);
    // 5. so = MLP2(agg2) + agg2 -> S2
    { float* sval = build_csr(1); spmm(sval, F, S2); }
    gemm(S2, so_W1, so_b1, nullptr, S3, DO, 1);
    gemm(S3, so_W2, so_b2, S2, S2, DO, 0);
    // 6. to = MLP2(agg3) + agg3 -> S3
    { float* sval = build_csr(2); spmm(sval, F, S3); }
    gemm(S3, to_W1, to_b1, nullptr, S4, DO, 1);
    gemm(S4, to_W2, to_b2, S3, S3, DO, 0);
    // 7. qo = MLP2(agg4) + agg4 -> S4  (hidden in OUT — CSR dead after spmm)
    { float* sval = build_csr(3); spmm(sval, F, S4); }
    gemm(S4, qo_W1, qo_b1, nullptr, OUT, DO, 1);
    gemm(OUT, qo_W2, qo_b2, S4, S4, DO, 0);

    // 8. attention
    gemm(F, q_W, q_b, nullptr, qbuf, PD, 0);
    const float* fsets[5] = {F, S1, S2, S3, S4};
    dim3 ngrd((N + 3) / 4);
    for (int k = 0; k < 5; ++k) {
        gemm(fsets[k], k_W, k_b, nullptr, keys, PD, 0);
        hipLaunchKernelGGL(scores_kernel, ngrd, blk, 0, stream, qbuf, keys, scores, N, k);
    }
    // 9. combined -> OUT
    hipLaunchKernelGGL(combine_kernel, ngrd, blk, 0, stream,
                       F, S1, S2, S3, S4, scores, OUT, N);
    // 10. out = MLP2(combined, m)
    gemm(OUT, m_W1, m_b1, nullptr, S1, DO, 1);
    gemm(S1, m_W2, m_b2, nullptr, OUT, DO, 0);
}

// Round 6
// 2791.337 us; speedup vs baseline: 5.3357x; 1.0380x over previous
//
#include <hip/hip_runtime.h>

// HigherOrderGINLayer — round 6: exact aggregation path.
// vs round 5 (absmax 0.1797): spmm gathers split hi+lo (f32-exact aggregates),
// F/ef stored split; hidden hi-only (negligible error) and keys fused into the
// GEMM epilogue (q kept f32, scores via shfl-reduce + atomicAdd) to fit the
// proven workspace bound (~235MB < 257MB).

#define DO 256
#define PD 128

typedef unsigned short u16;
typedef __attribute__((ext_vector_type(8))) short bf16x8;
typedef __attribute__((ext_vector_type(4))) float f32x4;

static __device__ __forceinline__ u16 f2b(float f) {
    unsigned u = __float_as_uint(f);
    return (u16)((u + 0x7fffu + ((u >> 16) & 1u)) >> 16);   // RNE
}
static __device__ __forceinline__ float b2f(u16 h) {
    return __uint_as_float(((unsigned)h) << 16);
}
static __device__ __forceinline__ float b2f2(u16 h, u16 l) {
    return b2f(h) + b2f(l);
}

// ------------- weights: transpose + split  Wt[c][k] = W[k][c] --------------
struct WDesc { const float* src; u16* hi; u16* lo; int C; };
struct WPack { WDesc w[15]; };

__global__ __launch_bounds__(256) void transpose_w_kernel(WPack p) {
    WDesc d = p.w[blockIdx.y];
    int idx = blockIdx.x * 256 + threadIdx.x;
    if (idx >= d.C * 256) return;
    int c = idx >> 8, k = idx & 255;
    float v = d.src[k * d.C + c];
    u16 h = f2b(v);
    d.hi[idx] = h;
    d.lo[idx] = f2b(v - b2f(h));
}

// ------------- f32 -> split bf16 -------------------------------------------
__global__ __launch_bounds__(256) void convert_split_kernel(
    const float* __restrict__ src, u16* __restrict__ hi, u16* __restrict__ lo,
    int n4)
{
    int i = blockIdx.x * 256 + threadIdx.x;
    if (i >= n4) return;
    float4 v = *(const float4*)&src[i * 4];
    ushort4 h, l;
    h.x = f2b(v.x); l.x = f2b(v.x - b2f(h.x));
    h.y = f2b(v.y); l.y = f2b(v.y - b2f(h.y));
    h.z = f2b(v.z); l.z = f2b(v.z - b2f(h.z));
    h.w = f2b(v.w); l.w = f2b(v.w - b2f(h.w));
    *(ushort4*)&hi[i * 4] = h;
    *(ushort4*)&lo[i * 4] = l;
}

// ------------- split-precision MFMA GEMM -----------------------------------
// C = act(A[N,256] @ W + bias) (+add). Alo optional (2 vs 3 MFMA terms).
// Output modes: split (Chi+Clo) | hi-only (Chi) | f32 (Cf) |
//               fused-scores (Qf,Sc): Sc[r*5] += sum_c Qf[r,c]*key[r,c].
__global__ __launch_bounds__(256) void gemm_mfma_kernel(
    const u16* __restrict__ Ahi, const u16* __restrict__ Alo,
    const u16* __restrict__ Whi, const u16* __restrict__ Wlo,
    const float* __restrict__ bias,
    const u16* __restrict__ Adh, const u16* __restrict__ Adl,
    u16* __restrict__ Chi, u16* __restrict__ Clo, float* __restrict__ Cf,
    const float* __restrict__ Qf, float* __restrict__ Sc,
    int N, int M, int relu)
{
    const int wave = threadIdx.x >> 6, lane = threadIdx.x & 63;
    const int wprg = M >> 6;                    // waves per col-span: 4 or 2
    const int rg   = wave / wprg;
    const int wc   = (wave % wprg) << 6;
    const int rpb  = (4 / wprg) << 6;           // rows/block: 64 or 128
    const int brow = blockIdx.x * rpb + rg * 64;
    const int lrow = lane & 15;
    const int kg   = lane >> 4;                 // k-group 0..3

    f32x4 acc[4][4] = {};

    for (int ks = 0; ks < 8; ++ks) {            // K = 256, 32 per step
        bf16x8 ah[4], al[4], bh[4], bl[4];
        #pragma unroll
        for (int m = 0; m < 4; ++m) {
            int r = brow + m * 16 + lrow;
            r = r < N ? r : N - 1;              // clamp tail (write guarded)
            size_t o = (size_t)r * 256 + ks * 32 + kg * 8;
            ah[m] = *(const bf16x8*)&Ahi[o];
            if (Alo) al[m] = *(const bf16x8*)&Alo[o];
        }
        #pragma unroll
        for (int n = 0; n < 4; ++n) {
            size_t o = (size_t)(wc + n * 16 + lrow) * 256 + ks * 32 + kg * 8;
            bh[n] = *(const bf16x8*)&Whi[o];
            bl[n] = *(const bf16x8*)&Wlo[o];
        }
        #pragma unroll
        for (int m = 0; m < 4; ++m)
            #pragma unroll
            for (int n = 0; n < 4; ++n) {
                acc[m][n] = __builtin_amdgcn_mfma_f32_16x16x32_bf16(
                                ah[m], bh[n], acc[m][n], 0, 0, 0);
                acc[m][n] = __builtin_amdgcn_mfma_f32_16x16x32_bf16(
                                ah[m], bl[n], acc[m][n], 0, 0, 0);
                if (Alo)
                    acc[m][n] = __builtin_amdgcn_mfma_f32_16x16x32_bf16(
                                    al[m], bh[n], acc[m][n], 0, 0, 0);
            }
    }

    if (Qf) {
        // fused keys->scores: per row, dot f32 key fragment with q (f32).
        #pragma unroll
        for (int m = 0; m < 4; ++m) {
            #pragma unroll
            for (int j = 0; j < 4; ++j) {
                int r = brow + m * 16 + kg * 4 + j;
                float p = 0.f;
                if (r < N) {
                    #pragma unroll
                    for (int n = 0; n < 4; ++n) {
                        int c = wc + n * 16 + lrow;
                        float v = acc[m][n][j] + bias[c];
                        p += Qf[(size_t)r * PD + c] * v;
                    }
                }
                p += __shfl_xor(p, 1, 64);      // reduce over lrow group
                p += __shfl_xor(p, 2, 64);
                p += __shfl_xor(p, 4, 64);
                p += __shfl_xor(p, 8, 64);
                if (lrow == 0 && r < N) atomicAdd(&Sc[(size_t)r * 5], p);
            }
        }
        return;
    }

    // epilogue: C/D layout col = lane&15, row = (lane>>4)*4 + j
    #pragma unroll
    for (int n = 0; n < 4; ++n) {
        int c = wc + n * 16 + lrow;
        float bv = bias[c];
        #pragma unroll
        for (int m = 0; m < 4; ++m) {
            #pragma unroll
            for (int j = 0; j < 4; ++j) {
                int r = brow + m * 16 + kg * 4 + j;
                if (r >= N) continue;
                size_t o = (size_t)r * M + c;
                float v = acc[m][n][j] + bv;
                if (relu) v = fmaxf(v, 0.f);
                if (Adh) v += b2f2(Adh[o], Adl[o]);
                if (Cf) {
                    Cf[o] = v;
                } else {
                    u16 h = f2b(v);
                    Chi[o] = h;
                    if (Clo) Clo[o] = f2b(v - b2f(h));
                }
            }
        }
    }
}

// ------------- CSR build ---------------------------------------------------
__global__ __launch_bounds__(256) void count_kernel(
    const int* __restrict__ rows, int* __restrict__ cnt, int E)
{
    int e = blockIdx.x * 256 + threadIdx.x;
    if (e < E) atomicAdd(&cnt[rows[e]], 1);
}

__global__ __launch_bounds__(1024) void scan_kernel(
    const int* __restrict__ cnt, int* __restrict__ off, int N)
{
    __shared__ int part[1024];
    const int t = threadIdx.x;
    const int chunk = (N + 1023) / 1024;
    const int lo = t * chunk;
    const int hi = min(lo + chunk, N);
    int s = 0;
    for (int i = lo; i < hi; ++i) s += cnt[i];
    part[t] = s;
    __syncthreads();
    for (int d = 1; d < 1024; d <<= 1) {
        int u = (t >= d) ? part[t - d] : 0;
        __syncthreads();
        part[t] += u;
        __syncthreads();
    }
    int running = part[t] - s;
    for (int i = lo; i < hi; ++i) { off[i] = running; running += cnt[i]; }
    if (t == 1023) off[N] = part[1023];
}

__global__ __launch_bounds__(256) void scatter_kernel(
    const int* __restrict__ rows, const int* __restrict__ cols,
    const float* __restrict__ vals, const int* __restrict__ off,
    int* __restrict__ cur, int* __restrict__ scol, float* __restrict__ sval,
    int E)
{
    int e = blockIdx.x * 256 + threadIdx.x;
    if (e >= E) return;
    int r = rows[e];
    int p = off[r] + atomicAdd(&cur[r], 1);
    scol[p] = cols[e];
    sval[p] = vals[e];
}

// ------------- SpMM: gather split (f32-exact), split store -----------------
__global__ __launch_bounds__(256) void spmm_csr_kernel(
    const int* __restrict__ off, const int* __restrict__ scol,
    const float* __restrict__ sval,
    const u16* __restrict__ Xh, const u16* __restrict__ Xl,
    u16* __restrict__ Yh, u16* __restrict__ Yl, int N)
{
    int r = blockIdx.x * 4 + (threadIdx.x >> 6);
    if (r >= N) return;
    int lane = threadIdx.x & 63;
    int e0 = off[r], e1 = off[r + 1];
    float a0 = 0.f, a1 = 0.f, a2 = 0.f, a3 = 0.f;
    for (int e = e0; e < e1; ++e) {
        int c = scol[e]; float v = sval[e];
        size_t xo = (size_t)c * DO + lane * 4;
        ushort4 xh = *(const ushort4*)&Xh[xo];
        ushort4 xl = *(const ushort4*)&Xl[xo];
        a0 = fmaf(v, b2f2(xh.x, xl.x), a0); a1 = fmaf(v, b2f2(xh.y, xl.y), a1);
        a2 = fmaf(v, b2f2(xh.z, xl.z), a2); a3 = fmaf(v, b2f2(xh.w, xl.w), a3);
    }
    size_t o = (size_t)r * DO + lane * 4;
    ushort4 h, l;
    h.x = f2b(a0); l.x = f2b(a0 - b2f(h.x));
    h.y = f2b(a1); l.y = f2b(a1 - b2f(h.y));
    h.z = f2b(a2); l.z = f2b(a2 - b2f(h.z));
    h.w = f2b(a3); l.w = f2b(a3 - b2f(h.w));
    *(ushort4*)&Yh[o] = h;
    *(ushort4*)&Yl[o] = l;
}

__global__ __launch_bounds__(256) void spmm_csr_dual_kernel(
    const int* __restrict__ off, const int* __restrict__ scol,
    const float* __restrict__ sval,
    const u16* __restrict__ X1h, const u16* __restrict__ X1l,
    const u16* __restrict__ X2h, const u16* __restrict__ X2l,
    u16* __restrict__ Y1h, u16* __restrict__ Y1l,
    u16* __restrict__ Y2h, u16* __restrict__ Y2l, int N)
{
    int r = blockIdx.x * 4 + (threadIdx.x >> 6);
    if (r >= N) return;
    int lane = threadIdx.x & 63;
    int e0 = off[r], e1 = off[r + 1];
    float a0 = 0.f, a1 = 0.f, a2 = 0.f, a3 = 0.f;
    float b0 = 0.f, b1 = 0.f, b2 = 0.f, b3 = 0.f;
    for (int e = e0; e < e1; ++e) {
        int c = scol[e]; float v = sval[e];
        size_t xo = (size_t)c * DO + lane * 4;
        ushort4 x1h = *(const ushort4*)&X1h[xo];
        ushort4 x1l = *(const ushort4*)&X1l[xo];
        ushort4 x2h = *(const ushort4*)&X2h[xo];
        ushort4 x2l = *(const ushort4*)&X2l[xo];
        a0 = fmaf(v, b2f2(x1h.x, x1l.x), a0); a1 = fmaf(v, b2f2(x1h.y, x1l.y), a1);
        a2 = fmaf(v, b2f2(x1h.z, x1l.z), a2); a3 = fmaf(v, b2f2(x1h.w, x1l.w), a3);
        b0 = fmaf(v, b2f2(x2h.x, x2l.x), b0); b1 = fmaf(v, b2f2(x2h.y, x2l.y), b1);
        b2 = fmaf(v, b2f2(x2h.z, x2l.z), b2); b3 = fmaf(v, b2f2(x2h.w, x2l.w), b3);
    }
    size_t o = (size_t)r * DO + lane * 4;
    ushort4 h, l;
    h.x = f2b(a0); l.x = f2b(a0 - b2f(h.x));
    h.y = f2b(a1); l.y = f2b(a1 - b2f(h.y));
    h.z = f2b(a2); l.z = f2b(a2 - b2f(h.z));
    h.w = f2b(a3); l.w = f2b(a3 - b2f(h.w));
    *(ushort4*)&Y1h[o] = h; *(ushort4*)&Y1l[o] = l;
    h.x = f2b(b0); l.x = f2b(b0 - b2f(h.x));
    h.y = f2b(b1); l.y = f2b(b1 - b2f(h.y));
    h.z = f2b(b2); l.z = f2b(b2 - b2f(h.z));
    h.w = f2b(b3); l.w = f2b(b3 - b2f(h.w));
    *(ushort4*)&Y2h[o] = h; *(ushort4*)&Y2l[o] = l;
}

// ------------- softmax-combine (all inputs split) --------------------------
__global__ __launch_bounds__(256) void combine_kernel(
    const u16* __restrict__ f0h, const u16* __restrict__ f0l,
    const u16* __restrict__ f1h, const u16* __restrict__ f1l,
    const u16* __restrict__ f2h, const u16* __restrict__ f2l,
    const u16* __restrict__ f3h, const u16* __restrict__ f3l,
    const u16* __restrict__ f4h, const u16* __restrict__ f4l,
    const float* __restrict__ scores,
    u16* __restrict__ oh, u16* __restrict__ ol, int N)
{
    int n = blockIdx.x * 4 + (threadIdx.x >> 6);
    if (n >= N) return;
    int lane = threadIdx.x & 63;
    float s[5];
    #pragma unroll
    for (int k = 0; k < 5; ++k) s[k] = scores[(size_t)n * 5 + k];
    float m = fmaxf(fmaxf(fmaxf(s[0], s[1]), fmaxf(s[2], s[3])), s[4]);
    float sum = 0.f;
    #pragma unroll
    for (int k = 0; k < 5; ++k) { s[k] = expf(s[k] - m); sum += s[k]; }
    float inv = 1.f / sum;
    #pragma unroll
    for (int k = 0; k < 5; ++k) s[k] *= inv;
    size_t o = (size_t)n * DO + lane * 4;
    ushort4 h0 = *(const ushort4*)&f0h[o], l0 = *(const ushort4*)&f0l[o];
    ushort4 h1 = *(const ushort4*)&f1h[o], l1 = *(const ushort4*)&f1l[o];
    ushort4 h2 = *(const ushort4*)&f2h[o], l2 = *(const ushort4*)&f2l[o];
    ushort4 h3 = *(const ushort4*)&f3h[o], l3 = *(const ushort4*)&f3l[o];
    ushort4 h4 = *(const ushort4*)&f4h[o], l4 = *(const ushort4*)&f4l[o];
    float r0 = s[0]*b2f2(h0.x,l0.x) + s[1]*b2f2(h1.x,l1.x) + s[2]*b2f2(h2.x,l2.x)
             + s[3]*b2f2(h3.x,l3.x) + s[4]*b2f2(h4.x,l4.x);
    float r1 = s[0]*b2f2(h0.y,l0.y) + s[1]*b2f2(h1.y,l1.y) + s[2]*b2f2(h2.y,l2.y)
             + s[3]*b2f2(h3.y,l3.y) + s[4]*b2f2(h4.y,l4.y);
    float r2 = s[0]*b2f2(h0.z,l0.z) + s[1]*b2f2(h1.z,l1.z) + s[2]*b2f2(h2.z,l2.z)
             + s[3]*b2f2(h3.z,l3.z) + s[4]*b2f2(h4.z,l4.z);
    float r3 = s[0]*b2f2(h0.w,l0.w) + s[1]*b2f2(h1.w,l1.w) + s[2]*b2f2(h2.w,l2.w)
             + s[3]*b2f2(h3.w,l3.w) + s[4]*b2f2(h4.w,l4.w);
    ushort4 h, l;
    h.x = f2b(r0); l.x = f2b(r0 - b2f(h.x));
    h.y = f2b(r1); l.y = f2b(r1 - b2f(h.y));
    h.z = f2b(r2); l.z = f2b(r2 - b2f(h.z));
    h.w = f2b(r3); l.w = f2b(r3 - b2f(h.w));
    *(ushort4*)&oh[o] = h;
    *(ushort4*)&ol[o] = l;
}

extern "C" void kernel_launch(void* const* d_in, const int* in_sizes, int n_in,
                              void* d_out, int out_size, void* d_ws, size_t ws_size,
                              hipStream_t stream)
{
    const float* features      = (const float*)d_in[0];
    const float* edge_features = (const float*)d_in[1];
    const int*   adj_idx[4] = {(const int*)d_in[2], (const int*)d_in[4],
                               (const int*)d_in[6], (const int*)d_in[8]};
    const float* adj_val[4] = {(const float*)d_in[3], (const float*)d_in[5],
                               (const float*)d_in[7], (const float*)d_in[9]};
    const int E[4] = {in_sizes[3], in_sizes[5], in_sizes[7], in_sizes[9]};
    const int Emax = max(max(E[0], E[1]), max(E[2], E[3]));

    const float* ft_W = (const float*)d_in[10]; const float* ft_b = (const float*)d_in[11];
    const float* fo_W1 = (const float*)d_in[12]; const float* fo_b1 = (const float*)d_in[13];
    const float* fo_W2 = (const float*)d_in[14]; const float* fo_b2 = (const float*)d_in[15];
    const float* em_W1 = (const float*)d_in[16]; const float* em_b1 = (const float*)d_in[17];
    const float* em_W2 = (const float*)d_in[18]; const float* em_b2 = (const float*)d_in[19];
    const float* so_W1 = (const float*)d_in[20]; const float* so_b1 = (const float*)d_in[21];
    const float* so_W2 = (const float*)d_in[22]; const float* so_b2 = (const float*)d_in[23];
    const float* to_W1 = (const float*)d_in[24]; const float* to_b1 = (const float*)d_in[25];
    const float* to_W2 = (const float*)d_in[26]; const float* to_b2 = (const float*)d_in[27];
    const float* qo_W1 = (const float*)d_in[28]; const float* qo_b1 = (const float*)d_in[29];
    const float* qo_W2 = (const float*)d_in[30]; const float* qo_b2 = (const float*)d_in[31];
    const float* m_W1  = (const float*)d_in[32]; const float* m_b1  = (const float*)d_in[33];
    const float* m_W2  = (const float*)d_in[34]; const float* m_b2  = (const float*)d_in[35];
    const float* q_W   = (const float*)d_in[36]; const float* q_b   = (const float*)d_in[37];
    const float* k_W   = (const float*)d_in[38]; const float* k_b   = (const float*)d_in[39];

    const int N = in_sizes[0] / 256;
    const size_t NS = (size_t)N * DO;

    // ---- workspace: 9 units (1 unit = NS u16 = NS*2 B) + WT + scores ------
    char* base = (char*)d_ws;
    size_t o = 0;
    auto take = [&](size_t bytes) { char* p = base + o; o += (bytes + 63) & ~(size_t)63; return p; };
    u16* B0 = (u16*)take(NS * 2);      // 1 unit: hidden-hi / CSR / q-f32
    u16* B1 = (u16*)take(NS * 4);      // Fin split -> agg1/fo -> combined
    u16* B2 = (u16*)take(NS * 4);      // Ein split -> aggef -> agg2/so
    u16* B3 = (u16*)take(NS * 4);      // ef split -> agg3/to
    u16* B4 = (u16*)take(NS * 4);      // F split (live to combine)
    const size_t WSQ = 65536, WRC = 32768;
    u16* WTh = (u16*)take((13 * WSQ + 2 * WRC) * 2);
    u16* WTl = (u16*)take((13 * WSQ + 2 * WRC) * 2);
    float* scores = (float*)take((size_t)N * 5 * 4);
    if (o > ws_size) return;           // graceful guard

    u16 *B1h = B1, *B1l = B1 + NS;
    u16 *B2h = B2, *B2l = B2 + NS;
    u16 *B3h = B3, *B3l = B3 + NS;
    u16 *Fh  = B4, *Fl  = B4 + NS;
    u16 *OTh = (u16*)d_out, *OTl = (u16*)d_out + NS;   // agg4/qo split slot
    u16 *Hh  = B0;                     // hidden hi-only
    float* qf = (float*)B0;            // q f32 [N,128] (== 1 unit exactly)
    const int NP = (N + 64) & ~63;     // CSR zone inside B0 (time-shared)
    int* cnt  = (int*)B0;
    int* cur  = cnt + NP;
    int* off  = cnt + 2 * NP;
    int* scol = cnt + 3 * NP + 64;
    float* sval = (float*)(scol + Emax);

    u16 *wh[15], *wl[15];
    for (int i = 0; i < 13; ++i) { wh[i] = WTh + (size_t)i * WSQ; wl[i] = WTl + (size_t)i * WSQ; }
    wh[13] = WTh + 13 * WSQ; wl[13] = WTl + 13 * WSQ;
    wh[14] = wh[13] + WRC;   wl[14] = wl[13] + WRC;

    dim3 blk(256);
    {   // weights: transpose + split
        WPack p;
        const float* src[15] = {ft_W, fo_W1, fo_W2, em_W1, em_W2, so_W1, so_W2,
                                to_W1, to_W2, qo_W1, qo_W2, m_W1, m_W2, q_W, k_W};
        for (int i = 0; i < 15; ++i) {
            p.w[i].src = src[i]; p.w[i].hi = wh[i]; p.w[i].lo = wl[i];
            p.w[i].C = (i < 13) ? 256 : 128;
        }
        hipLaunchKernelGGL(transpose_w_kernel, dim3(256, 15), blk, 0, stream, p);
    }
    {   // inputs -> split bf16: features -> B1, edge_features -> B2
        int n4 = (int)(NS / 4);
        dim3 g((n4 + 255) / 256);
        hipLaunchKernelGGL(convert_split_kernel, g, blk, 0, stream, features, B1h, B1l, n4);
        hipLaunchKernelGGL(convert_split_kernel, g, blk, 0, stream, edge_features, B2h, B2l, n4);
    }

    auto gemm = [&](const u16* ah, const u16* al, int w, const float* b,
                    const u16* adh, const u16* adl,
                    u16* ch, u16* cl, float* cf, const float* Qf, float* Sc,
                    int M_, int relu) {
        int rpb = (M_ == 256) ? 64 : 128;
        dim3 grd((N + rpb - 1) / rpb);
        hipLaunchKernelGGL(gemm_mfma_kernel, grd, blk, 0, stream,
                           ah, al, wh[w], wl[w], b, adh, adl, ch, cl, cf, Qf, Sc, N, M_, relu);
    };
    auto build_csr = [&](int i) {
        int Ei = E[i];
        hipMemsetAsync(cnt, 0, (size_t)N * sizeof(int), stream);
        hipMemsetAsync(cur, 0, (size_t)N * sizeof(int), stream);
        dim3 egrd((Ei + 255) / 256);
        hipLaunchKernelGGL(count_kernel, egrd, blk, 0, stream, adj_idx[i], cnt, Ei);
        hipLaunchKernelGGL(scan_kernel, dim3(1), dim3(1024), 0, stream, cnt, off, N);
        hipLaunchKernelGGL(scatter_kernel, egrd, blk, 0, stream,
                           adj_idx[i], adj_idx[i] + Ei, adj_val[i], off, cur, scol, sval, Ei);
    };
    dim3 rgrd((N + 3) / 4);
    auto spmm = [&](const u16* xh, const u16* xl, u16* yh, u16* yl) {
        hipLaunchKernelGGL(spmm_csr_kernel, rgrd, blk, 0, stream,
                           off, scol, sval, xh, xl, yh, yl, N);
    };

    // 1. F = features @ ft_W + ft_b -> B4 split
    gemm(B1h, B1l, 0, ft_b, nullptr, nullptr, Fh, Fl, nullptr, nullptr, nullptr, DO, 0);
    // 2. ef = MLP2(edge_features) -> B3 split (hidden hi in B0)
    gemm(B2h, B2l, 3, em_b1, nullptr, nullptr, Hh, nullptr, nullptr, nullptr, nullptr, DO, 1);
    gemm(Hh, nullptr, 4, em_b2, nullptr, nullptr, B3h, B3l, nullptr, nullptr, nullptr, DO, 0);
    // 3. adj1 (CSR in B0; hidden dead): agg1 -> B1 (Fin dead), aggef -> B2 (Ein dead)
    build_csr(0);
    hipLaunchKernelGGL(spmm_csr_dual_kernel, rgrd, blk, 0, stream,
                       off, scol, sval, Fh, Fl, B3h, B3l, B1h, B1l, B2h, B2l, N);
    // 4. fo = MLP2(agg1) + aggef -> B1
    gemm(B1h, B1l, 1, fo_b1, nullptr, nullptr, Hh, nullptr, nullptr, nullptr, nullptr, DO, 1);
    gemm(Hh, nullptr, 2, fo_b2, B2h, B2l, B1h, B1l, nullptr, nullptr, nullptr, DO, 0);
    // 5. so = MLP2(agg2) + agg2 -> B2 (aggef dead)
    build_csr(1); spmm(Fh, Fl, B2h, B2l);
    gemm(B2h, B2l, 5, so_b1, nullptr, nullptr, Hh, nullptr, nullptr, nullptr, nullptr, DO, 1);
    gemm(Hh, nullptr, 6, so_b2, B2h, B2l, B2h, B2l, nullptr, nullptr, nullptr, DO, 0);
    // 6. to = MLP2(agg3) + agg3 -> B3 (ef dead)
    build_csr(2); spmm(Fh, Fl, B3h, B3l);
    gemm(B3h, B3l, 7, to_b1, nullptr, nullptr, Hh, nullptr, nullptr, nullptr, nullptr, DO, 1);
    gemm(Hh, nullptr, 8, to_b2, B3h, B3l, B3h, B3l, nullptr, nullptr, nullptr, DO, 0);
    // 7. qo = MLP2(agg4) + agg4 -> d_out slot
    build_csr(3); spmm(Fh, Fl, OTh, OTl);
    gemm(OTh, OTl, 9, qo_b1, nullptr, nullptr, Hh, nullptr, nullptr, nullptr, nullptr, DO, 1);
    gemm(Hh, nullptr, 10, qo_b2, OTh, OTl, OTh, OTl, nullptr, nullptr, nullptr, DO, 0);

    // 8. attention: q f32 -> B0 (hidden/CSR dead); fused keys->scores
    gemm(Fh, Fl, 13, q_b, nullptr, nullptr, nullptr, nullptr, qf, nullptr, nullptr, PD, 0);
    hipMemsetAsync(scores, 0, (size_t)N * 5 * sizeof(float), stream);
    const u16* fsh[5] = {Fh, B1h, B2h, B3h, OTh};
    const u16* fsl[5] = {Fl, B1l, B2l, B3l, OTl};
    for (int k = 0; k < 5; ++k)
        gemm(fsh[k], fsl[k], 14, k_b, nullptr, nullptr, nullptr, nullptr, nullptr,
             qf, scores + k, PD, 0);
    // 9. combined -> B1 (in-place over fo; per-element read-then-write)
    hipLaunchKernelGGL(combine_kernel, rgrd, blk, 0, stream,
                       Fh, Fl, B1h, B1l, B2h, B2l, B3h, B3l, OTh, OTl, scores,
                       B1h, B1l, N);
    // 10. out = MLP2(combined): hidden -> B0 (q dead), final f32 -> d_out (qo dead)
    gemm(B1h, B1l, 11, m_b1, nullptr, nullptr, Hh, nullptr, nullptr, nullptr, nullptr, DO, 1);
    gemm(Hh, nullptr, 12, m_b2, nullptr, nullptr, nullptr, nullptr, (float*)d_out,
         nullptr, nullptr, DO, 0);
}

// Round 7
// 2370.795 us; speedup vs baseline: 6.2822x; 1.1774x over previous
//
#include <hip/hip_runtime.h>

// HigherOrderGINLayer — round 7: LDS-staged fused-MLP MFMA GEMM.
// Round-6 profile: 19 zero-LDS GEMMs ~1.8ms (~95us each, 4x redundant A reads
// across waves + hidden HBM round-trips). This round: 64-row A-tile staged in
// LDS (XOR-swizzled, both-sides), MLP pairs fused (H-hi kept in LDS), same
// split-bf16 numerics as round 6 (absmax 0.0547).

#define DO 256
#define PD 128

typedef unsigned short u16;
typedef __attribute__((ext_vector_type(8))) short bf16x8;
typedef __attribute__((ext_vector_type(4))) float f32x4;

static __device__ __forceinline__ u16 f2b(float f) {
    unsigned u = __float_as_uint(f);
    return (u16)((u + 0x7fffu + ((u >> 16) & 1u)) >> 16);   // RNE
}
static __device__ __forceinline__ float b2f(u16 h) {
    return __uint_as_float(((unsigned)h) << 16);
}
static __device__ __forceinline__ float b2f2(u16 h, u16 l) {
    return b2f(h) + b2f(l);
}

// ------------- weights: transpose + split  Wt[c][k] = W[k][c] --------------
struct WDesc { const float* src; u16* hi; u16* lo; int C; };
struct WPack { WDesc w[15]; };

__global__ __launch_bounds__(256) void transpose_w_kernel(WPack p) {
    WDesc d = p.w[blockIdx.y];
    int idx = blockIdx.x * 256 + threadIdx.x;
    if (idx >= d.C * 256) return;
    int c = idx >> 8, k = idx & 255;
    float v = d.src[k * d.C + c];
    u16 h = f2b(v);
    d.hi[idx] = h;
    d.lo[idx] = f2b(v - b2f(h));
}

// ------------- f32 -> split bf16 -------------------------------------------
__global__ __launch_bounds__(256) void convert_split_kernel(
    const float* __restrict__ src, u16* __restrict__ hi, u16* __restrict__ lo,
    int n4)
{
    int i = blockIdx.x * 256 + threadIdx.x;
    if (i >= n4) return;
    float4 v = *(const float4*)&src[i * 4];
    ushort4 h, l;
    h.x = f2b(v.x); l.x = f2b(v.x - b2f(h.x));
    h.y = f2b(v.y); l.y = f2b(v.y - b2f(h.y));
    h.z = f2b(v.z); l.z = f2b(v.z - b2f(h.z));
    h.w = f2b(v.w); l.w = f2b(v.w - b2f(h.w));
    *(ushort4*)&hi[i * 4] = h;
    *(ushort4*)&lo[i * 4] = l;
}

// ------------- LDS-staged split GEMM / fused MLP ---------------------------
// Block: 256 thr = 4 waves, 64 rows of A. M = NF*64? no: M = NF*16*4 waves.
// NF=4 -> M=256 (wave w: cols w*64); NF=2 -> M=128 (wave w: cols w*32).
// A (hi+lo) staged in 64KB LDS, XOR-swizzled (byte ^= (row&7)<<4).
// GEMM1: 3-term split MFMA. FUSED: relu(acc+b1) -> H(hi) in LDS -> GEMM2
// 2-term + b2 (+split add) -> split or f32 out. SCORE: dot with Qf -> Sc.
template<int NF, bool FUSED, bool SCORE>
__global__ __launch_bounds__(256) void gemm_tile_kernel(
    const u16* __restrict__ Ahi, const u16* __restrict__ Alo,
    const u16* __restrict__ W1h, const u16* __restrict__ W1l,
    const float* __restrict__ b1,
    const u16* __restrict__ W2h, const u16* __restrict__ W2l,
    const float* __restrict__ b2,
    const u16* __restrict__ Adh, const u16* __restrict__ Adl,
    u16* __restrict__ Chi, u16* __restrict__ Clo, float* __restrict__ Cf,
    const float* __restrict__ Qf, float* __restrict__ Sc,
    int N)
{
    constexpr int M = NF * 64;
    __shared__ char smem[65536];          // [0,32K) A-hi / H ; [32K,64K) A-lo

    const int tid  = threadIdx.x;
    const int wave = tid >> 6, lane = tid & 63;
    const int lrow = lane & 15, kg = lane >> 4;
    const int wc   = wave * (NF * 16);
    const int brow = blockIdx.x * 64;

    // ---- stage A tile (64 rows x 256 k, hi+lo) into LDS, swizzled ----
    #pragma unroll
    for (int j = 0; j < 8; ++j) {
        int i = tid + j * 256;            // chunk 0..2047 (16B each)
        int row = i >> 5, slot = i & 31;
        int srow = brow + row; srow = srow < N ? srow : N - 1;
        size_t go = (size_t)srow * 256 + slot * 8;
        bf16x8 vh = *(const bf16x8*)&Ahi[go];
        bf16x8 vl = *(const bf16x8*)&Alo[go];
        int db = (row * 512 + slot * 16) ^ ((row & 7) << 4);
        *(bf16x8*)(smem + db) = vh;
        *(bf16x8*)(smem + 32768 + db) = vl;
    }
    __syncthreads();

    // ---- GEMM1: 3-term split ----
    f32x4 acc[4][NF] = {};
    #pragma unroll
    for (int ks = 0; ks < 8; ++ks) {
        bf16x8 ah[4], al[4], bh[NF], bl[NF];
        #pragma unroll
        for (int m = 0; m < 4; ++m) {
            int arow = m * 16 + lrow;
            int ab = (arow * 512 + (ks * 4 + kg) * 16) ^ ((lrow & 7) << 4);
            ah[m] = *(const bf16x8*)(smem + ab);
            al[m] = *(const bf16x8*)(smem + 32768 + ab);
        }
        #pragma unroll
        for (int n = 0; n < NF; ++n) {
            size_t o = (size_t)(wc + n * 16 + lrow) * 256 + ks * 32 + kg * 8;
            bh[n] = *(const bf16x8*)&W1h[o];
            bl[n] = *(const bf16x8*)&W1l[o];
        }
        #pragma unroll
        for (int m = 0; m < 4; ++m)
            #pragma unroll
            for (int n = 0; n < NF; ++n) {
                acc[m][n] = __builtin_amdgcn_mfma_f32_16x16x32_bf16(
                                ah[m], bh[n], acc[m][n], 0, 0, 0);
                acc[m][n] = __builtin_amdgcn_mfma_f32_16x16x32_bf16(
                                ah[m], bl[n], acc[m][n], 0, 0, 0);
                acc[m][n] = __builtin_amdgcn_mfma_f32_16x16x32_bf16(
                                al[m], bh[n], acc[m][n], 0, 0, 0);
            }
    }

    if (SCORE) {
        // fused keys->scores: p = sum_c q[r,c] * (acc+b1)[r,c]
        #pragma unroll
        for (int m = 0; m < 4; ++m) {
            #pragma unroll
            for (int j = 0; j < 4; ++j) {
                int r = brow + m * 16 + kg * 4 + j;
                float p = 0.f;
                if (r < N) {
                    #pragma unroll
                    for (int n = 0; n < NF; ++n) {
                        int c = wc + n * 16 + lrow;
                        p += Qf[(size_t)r * M + c] * (acc[m][n][j] + b1[c]);
                    }
                }
                p += __shfl_xor(p, 1, 64);
                p += __shfl_xor(p, 2, 64);
                p += __shfl_xor(p, 4, 64);
                p += __shfl_xor(p, 8, 64);
                if (lrow == 0 && r < N) atomicAdd(&Sc[(size_t)r * 5], p);
            }
        }
        return;
    }

    if (!FUSED) {
        // single GEMM epilogue: v = acc + b1 -> split or f32 (no relu/add)
        #pragma unroll
        for (int n = 0; n < NF; ++n) {
            int c = wc + n * 16 + lrow;
            float bv = b1[c];
            #pragma unroll
            for (int m = 0; m < 4; ++m)
                #pragma unroll
                for (int j = 0; j < 4; ++j) {
                    int r = brow + m * 16 + kg * 4 + j;
                    if (r >= N) continue;
                    size_t o = (size_t)r * M + c;
                    float v = acc[m][n][j] + bv;
                    if (Cf) Cf[o] = v;
                    else {
                        u16 h = f2b(v);
                        Chi[o] = h;
                        Clo[o] = f2b(v - b2f(h));
                    }
                }
        }
        return;
    }

    // ---- fused: H = relu(acc + b1) -> LDS (hi region, swizzled) ----
    __syncthreads();                      // all A reads done
    #pragma unroll
    for (int n = 0; n < NF; ++n) {
        int c = wc + n * 16 + lrow;
        float bv = b1[c];
        #pragma unroll
        for (int m = 0; m < 4; ++m)
            #pragma unroll
            for (int j = 0; j < 4; ++j) {
                int rl = m * 16 + kg * 4 + j;
                float v = fmaxf(acc[m][n][j] + bv, 0.f);
                int hb = (rl * 512 + c * 2) ^ ((rl & 7) << 4);
                *(u16*)(smem + hb) = f2b(v);
            }
    }
    __syncthreads();

    // ---- GEMM2: 2-term (H hi-only, same numerics as round 6) ----
    #pragma unroll
    for (int m = 0; m < 4; ++m)
        #pragma unroll
        for (int n = 0; n < NF; ++n)
            acc[m][n] = f32x4{0.f, 0.f, 0.f, 0.f};
    #pragma unroll
    for (int ks = 0; ks < 8; ++ks) {
        bf16x8 ah[4], bh[NF], bl[NF];
        #pragma unroll
        for (int m = 0; m < 4; ++m) {
            int arow = m * 16 + lrow;
            int ab = (arow * 512 + (ks * 4 + kg) * 16) ^ ((lrow & 7) << 4);
            ah[m] = *(const bf16x8*)(smem + ab);
        }
        #pragma unroll
        for (int n = 0; n < NF; ++n) {
            size_t o = (size_t)(wc + n * 16 + lrow) * 256 + ks * 32 + kg * 8;
            bh[n] = *(const bf16x8*)&W2h[o];
            bl[n] = *(const bf16x8*)&W2l[o];
        }
        #pragma unroll
        for (int m = 0; m < 4; ++m)
            #pragma unroll
            for (int n = 0; n < NF; ++n) {
                acc[m][n] = __builtin_amdgcn_mfma_f32_16x16x32_bf16(
                                ah[m], bh[n], acc[m][n], 0, 0, 0);
                acc[m][n] = __builtin_amdgcn_mfma_f32_16x16x32_bf16(
                                ah[m], bl[n], acc[m][n], 0, 0, 0);
            }
    }

    #pragma unroll
    for (int n = 0; n < NF; ++n) {
        int c = wc + n * 16 + lrow;
        float bv = b2[c];
        #pragma unroll
        for (int m = 0; m < 4; ++m)
            #pragma unroll
            for (int j = 0; j < 4; ++j) {
                int r = brow + m * 16 + kg * 4 + j;
                if (r >= N) continue;
                size_t o = (size_t)r * M + c;
                float v = acc[m][n][j] + bv;
                if (Adh) v += b2f2(Adh[o], Adl[o]);
                if (Cf) Cf[o] = v;
                else {
                    u16 h = f2b(v);
                    Chi[o] = h;
                    Clo[o] = f2b(v - b2f(h));
                }
            }
    }
}

// ------------- CSR build ---------------------------------------------------
__global__ __launch_bounds__(256) void count_kernel(
    const int* __restrict__ rows, int* __restrict__ cnt, int E)
{
    int e = blockIdx.x * 256 + threadIdx.x;
    if (e < E) atomicAdd(&cnt[rows[e]], 1);
}

__global__ __launch_bounds__(1024) void scan_kernel(
    const int* __restrict__ cnt, int* __restrict__ off, int N)
{
    __shared__ int part[1024];
    const int t = threadIdx.x;
    const int chunk = (N + 1023) / 1024;
    const int lo = t * chunk;
    const int hi = min(lo + chunk, N);
    int s = 0;
    for (int i = lo; i < hi; ++i) s += cnt[i];
    part[t] = s;
    __syncthreads();
    for (int d = 1; d < 1024; d <<= 1) {
        int u = (t >= d) ? part[t - d] : 0;
        __syncthreads();
        part[t] += u;
        __syncthreads();
    }
    int running = part[t] - s;
    for (int i = lo; i < hi; ++i) { off[i] = running; running += cnt[i]; }
    if (t == 1023) off[N] = part[1023];
}

__global__ __launch_bounds__(256) void scatter_kernel(
    const int* __restrict__ rows, const int* __restrict__ cols,
    const float* __restrict__ vals, const int* __restrict__ off,
    int* __restrict__ cur, int* __restrict__ scol, float* __restrict__ sval,
    int E)
{
    int e = blockIdx.x * 256 + threadIdx.x;
    if (e >= E) return;
    int r = rows[e];
    int p = off[r] + atomicAdd(&cur[r], 1);
    scol[p] = cols[e];
    sval[p] = vals[e];
}

// ------------- SpMM: gather split (f32-exact), split store -----------------
__global__ __launch_bounds__(256) void spmm_csr_kernel(
    const int* __restrict__ off, const int* __restrict__ scol,
    const float* __restrict__ sval,
    const u16* __restrict__ Xh, const u16* __restrict__ Xl,
    u16* __restrict__ Yh, u16* __restrict__ Yl, int N)
{
    int r = blockIdx.x * 4 + (threadIdx.x >> 6);
    if (r >= N) return;
    int lane = threadIdx.x & 63;
    int e0 = off[r], e1 = off[r + 1];
    float a0 = 0.f, a1 = 0.f, a2 = 0.f, a3 = 0.f;
    for (int e = e0; e < e1; ++e) {
        int c = scol[e]; float v = sval[e];
        size_t xo = (size_t)c * DO + lane * 4;
        ushort4 xh = *(const ushort4*)&Xh[xo];
        ushort4 xl = *(const ushort4*)&Xl[xo];
        a0 = fmaf(v, b2f2(xh.x, xl.x), a0); a1 = fmaf(v, b2f2(xh.y, xl.y), a1);
        a2 = fmaf(v, b2f2(xh.z, xl.z), a2); a3 = fmaf(v, b2f2(xh.w, xl.w), a3);
    }
    size_t o = (size_t)r * DO + lane * 4;
    ushort4 h, l;
    h.x = f2b(a0); l.x = f2b(a0 - b2f(h.x));
    h.y = f2b(a1); l.y = f2b(a1 - b2f(h.y));
    h.z = f2b(a2); l.z = f2b(a2 - b2f(h.z));
    h.w = f2b(a3); l.w = f2b(a3 - b2f(h.w));
    *(ushort4*)&Yh[o] = h;
    *(ushort4*)&Yl[o] = l;
}

__global__ __launch_bounds__(256) void spmm_csr_dual_kernel(
    const int* __restrict__ off, const int* __restrict__ scol,
    const float* __restrict__ sval,
    const u16* __restrict__ X1h, const u16* __restrict__ X1l,
    const u16* __restrict__ X2h, const u16* __restrict__ X2l,
    u16* __restrict__ Y1h, u16* __restrict__ Y1l,
    u16* __restrict__ Y2h, u16* __restrict__ Y2l, int N)
{
    int r = blockIdx.x * 4 + (threadIdx.x >> 6);
    if (r >= N) return;
    int lane = threadIdx.x & 63;
    int e0 = off[r], e1 = off[r + 1];
    float a0 = 0.f, a1 = 0.f, a2 = 0.f, a3 = 0.f;
    float b0 = 0.f, b1 = 0.f, b2 = 0.f, b3 = 0.f;
    for (int e = e0; e < e1; ++e) {
        int c = scol[e]; float v = sval[e];
        size_t xo = (size_t)c * DO + lane * 4;
        ushort4 x1h = *(const ushort4*)&X1h[xo];
        ushort4 x1l = *(const ushort4*)&X1l[xo];
        ushort4 x2h = *(const ushort4*)&X2h[xo];
        ushort4 x2l = *(const ushort4*)&X2l[xo];
        a0 = fmaf(v, b2f2(x1h.x, x1l.x), a0); a1 = fmaf(v, b2f2(x1h.y, x1l.y), a1);
        a2 = fmaf(v, b2f2(x1h.z, x1l.z), a2); a3 = fmaf(v, b2f2(x1h.w, x1l.w), a3);
        b0 = fmaf(v, b2f2(x2h.x, x2l.x), b0); b1 = fmaf(v, b2f2(x2h.y, x2l.y), b1);
        b2 = fmaf(v, b2f2(x2h.z, x2l.z), b2); b3 = fmaf(v, b2f2(x2h.w, x2l.w), b3);
    }
    size_t o = (size_t)r * DO + lane * 4;
    ushort4 h, l;
    h.x = f2b(a0); l.x = f2b(a0 - b2f(h.x));
    h.y = f2b(a1); l.y = f2b(a1 - b2f(h.y));
    h.z = f2b(a2); l.z = f2b(a2 - b2f(h.z));
    h.w = f2b(a3); l.w = f2b(a3 - b2f(h.w));
    *(ushort4*)&Y1h[o] = h; *(ushort4*)&Y1l[o] = l;
    h.x = f2b(b0); l.x = f2b(b0 - b2f(h.x));
    h.y = f2b(b1); l.y = f2b(b1 - b2f(h.y));
    h.z = f2b(b2); l.z = f2b(b2 - b2f(h.z));
    h.w = f2b(b3); l.w = f2b(b3 - b2f(h.w));
    *(ushort4*)&Y2h[o] = h; *(ushort4*)&Y2l[o] = l;
}

// ------------- softmax-combine (all inputs split) --------------------------
__global__ __launch_bounds__(256) void combine_kernel(
    const u16* __restrict__ f0h, const u16* __restrict__ f0l,
    const u16* __restrict__ f1h, const u16* __restrict__ f1l,
    const u16* __restrict__ f2h, const u16* __restrict__ f2l,
    const u16* __restrict__ f3h, const u16* __restrict__ f3l,
    const u16* __restrict__ f4h, const u16* __restrict__ f4l,
    const float* __restrict__ scores,
    u16* __restrict__ oh, u16* __restrict__ ol, int N)
{
    int n = blockIdx.x * 4 + (threadIdx.x >> 6);
    if (n >= N) return;
    int lane = threadIdx.x & 63;
    float s[5];
    #pragma unroll
    for (int k = 0; k < 5; ++k) s[k] = scores[(size_t)n * 5 + k];
    float m = fmaxf(fmaxf(fmaxf(s[0], s[1]), fmaxf(s[2], s[3])), s[4]);
    float sum = 0.f;
    #pragma unroll
    for (int k = 0; k < 5; ++k) { s[k] = expf(s[k] - m); sum += s[k]; }
    float inv = 1.f / sum;
    #pragma unroll
    for (int k = 0; k < 5; ++k) s[k] *= inv;
    size_t o = (size_t)n * DO + lane * 4;
    ushort4 h0 = *(const ushort4*)&f0h[o], l0 = *(const ushort4*)&f0l[o];
    ushort4 h1 = *(const ushort4*)&f1h[o], l1 = *(const ushort4*)&f1l[o];
    ushort4 h2 = *(const ushort4*)&f2h[o], l2 = *(const ushort4*)&f2l[o];
    ushort4 h3 = *(const ushort4*)&f3h[o], l3 = *(const ushort4*)&f3l[o];
    ushort4 h4 = *(const ushort4*)&f4h[o], l4 = *(const ushort4*)&f4l[o];
    float r0 = s[0]*b2f2(h0.x,l0.x) + s[1]*b2f2(h1.x,l1.x) + s[2]*b2f2(h2.x,l2.x)
             + s[3]*b2f2(h3.x,l3.x) + s[4]*b2f2(h4.x,l4.x);
    float r1 = s[0]*b2f2(h0.y,l0.y) + s[1]*b2f2(h1.y,l1.y) + s[2]*b2f2(h2.y,l2.y)
             + s[3]*b2f2(h3.y,l3.y) + s[4]*b2f2(h4.y,l4.y);
    float r2 = s[0]*b2f2(h0.z,l0.z) + s[1]*b2f2(h1.z,l1.z) + s[2]*b2f2(h2.z,l2.z)
             + s[3]*b2f2(h3.z,l3.z) + s[4]*b2f2(h4.z,l4.z);
    float r3 = s[0]*b2f2(h0.w,l0.w) + s[1]*b2f2(h1.w,l1.w) + s[2]*b2f2(h2.w,l2.w)
             + s[3]*b2f2(h3.w,l3.w) + s[4]*b2f2(h4.w,l4.w);
    ushort4 h, l;
    h.x = f2b(r0); l.x = f2b(r0 - b2f(h.x));
    h.y = f2b(r1); l.y = f2b(r1 - b2f(h.y));
    h.z = f2b(r2); l.z = f2b(r2 - b2f(h.z));
    h.w = f2b(r3); l.w = f2b(r3 - b2f(h.w));
    *(ushort4*)&oh[o] = h;
    *(ushort4*)&ol[o] = l;
}

extern "C" void kernel_launch(void* const* d_in, const int* in_sizes, int n_in,
                              void* d_out, int out_size, void* d_ws, size_t ws_size,
                              hipStream_t stream)
{
    const float* features      = (const float*)d_in[0];
    const float* edge_features = (const float*)d_in[1];
    const int*   adj_idx[4] = {(const int*)d_in[2], (const int*)d_in[4],
                               (const int*)d_in[6], (const int*)d_in[8]};
    const float* adj_val[4] = {(const float*)d_in[3], (const float*)d_in[5],
                               (const float*)d_in[7], (const float*)d_in[9]};
    const int E[4] = {in_sizes[3], in_sizes[5], in_sizes[7], in_sizes[9]};
    const int Emax = max(max(E[0], E[1]), max(E[2], E[3]));

    const float* ft_W = (const float*)d_in[10]; const float* ft_b = (const float*)d_in[11];
    const float* fo_W1 = (const float*)d_in[12]; const float* fo_b1 = (const float*)d_in[13];
    const float* fo_W2 = (const float*)d_in[14]; const float* fo_b2 = (const float*)d_in[15];
    const float* em_W1 = (const float*)d_in[16]; const float* em_b1 = (const float*)d_in[17];
    const float* em_W2 = (const float*)d_in[18]; const float* em_b2 = (const float*)d_in[19];
    const float* so_W1 = (const float*)d_in[20]; const float* so_b1 = (const float*)d_in[21];
    const float* so_W2 = (const float*)d_in[22]; const float* so_b2 = (const float*)d_in[23];
    const float* to_W1 = (const float*)d_in[24]; const float* to_b1 = (const float*)d_in[25];
    const float* to_W2 = (const float*)d_in[26]; const float* to_b2 = (const float*)d_in[27];
    const float* qo_W1 = (const float*)d_in[28]; const float* qo_b1 = (const float*)d_in[29];
    const float* qo_W2 = (const float*)d_in[30]; const float* qo_b2 = (const float*)d_in[31];
    const float* m_W1  = (const float*)d_in[32]; const float* m_b1  = (const float*)d_in[33];
    const float* m_W2  = (const float*)d_in[34]; const float* m_b2  = (const float*)d_in[35];
    const float* q_W   = (const float*)d_in[36]; const float* q_b   = (const float*)d_in[37];
    const float* k_W   = (const float*)d_in[38]; const float* k_b   = (const float*)d_in[39];

    const int N = in_sizes[0] / 256;
    const size_t NS = (size_t)N * DO;

    // ---- workspace (same layout as round 6, proven) ----
    char* base = (char*)d_ws;
    size_t o = 0;
    auto take = [&](size_t bytes) { char* p = base + o; o += (bytes + 63) & ~(size_t)63; return p; };
    u16* B0 = (u16*)take(NS * 2);      // CSR zone / q-f32 (time-shared)
    u16* B1 = (u16*)take(NS * 4);      // Fin -> agg1/fo -> combined
    u16* B2 = (u16*)take(NS * 4);      // Ein -> aggef -> agg2/so
    u16* B3 = (u16*)take(NS * 4);      // ef -> agg3/to
    u16* B4 = (u16*)take(NS * 4);      // F split (live to combine)
    const size_t WSQ = 65536, WRC = 32768;
    u16* WTh = (u16*)take((13 * WSQ + 2 * WRC) * 2);
    u16* WTl = (u16*)take((13 * WSQ + 2 * WRC) * 2);
    float* scores = (float*)take((size_t)N * 5 * 4);
    if (o > ws_size) return;           // graceful guard

    u16 *B1h = B1, *B1l = B1 + NS;
    u16 *B2h = B2, *B2l = B2 + NS;
    u16 *B3h = B3, *B3l = B3 + NS;
    u16 *Fh  = B4, *Fl  = B4 + NS;
    u16 *OTh = (u16*)d_out, *OTl = (u16*)d_out + NS;   // agg4/qo split slot
    float* qf = (float*)B0;            // q f32 [N,128]
    const int NP = (N + 64) & ~63;     // CSR zone inside B0 (time-shared)
    int* cnt  = (int*)B0;
    int* cur  = cnt + NP;
    int* off  = cnt + 2 * NP;
    int* scol = cnt + 3 * NP + 64;
    float* sval = (float*)(scol + Emax);

    u16 *wh[15], *wl[15];
    for (int i = 0; i < 13; ++i) { wh[i] = WTh + (size_t)i * WSQ; wl[i] = WTl + (size_t)i * WSQ; }
    wh[13] = WTh + 13 * WSQ; wl[13] = WTl + 13 * WSQ;
    wh[14] = wh[13] + WRC;   wl[14] = wl[13] + WRC;

    dim3 blk(256);
    {   // weights: transpose + split
        WPack p;
        const float* src[15] = {ft_W, fo_W1, fo_W2, em_W1, em_W2, so_W1, so_W2,
                                to_W1, to_W2, qo_W1, qo_W2, m_W1, m_W2, q_W, k_W};
        for (int i = 0; i < 15; ++i) {
            p.w[i].src = src[i]; p.w[i].hi = wh[i]; p.w[i].lo = wl[i];
            p.w[i].C = (i < 13) ? 256 : 128;
        }
        hipLaunchKernelGGL(transpose_w_kernel, dim3(256, 15), blk, 0, stream, p);
    }
    {   // inputs -> split bf16
        int n4 = (int)(NS / 4);
        dim3 g((n4 + 255) / 256);
        hipLaunchKernelGGL(convert_split_kernel, g, blk, 0, stream, features, B1h, B1l, n4);
        hipLaunchKernelGGL(convert_split_kernel, g, blk, 0, stream, edge_features, B2h, B2l, n4);
    }

    dim3 ggrd((N + 63) / 64);
    // fused MLP: A split -> W1/b1 -> relu -> W2/b2 (+add) -> split out
    auto mlp = [&](const u16* ah, const u16* al, int w1, const float* bb1,
                   int w2, const float* bb2, const u16* adh, const u16* adl,
                   u16* ch, u16* cl, float* cf) {
        hipLaunchKernelGGL((gemm_tile_kernel<4, true, false>), ggrd, blk, 0, stream,
                           ah, al, wh[w1], wl[w1], bb1, wh[w2], wl[w2], bb2,
                           adh, adl, ch, cl, cf, nullptr, nullptr, N);
    };
    auto build_csr = [&](int i) {
        int Ei = E[i];
        hipMemsetAsync(cnt, 0, (size_t)N * sizeof(int), stream);
        hipMemsetAsync(cur, 0, (size_t)N * sizeof(int), stream);
        dim3 egrd((Ei + 255) / 256);
        hipLaunchKernelGGL(count_kernel, egrd, blk, 0, stream, adj_idx[i], cnt, Ei);
        hipLaunchKernelGGL(scan_kernel, dim3(1), dim3(1024), 0, stream, cnt, off, N);
        hipLaunchKernelGGL(scatter_kernel, egrd, blk, 0, stream,
                           adj_idx[i], adj_idx[i] + Ei, adj_val[i], off, cur, scol, sval, Ei);
    };
    dim3 rgrd((N + 3) / 4);
    auto spmm = [&](const u16* xh, const u16* xl, u16* yh, u16* yl) {
        hipLaunchKernelGGL(spmm_csr_kernel, rgrd, blk, 0, stream,
                           off, scol, sval, xh, xl, yh, yl, N);
    };

    // 1. F = features @ ft_W + ft_b -> B4 split   (single GEMM)
    hipLaunchKernelGGL((gemm_tile_kernel<4, false, false>), ggrd, blk, 0, stream,
                       B1h, B1l, wh[0], wl[0], ft_b, nullptr, nullptr, nullptr,
                       nullptr, nullptr, Fh, Fl, nullptr, nullptr, nullptr, N);
    // 2. ef = MLP2(edge_features, em) -> B3 split
    mlp(B2h, B2l, 3, em_b1, 4, em_b2, nullptr, nullptr, B3h, B3l, nullptr);
    // 3. adj1: agg1 -> B1 (Fin dead), aggef -> B2 (Ein dead)
    build_csr(0);
    hipLaunchKernelGGL(spmm_csr_dual_kernel, rgrd, blk, 0, stream,
                       off, scol, sval, Fh, Fl, B3h, B3l, B1h, B1l, B2h, B2l, N);
    // 4. fo = MLP2(agg1) + aggef -> B1
    mlp(B1h, B1l, 1, fo_b1, 2, fo_b2, B2h, B2l, B1h, B1l, nullptr);
    // 5. so = MLP2(agg2) + agg2 -> B2 (aggef dead)
    build_csr(1); spmm(Fh, Fl, B2h, B2l);
    mlp(B2h, B2l, 5, so_b1, 6, so_b2, B2h, B2l, B2h, B2l, nullptr);
    // 6. to = MLP2(agg3) + agg3 -> B3 (ef dead)
    build_csr(2); spmm(Fh, Fl, B3h, B3l);
    mlp(B3h, B3l, 7, to_b1, 8, to_b2, B3h, B3l, B3h, B3l, nullptr);
    // 7. qo = MLP2(agg4) + agg4 -> d_out slot
    build_csr(3); spmm(Fh, Fl, OTh, OTl);
    mlp(OTh, OTl, 9, qo_b1, 10, qo_b2, OTh, OTl, OTh, OTl, nullptr);

    // 8. attention: q f32 -> B0 (CSR dead); fused keys->scores
    hipLaunchKernelGGL((gemm_tile_kernel<2, false, false>), ggrd, blk, 0, stream,
                       Fh, Fl, wh[13], wl[13], q_b, nullptr, nullptr, nullptr,
                       nullptr, nullptr, nullptr, nullptr, qf, nullptr, nullptr, N);
    hipMemsetAsync(scores, 0, (size_t)N * 5 * sizeof(float), stream);
    const u16* fsh[5] = {Fh, B1h, B2h, B3h, OTh};
    const u16* fsl[5] = {Fl, B1l, B2l, B3l, OTl};
    for (int k = 0; k < 5; ++k)
        hipLaunchKernelGGL((gemm_tile_kernel<2, false, true>), ggrd, blk, 0, stream,
                           fsh[k], fsl[k], wh[14], wl[14], k_b, nullptr, nullptr, nullptr,
                           nullptr, nullptr, nullptr, nullptr, nullptr, qf, scores + k, N);
    // 9. combined -> B1 (in-place over fo)
    hipLaunchKernelGGL(combine_kernel, rgrd, blk, 0, stream,
                       Fh, Fl, B1h, B1l, B2h, B2l, B3h, B3l, OTh, OTl, scores,
                       B1h, B1l, N);
    // 10. out = MLP2(combined, m) -> f32 d_out (qo dead)
    mlp(B1h, B1l, 11, m_b1, 12, m_b2, nullptr, nullptr, nullptr, nullptr, (float*)d_out);
}

// Round 9
// 2337.021 us; speedup vs baseline: 6.3730x; 1.0145x over previous
//
#include <hip/hip_runtime.h>

// HigherOrderGINLayer — round 9: score-fold kept, qk never materialized.
// Round-8 failed (0.1719): qk stored bf16-hi lost too much score precision.
// Fix: run the qk=F@P+pb GEMM after all 5 feature sets exist and fuse the
// score dot (vs all 5 split f_k) into its epilogue with f32 accumulators +
// shfl-reduce + atomicAdd (the round-6-proven pattern). A-hi-only LDS staging
// and fused MLPs kept.

#define DO 256

typedef unsigned short u16;
typedef __attribute__((ext_vector_type(8))) short bf16x8;
typedef __attribute__((ext_vector_type(4))) float f32x4;

static __device__ __forceinline__ u16 f2b(float f) {
    unsigned u = __float_as_uint(f);
    return (u16)((u + 0x7fffu + ((u >> 16) & 1u)) >> 16);   // RNE
}
static __device__ __forceinline__ float b2f(u16 h) {
    return __uint_as_float(((unsigned)h) << 16);
}
static __device__ __forceinline__ float b2f2(u16 h, u16 l) {
    return b2f(h) + b2f(l);
}

// ------------- weights: transpose + split  Wt[c][k] = W[k][c] --------------
struct WDesc { const float* src; u16* hi; u16* lo; int C; };
struct WPack { WDesc w[13]; };

__global__ __launch_bounds__(256) void transpose_w_kernel(WPack p) {
    WDesc d = p.w[blockIdx.y];
    int idx = blockIdx.x * 256 + threadIdx.x;
    if (idx >= d.C * 256) return;
    int c = idx >> 8, k = idx & 255;
    float v = d.src[k * d.C + c];
    u16 h = f2b(v);
    d.hi[idx] = h;
    d.lo[idx] = f2b(v - b2f(h));
}

// P(t)[j][i] = sum_p qW[i,p]*kW[j,p]  (split, Wt layout idx = j*256+i)
__global__ __launch_bounds__(256) void build_p_kernel(
    const float* __restrict__ qW, const float* __restrict__ kW,
    u16* __restrict__ ph, u16* __restrict__ pl)
{
    int idx = blockIdx.x * 256 + threadIdx.x;      // 65536
    int j = idx >> 8, i = idx & 255;
    float s = 0.f;
    #pragma unroll 8
    for (int p = 0; p < 128; ++p) s += qW[i * 128 + p] * kW[j * 128 + p];
    u16 h = f2b(s);
    ph[idx] = h;
    pl[idx] = f2b(s - b2f(h));
}

// pb[j] = sum_p q_b[p] * kW[j,p]
__global__ __launch_bounds__(256) void build_pb_kernel(
    const float* __restrict__ qb, const float* __restrict__ kW,
    float* __restrict__ pb)
{
    int j = threadIdx.x;
    float s = 0.f;
    #pragma unroll 8
    for (int p = 0; p < 128; ++p) s += qb[p] * kW[j * 128 + p];
    pb[j] = s;
}

// ------------- f32 -> split bf16 -------------------------------------------
__global__ __launch_bounds__(256) void convert_split_kernel(
    const float* __restrict__ src, u16* __restrict__ hi, u16* __restrict__ lo,
    int n4)
{
    int i = blockIdx.x * 256 + threadIdx.x;
    if (i >= n4) return;
    float4 v = *(const float4*)&src[i * 4];
    ushort4 h, l;
    h.x = f2b(v.x); l.x = f2b(v.x - b2f(h.x));
    h.y = f2b(v.y); l.y = f2b(v.y - b2f(h.y));
    h.z = f2b(v.z); l.z = f2b(v.z - b2f(h.z));
    h.w = f2b(v.w); l.w = f2b(v.w - b2f(h.w));
    *(ushort4*)&hi[i * 4] = h;
    *(ushort4*)&lo[i * 4] = l;
}

// ------------- LDS(A-hi) split GEMM / fused MLP / fused scores -------------
// 256 thr = 4 waves, 64 rows x 256 cols. A-hi staged in 32KB LDS (XOR-swz);
// A-lo direct from global. GEMM1 = 3-term split MFMA.
// FUSED: relu(acc+b1) -> H-hi LDS -> GEMM2 2-term + b2 (+split add).
// SCORE: acc = qk (f32); dot vs 5 split f-sets -> shfl reduce -> atomicAdd Sc.
template<bool FUSED, bool SCORE>
__global__ __launch_bounds__(256) void gemm_tile_kernel(
    const u16* __restrict__ Ahi, const u16* __restrict__ Alo,
    const u16* __restrict__ W1h, const u16* __restrict__ W1l,
    const float* __restrict__ b1,
    const u16* __restrict__ W2h, const u16* __restrict__ W2l,
    const float* __restrict__ b2,
    const u16* __restrict__ Adh, const u16* __restrict__ Adl,
    u16* __restrict__ Chi, u16* __restrict__ Clo, float* __restrict__ Cf,
    const u16* __restrict__ F0h, const u16* __restrict__ F0l,
    const u16* __restrict__ F1h, const u16* __restrict__ F1l,
    const u16* __restrict__ F2h, const u16* __restrict__ F2l,
    const u16* __restrict__ F3h, const u16* __restrict__ F3l,
    const u16* __restrict__ F4h, const u16* __restrict__ F4l,
    float* __restrict__ Sc,
    int N)
{
    __shared__ char smem[32768];          // A-hi, then H-hi (fused)

    const int tid  = threadIdx.x;
    const int wave = tid >> 6, lane = tid & 63;
    const int lrow = lane & 15, kg = lane >> 4;
    const int wc   = wave * 64;
    const int brow = blockIdx.x * 64;

    // ---- stage A-hi (64 rows x 256 k) into LDS, swizzled ----
    #pragma unroll
    for (int j = 0; j < 8; ++j) {
        int i = tid + j * 256;            // chunk 0..2047 (16B each)
        int row = i >> 5, slot = i & 31;
        int srow = brow + row; srow = srow < N ? srow : N - 1;
        bf16x8 vh = *(const bf16x8*)&Ahi[(size_t)srow * 256 + slot * 8];
        int db = (row * 512 + slot * 16) ^ ((row & 7) << 4);
        *(bf16x8*)(smem + db) = vh;
    }
    __syncthreads();

    // ---- GEMM1: 3-term split (ah LDS, al global) ----
    f32x4 acc[4][4] = {};
    #pragma unroll
    for (int ks = 0; ks < 8; ++ks) {
        bf16x8 ah[4], al[4], bh[4], bl[4];
        #pragma unroll
        for (int m = 0; m < 4; ++m) {
            int arow = m * 16 + lrow;
            int ab = (arow * 512 + (ks * 4 + kg) * 16) ^ ((lrow & 7) << 4);
            ah[m] = *(const bf16x8*)(smem + ab);
            int r = brow + arow; r = r < N ? r : N - 1;
            al[m] = *(const bf16x8*)&Alo[(size_t)r * 256 + ks * 32 + kg * 8];
        }
        #pragma unroll
        for (int n = 0; n < 4; ++n) {
            size_t o = (size_t)(wc + n * 16 + lrow) * 256 + ks * 32 + kg * 8;
            bh[n] = *(const bf16x8*)&W1h[o];
            bl[n] = *(const bf16x8*)&W1l[o];
        }
        #pragma unroll
        for (int m = 0; m < 4; ++m)
            #pragma unroll
            for (int n = 0; n < 4; ++n) {
                acc[m][n] = __builtin_amdgcn_mfma_f32_16x16x32_bf16(
                                ah[m], bh[n], acc[m][n], 0, 0, 0);
                acc[m][n] = __builtin_amdgcn_mfma_f32_16x16x32_bf16(
                                ah[m], bl[n], acc[m][n], 0, 0, 0);
                acc[m][n] = __builtin_amdgcn_mfma_f32_16x16x32_bf16(
                                al[m], bh[n], acc[m][n], 0, 0, 0);
            }
    }

    if (SCORE) {
        // qk fragments (f32) . f_k — reduce over 16-lane col group, atomic.
        #pragma unroll
        for (int m = 0; m < 4; ++m) {
            #pragma unroll
            for (int j = 0; j < 4; ++j) {
                int r = brow + m * 16 + kg * 4 + j;
                float p0 = 0.f, p1 = 0.f, p2 = 0.f, p3 = 0.f, p4 = 0.f;
                if (r < N) {
                    #pragma unroll
                    for (int n = 0; n < 4; ++n) {
                        int c = wc + n * 16 + lrow;
                        float v = acc[m][n][j] + b1[c];
                        size_t fo_ = (size_t)r * 256 + c;
                        p0 += v * b2f2(F0h[fo_], F0l[fo_]);
                        p1 += v * b2f2(F1h[fo_], F1l[fo_]);
                        p2 += v * b2f2(F2h[fo_], F2l[fo_]);
                        p3 += v * b2f2(F3h[fo_], F3l[fo_]);
                        p4 += v * b2f2(F4h[fo_], F4l[fo_]);
                    }
                }
                #pragma unroll
                for (int d = 1; d < 16; d <<= 1) {
                    p0 += __shfl_xor(p0, d, 64);
                    p1 += __shfl_xor(p1, d, 64);
                    p2 += __shfl_xor(p2, d, 64);
                    p3 += __shfl_xor(p3, d, 64);
                    p4 += __shfl_xor(p4, d, 64);
                }
                if (lrow == 0 && r < N) {
                    atomicAdd(&Sc[(size_t)r * 5 + 0], p0);
                    atomicAdd(&Sc[(size_t)r * 5 + 1], p1);
                    atomicAdd(&Sc[(size_t)r * 5 + 2], p2);
                    atomicAdd(&Sc[(size_t)r * 5 + 3], p3);
                    atomicAdd(&Sc[(size_t)r * 5 + 4], p4);
                }
            }
        }
        return;
    }

    if (!FUSED) {
        #pragma unroll
        for (int n = 0; n < 4; ++n) {
            int c = wc + n * 16 + lrow;
            float bv = b1[c];
            #pragma unroll
            for (int m = 0; m < 4; ++m)
                #pragma unroll
                for (int j = 0; j < 4; ++j) {
                    int r = brow + m * 16 + kg * 4 + j;
                    if (r >= N) continue;
                    size_t o = (size_t)r * 256 + c;
                    float v = acc[m][n][j] + bv;
                    if (Cf) Cf[o] = v;
                    else {
                        u16 h = f2b(v);
                        Chi[o] = h;
                        if (Clo) Clo[o] = f2b(v - b2f(h));
                    }
                }
        }
        return;
    }

    // ---- fused: H = relu(acc + b1) -> LDS (swizzled) ----
    __syncthreads();                      // all A-hi reads done
    #pragma unroll
    for (int n = 0; n < 4; ++n) {
        int c = wc + n * 16 + lrow;
        float bv = b1[c];
        #pragma unroll
        for (int m = 0; m < 4; ++m)
            #pragma unroll
            for (int j = 0; j < 4; ++j) {
                int rl = m * 16 + kg * 4 + j;
                float v = fmaxf(acc[m][n][j] + bv, 0.f);
                int hb = (rl * 512 + c * 2) ^ ((rl & 7) << 4);
                *(u16*)(smem + hb) = f2b(v);
            }
    }
    __syncthreads();

    // ---- GEMM2: 2-term (H hi-only) ----
    #pragma unroll
    for (int m = 0; m < 4; ++m)
        #pragma unroll
        for (int n = 0; n < 4; ++n)
            acc[m][n] = f32x4{0.f, 0.f, 0.f, 0.f};
    #pragma unroll
    for (int ks = 0; ks < 8; ++ks) {
        bf16x8 ah[4], bh[4], bl[4];
        #pragma unroll
        for (int m = 0; m < 4; ++m) {
            int arow = m * 16 + lrow;
            int ab = (arow * 512 + (ks * 4 + kg) * 16) ^ ((lrow & 7) << 4);
            ah[m] = *(const bf16x8*)(smem + ab);
        }
        #pragma unroll
        for (int n = 0; n < 4; ++n) {
            size_t o = (size_t)(wc + n * 16 + lrow) * 256 + ks * 32 + kg * 8;
            bh[n] = *(const bf16x8*)&W2h[o];
            bl[n] = *(const bf16x8*)&W2l[o];
        }
        #pragma unroll
        for (int m = 0; m < 4; ++m)
            #pragma unroll
            for (int n = 0; n < 4; ++n) {
                acc[m][n] = __builtin_amdgcn_mfma_f32_16x16x32_bf16(
                                ah[m], bh[n], acc[m][n], 0, 0, 0);
                acc[m][n] = __builtin_amdgcn_mfma_f32_16x16x32_bf16(
                                ah[m], bl[n], acc[m][n], 0, 0, 0);
            }
    }

    #pragma unroll
    for (int n = 0; n < 4; ++n) {
        int c = wc + n * 16 + lrow;
        float bv = b2[c];
        #pragma unroll
        for (int m = 0; m < 4; ++m)
            #pragma unroll
            for (int j = 0; j < 4; ++j) {
                int r = brow + m * 16 + kg * 4 + j;
                if (r >= N) continue;
                size_t o = (size_t)r * 256 + c;
                float v = acc[m][n][j] + bv;
                if (Adh) v += b2f2(Adh[o], Adl[o]);
                if (Cf) Cf[o] = v;
                else {
                    u16 h = f2b(v);
                    Chi[o] = h;
                    if (Clo) Clo[o] = f2b(v - b2f(h));
                }
            }
    }
}

// ------------- CSR build ---------------------------------------------------
__global__ __launch_bounds__(256) void count_kernel(
    const int* __restrict__ rows, int* __restrict__ cnt, int E)
{
    int e = blockIdx.x * 256 + threadIdx.x;
    if (e < E) atomicAdd(&cnt[rows[e]], 1);
}

__global__ __launch_bounds__(1024) void scan_kernel(
    const int* __restrict__ cnt, int* __restrict__ off, int N)
{
    __shared__ int part[1024];
    const int t = threadIdx.x;
    const int chunk = (N + 1023) / 1024;
    const int lo = t * chunk;
    const int hi = min(lo + chunk, N);
    int s = 0;
    for (int i = lo; i < hi; ++i) s += cnt[i];
    part[t] = s;
    __syncthreads();
    for (int d = 1; d < 1024; d <<= 1) {
        int u = (t >= d) ? part[t - d] : 0;
        __syncthreads();
        part[t] += u;
        __syncthreads();
    }
    int running = part[t] - s;
    for (int i = lo; i < hi; ++i) { off[i] = running; running += cnt[i]; }
    if (t == 1023) off[N] = part[1023];
}

__global__ __launch_bounds__(256) void scatter_kernel(
    const int* __restrict__ rows, const int* __restrict__ cols,
    const float* __restrict__ vals, const int* __restrict__ off,
    int* __restrict__ cur, int* __restrict__ scol, float* __restrict__ sval,
    int E)
{
    int e = blockIdx.x * 256 + threadIdx.x;
    if (e >= E) return;
    int r = rows[e];
    int p = off[r] + atomicAdd(&cur[r], 1);
    scol[p] = cols[e];
    sval[p] = vals[e];
}

// ------------- SpMM: gather split (f32-exact), split store -----------------
__global__ __launch_bounds__(256) void spmm_csr_kernel(
    const int* __restrict__ off, const int* __restrict__ scol,
    const float* __restrict__ sval,
    const u16* __restrict__ Xh, const u16* __restrict__ Xl,
    u16* __restrict__ Yh, u16* __restrict__ Yl, int N)
{
    int r = blockIdx.x * 4 + (threadIdx.x >> 6);
    if (r >= N) return;
    int lane = threadIdx.x & 63;
    int e0 = off[r], e1 = off[r + 1];
    float a0 = 0.f, a1 = 0.f, a2 = 0.f, a3 = 0.f;
    for (int e = e0; e < e1; ++e) {
        int c = scol[e]; float v = sval[e];
        size_t xo = (size_t)c * DO + lane * 4;
        ushort4 xh = *(const ushort4*)&Xh[xo];
        ushort4 xl = *(const ushort4*)&Xl[xo];
        a0 = fmaf(v, b2f2(xh.x, xl.x), a0); a1 = fmaf(v, b2f2(xh.y, xl.y), a1);
        a2 = fmaf(v, b2f2(xh.z, xl.z), a2); a3 = fmaf(v, b2f2(xh.w, xl.w), a3);
    }
    size_t o = (size_t)r * DO + lane * 4;
    ushort4 h, l;
    h.x = f2b(a0); l.x = f2b(a0 - b2f(h.x));
    h.y = f2b(a1); l.y = f2b(a1 - b2f(h.y));
    h.z = f2b(a2); l.z = f2b(a2 - b2f(h.z));
    h.w = f2b(a3); l.w = f2b(a3 - b2f(h.w));
    *(ushort4*)&Yh[o] = h;
    *(ushort4*)&Yl[o] = l;
}

__global__ __launch_bounds__(256) void spmm_csr_dual_kernel(
    const int* __restrict__ off, const int* __restrict__ scol,
    const float* __restrict__ sval,
    const u16* __restrict__ X1h, const u16* __restrict__ X1l,
    const u16* __restrict__ X2h, const u16* __restrict__ X2l,
    u16* __restrict__ Y1h, u16* __restrict__ Y1l,
    u16* __restrict__ Y2h, u16* __restrict__ Y2l, int N)
{
    int r = blockIdx.x * 4 + (threadIdx.x >> 6);
    if (r >= N) return;
    int lane = threadIdx.x & 63;
    int e0 = off[r], e1 = off[r + 1];
    float a0 = 0.f, a1 = 0.f, a2 = 0.f, a3 = 0.f;
    float b0 = 0.f, b1 = 0.f, b2 = 0.f, b3 = 0.f;
    for (int e = e0; e < e1; ++e) {
        int c = scol[e]; float v = sval[e];
        size_t xo = (size_t)c * DO + lane * 4;
        ushort4 x1h = *(const ushort4*)&X1h[xo];
        ushort4 x1l = *(const ushort4*)&X1l[xo];
        ushort4 x2h = *(const ushort4*)&X2h[xo];
        ushort4 x2l = *(const ushort4*)&X2l[xo];
        a0 = fmaf(v, b2f2(x1h.x, x1l.x), a0); a1 = fmaf(v, b2f2(x1h.y, x1l.y), a1);
        a2 = fmaf(v, b2f2(x1h.z, x1l.z), a2); a3 = fmaf(v, b2f2(x1h.w, x1l.w), a3);
        b0 = fmaf(v, b2f2(x2h.x, x2l.x), b0); b1 = fmaf(v, b2f2(x2h.y, x2l.y), b1);
        b2 = fmaf(v, b2f2(x2h.z, x2l.z), b2); b3 = fmaf(v, b2f2(x2h.w, x2l.w), b3);
    }
    size_t o = (size_t)r * DO + lane * 4;
    ushort4 h, l;
    h.x = f2b(a0); l.x = f2b(a0 - b2f(h.x));
    h.y = f2b(a1); l.y = f2b(a1 - b2f(h.y));
    h.z = f2b(a2); l.z = f2b(a2 - b2f(h.z));
    h.w = f2b(a3); l.w = f2b(a3 - b2f(h.w));
    *(ushort4*)&Y1h[o] = h; *(ushort4*)&Y1l[o] = l;
    h.x = f2b(b0); l.x = f2b(b0 - b2f(h.x));
    h.y = f2b(b1); l.y = f2b(b1 - b2f(h.y));
    h.z = f2b(b2); l.z = f2b(b2 - b2f(h.z));
    h.w = f2b(b3); l.w = f2b(b3 - b2f(h.w));
    *(ushort4*)&Y2h[o] = h; *(ushort4*)&Y2l[o] = l;
}

// ------------- softmax-combine (scores precomputed, all inputs split) ------
__global__ __launch_bounds__(256) void combine_kernel(
    const u16* __restrict__ f0h, const u16* __restrict__ f0l,
    const u16* __restrict__ f1h, const u16* __restrict__ f1l,
    const u16* __restrict__ f2h, const u16* __restrict__ f2l,
    const u16* __restrict__ f3h, const u16* __restrict__ f3l,
    const u16* __restrict__ f4h, const u16* __restrict__ f4l,
    const float* __restrict__ scores,
    u16* __restrict__ oh, u16* __restrict__ ol, int N)
{
    int n = blockIdx.x * 4 + (threadIdx.x >> 6);
    if (n >= N) return;
    int lane = threadIdx.x & 63;
    float s[5];
    #pragma unroll
    for (int k = 0; k < 5; ++k) s[k] = scores[(size_t)n * 5 + k];
    float m = fmaxf(fmaxf(fmaxf(s[0], s[1]), fmaxf(s[2], s[3])), s[4]);
    float sum = 0.f;
    #pragma unroll
    for (int k = 0; k < 5; ++k) { s[k] = expf(s[k] - m); sum += s[k]; }
    float inv = 1.f / sum;
    #pragma unroll
    for (int k = 0; k < 5; ++k) s[k] *= inv;
    size_t o = (size_t)n * DO + lane * 4;
    ushort4 h0 = *(const ushort4*)&f0h[o], l0 = *(const ushort4*)&f0l[o];
    ushort4 h1 = *(const ushort4*)&f1h[o], l1 = *(const ushort4*)&f1l[o];
    ushort4 h2 = *(const ushort4*)&f2h[o], l2 = *(const ushort4*)&f2l[o];
    ushort4 h3 = *(const ushort4*)&f3h[o], l3 = *(const ushort4*)&f3l[o];
    ushort4 h4 = *(const ushort4*)&f4h[o], l4 = *(const ushort4*)&f4l[o];
    float r0 = s[0]*b2f2(h0.x,l0.x) + s[1]*b2f2(h1.x,l1.x) + s[2]*b2f2(h2.x,l2.x)
             + s[3]*b2f2(h3.x,l3.x) + s[4]*b2f2(h4.x,l4.x);
    float r1 = s[0]*b2f2(h0.y,l0.y) + s[1]*b2f2(h1.y,l1.y) + s[2]*b2f2(h2.y,l2.y)
             + s[3]*b2f2(h3.y,l3.y) + s[4]*b2f2(h4.y,l4.y);
    float r2 = s[0]*b2f2(h0.z,l0.z) + s[1]*b2f2(h1.z,l1.z) + s[2]*b2f2(h2.z,l2.z)
             + s[3]*b2f2(h3.z,l3.z) + s[4]*b2f2(h4.z,l4.z);
    float r3 = s[0]*b2f2(h0.w,l0.w) + s[1]*b2f2(h1.w,l1.w) + s[2]*b2f2(h2.w,l2.w)
             + s[3]*b2f2(h3.w,l3.w) + s[4]*b2f2(h4.w,l4.w);
    ushort4 h, l;
    h.x = f2b(r0); l.x = f2b(r0 - b2f(h.x));
    h.y = f2b(r1); l.y = f2b(r1 - b2f(h.y));
    h.z = f2b(r2); l.z = f2b(r2 - b2f(h.z));
    h.w = f2b(r3); l.w = f2b(r3 - b2f(h.w));
    *(ushort4*)&oh[o] = h;
    *(ushort4*)&ol[o] = l;
}

extern "C" void kernel_launch(void* const* d_in, const int* in_sizes, int n_in,
                              void* d_out, int out_size, void* d_ws, size_t ws_size,
                              hipStream_t stream)
{
    const float* features      = (const float*)d_in[0];
    const float* edge_features = (const float*)d_in[1];
    const int*   adj_idx[4] = {(const int*)d_in[2], (const int*)d_in[4],
                               (const int*)d_in[6], (const int*)d_in[8]};
    const float* adj_val[4] = {(const float*)d_in[3], (const float*)d_in[5],
                               (const float*)d_in[7], (const float*)d_in[9]};
    const int E[4] = {in_sizes[3], in_sizes[5], in_sizes[7], in_sizes[9]};
    const int Emax = max(max(E[0], E[1]), max(E[2], E[3]));

    const float* ft_W = (const float*)d_in[10]; const float* ft_b = (const float*)d_in[11];
    const float* fo_W1 = (const float*)d_in[12]; const float* fo_b1 = (const float*)d_in[13];
    const float* fo_W2 = (const float*)d_in[14]; const float* fo_b2 = (const float*)d_in[15];
    const float* em_W1 = (const float*)d_in[16]; const float* em_b1 = (const float*)d_in[17];
    const float* em_W2 = (const float*)d_in[18]; const float* em_b2 = (const float*)d_in[19];
    const float* so_W1 = (const float*)d_in[20]; const float* so_b1 = (const float*)d_in[21];
    const float* so_W2 = (const float*)d_in[22]; const float* so_b2 = (const float*)d_in[23];
    const float* to_W1 = (const float*)d_in[24]; const float* to_b1 = (const float*)d_in[25];
    const float* to_W2 = (const float*)d_in[26]; const float* to_b2 = (const float*)d_in[27];
    const float* qo_W1 = (const float*)d_in[28]; const float* qo_b1 = (const float*)d_in[29];
    const float* qo_W2 = (const float*)d_in[30]; const float* qo_b2 = (const float*)d_in[31];
    const float* m_W1  = (const float*)d_in[32]; const float* m_b1  = (const float*)d_in[33];
    const float* m_W2  = (const float*)d_in[34]; const float* m_b2  = (const float*)d_in[35];
    const float* q_W   = (const float*)d_in[36]; const float* q_b   = (const float*)d_in[37];
    const float* k_W   = (const float*)d_in[38]; const float* k_b   = (const float*)d_in[39];
    (void)k_b;   // q.k_b is constant across the 5 scores -> softmax-invariant

    const int N = in_sizes[0] / 256;
    const size_t NS = (size_t)N * DO;

    // ---- workspace: CSR zone + 4 split slots + WT + scores (~219MB) -------
    char* base = (char*)d_ws;
    size_t o = 0;
    auto take = [&](size_t bytes) { char* p = base + o; o += (bytes + 63) & ~(size_t)63; return p; };
    const int NP = (N + 64) & ~63;
    int*   cnt  = (int*)take((size_t)(3 * NP + 64) * 4);   // cnt|cur|off
    int*   scol = (int*)take((size_t)Emax * 4);
    float* sval = (float*)take((size_t)Emax * 4);
    u16* B1 = (u16*)take(NS * 4);      // Fin -> agg1/fo -> combined
    u16* B2 = (u16*)take(NS * 4);      // Ein -> aggef -> agg2/so
    u16* B3 = (u16*)take(NS * 4);      // ef -> agg3/to
    u16* B4 = (u16*)take(NS * 4);      // F split (live to combine)
    const size_t WSQ = 65536;
    u16* WTh = (u16*)take(14 * WSQ * 2);   // 13 weights + P (slot 13)
    u16* WTl = (u16*)take(14 * WSQ * 2);
    float* pb = (float*)take(256 * 4);
    float* scores = (float*)take((size_t)N * 5 * 4);
    if (o > ws_size) return;           // graceful guard

    int* cur = cnt + NP;
    int* off = cnt + 2 * NP;
    u16 *B1h = B1, *B1l = B1 + NS;
    u16 *B2h = B2, *B2l = B2 + NS;
    u16 *B3h = B3, *B3l = B3 + NS;
    u16 *Fh  = B4, *Fl  = B4 + NS;
    u16 *OTh = (u16*)d_out, *OTl = (u16*)d_out + NS;   // agg4/qo split slot

    u16 *wh[14], *wl[14];
    for (int i = 0; i < 14; ++i) { wh[i] = WTh + (size_t)i * WSQ; wl[i] = WTl + (size_t)i * WSQ; }

    dim3 blk(256);
    {   // weights: transpose + split (13 square weights)
        WPack p;
        const float* src[13] = {ft_W, fo_W1, fo_W2, em_W1, em_W2, so_W1, so_W2,
                                to_W1, to_W2, qo_W1, qo_W2, m_W1, m_W2};
        for (int i = 0; i < 13; ++i) {
            p.w[i].src = src[i]; p.w[i].hi = wh[i]; p.w[i].lo = wl[i]; p.w[i].C = 256;
        }
        hipLaunchKernelGGL(transpose_w_kernel, dim3(256, 13), blk, 0, stream, p);
    }
    // P = qW @ kW^T (split, slot 13) ; pb = q_b @ kW^T
    hipLaunchKernelGGL(build_p_kernel, dim3(256), blk, 0, stream, q_W, k_W, wh[13], wl[13]);
    hipLaunchKernelGGL(build_pb_kernel, dim3(1), blk, 0, stream, q_b, k_W, pb);
    {   // inputs -> split bf16
        int n4 = (int)(NS / 4);
        dim3 g((n4 + 255) / 256);
        hipLaunchKernelGGL(convert_split_kernel, g, blk, 0, stream, features, B1h, B1l, n4);
        hipLaunchKernelGGL(convert_split_kernel, g, blk, 0, stream, edge_features, B2h, B2l, n4);
    }

    dim3 ggrd((N + 63) / 64);
    auto mlp = [&](const u16* ah, const u16* al, int w1, const float* bb1,
                   int w2, const float* bb2, const u16* adh, const u16* adl,
                   u16* ch, u16* cl, float* cf) {
        hipLaunchKernelGGL((gemm_tile_kernel<true, false>), ggrd, blk, 0, stream,
                           ah, al, wh[w1], wl[w1], bb1, wh[w2], wl[w2], bb2,
                           adh, adl, ch, cl, cf,
                           nullptr, nullptr, nullptr, nullptr, nullptr,
                           nullptr, nullptr, nullptr, nullptr, nullptr,
                           nullptr, N);
    };
    auto gemm1 = [&](const u16* ah, const u16* al, int w, const float* bb,
                     u16* ch, u16* cl, float* cf) {
        hipLaunchKernelGGL((gemm_tile_kernel<false, false>), ggrd, blk, 0, stream,
                           ah, al, wh[w], wl[w], bb, nullptr, nullptr, nullptr,
                           nullptr, nullptr, ch, cl, cf,
                           nullptr, nullptr, nullptr, nullptr, nullptr,
                           nullptr, nullptr, nullptr, nullptr, nullptr,
                           nullptr, N);
    };
    auto build_csr = [&](int i) {
        int Ei = E[i];
        hipMemsetAsync(cnt, 0, (size_t)N * sizeof(int), stream);
        hipMemsetAsync(cur, 0, (size_t)N * sizeof(int), stream);
        dim3 egrd((Ei + 255) / 256);
        hipLaunchKernelGGL(count_kernel, egrd, blk, 0, stream, adj_idx[i], cnt, Ei);
        hipLaunchKernelGGL(scan_kernel, dim3(1), dim3(1024), 0, stream, cnt, off, N);
        hipLaunchKernelGGL(scatter_kernel, egrd, blk, 0, stream,
                           adj_idx[i], adj_idx[i] + Ei, adj_val[i], off, cur, scol, sval, Ei);
    };
    dim3 rgrd((N + 3) / 4);
    auto spmm = [&](const u16* xh, const u16* xl, u16* yh, u16* yl) {
        hipLaunchKernelGGL(spmm_csr_kernel, rgrd, blk, 0, stream,
                           off, scol, sval, xh, xl, yh, yl, N);
    };

    // 1. F = features @ ft_W + ft_b -> B4 split
    gemm1(B1h, B1l, 0, ft_b, Fh, Fl, nullptr);
    // 2. ef = MLP2(edge_features, em) -> B3 split
    mlp(B2h, B2l, 3, em_b1, 4, em_b2, nullptr, nullptr, B3h, B3l, nullptr);
    // 3. adj1: agg1 -> B1 (Fin dead), aggef -> B2 (Ein dead)
    build_csr(0);
    hipLaunchKernelGGL(spmm_csr_dual_kernel, rgrd, blk, 0, stream,
                       off, scol, sval, Fh, Fl, B3h, B3l, B1h, B1l, B2h, B2l, N);
    // 4. fo = MLP2(agg1) + aggef -> B1
    mlp(B1h, B1l, 1, fo_b1, 2, fo_b2, B2h, B2l, B1h, B1l, nullptr);
    // 5. so = MLP2(agg2) + agg2 -> B2 (aggef dead)
    build_csr(1); spmm(Fh, Fl, B2h, B2l);
    mlp(B2h, B2l, 5, so_b1, 6, so_b2, B2h, B2l, B2h, B2l, nullptr);
    // 6. to = MLP2(agg3) + agg3 -> B3 (ef dead)
    build_csr(2); spmm(Fh, Fl, B3h, B3l);
    mlp(B3h, B3l, 7, to_b1, 8, to_b2, B3h, B3l, B3h, B3l, nullptr);
    // 7. qo = MLP2(agg4) + agg4 -> d_out slot
    build_csr(3); spmm(Fh, Fl, OTh, OTl);
    mlp(OTh, OTl, 9, qo_b1, 10, qo_b2, OTh, OTl, OTh, OTl, nullptr);

    // 8. scores: qk = F@P+pb in-register (f32), dot vs 5 f-sets -> scores
    hipMemsetAsync(scores, 0, (size_t)N * 5 * sizeof(float), stream);
    hipLaunchKernelGGL((gemm_tile_kernel<false, true>), ggrd, blk, 0, stream,
                       Fh, Fl, wh[13], wl[13], pb, nullptr, nullptr, nullptr,
                       nullptr, nullptr, nullptr, nullptr, nullptr,
                       Fh, Fl, B1h, B1l, B2h, B2l, B3h, B3l, OTh, OTl,
                       scores, N);
    // 9. softmax + combine -> B1 (in-place over fo)
    hipLaunchKernelGGL(combine_kernel, rgrd, blk, 0, stream,
                       Fh, Fl, B1h, B1l, B2h, B2l, B3h, B3l, OTh, OTl, scores,
                       B1h, B1l, N);
    // 10. out = MLP2(combined, m) -> f32 d_out (qo dead)
    mlp(B1h, B1l, 11, m_b1, 12, m_b2, nullptr, nullptr, nullptr, nullptr, (float*)d_out);
}

// Round 10
// 2167.346 us; speedup vs baseline: 6.8719x; 1.0783x over previous
//
#include <hip/hip_runtime.h>

// HigherOrderGINLayer — round 10: fragment-packed weights (coalesced B loads),
// A hi+lo both LDS-staged, and a merged score+combine kernel (LDS reduce).
// Round-9 analysis: GEMMs were L2-transaction-bound — B fragment loads hit 16
// strided rows per instruction. Packing weights in MFMA-fragment-linear order
// makes every B load one 1KB coalesced transaction. Numerics unchanged from
// the proven 0.0547 configuration.

#define DO 256

typedef unsigned short u16;
typedef __attribute__((ext_vector_type(8))) short bf16x8;
typedef __attribute__((ext_vector_type(4))) float f32x4;

static __device__ __forceinline__ u16 f2b(float f) {
    unsigned u = __float_as_uint(f);
    return (u16)((u + 0x7fffu + ((u >> 16) & 1u)) >> 16);   // RNE
}
static __device__ __forceinline__ float b2f(u16 h) {
    return __uint_as_float(((unsigned)h) << 16);
}
static __device__ __forceinline__ float b2f2(u16 h, u16 l) {
    return b2f(h) + b2f(l);
}

// Packed weight layout (per 256x256 weight, 65536 elems):
//   idx = ((frag*8 + ks)*64 + lane)*8 + e
//   col c = frag*16 + (lane&15),  k = ks*32 + (lane>>4)*8 + e
// Wave w, fragment n, k-step ks loads 1KB coalesced at
//   base = ((w*4+n)*8 + ks)*512 + lane*8.

// ------------- weights: transpose + split + pack ---------------------------
struct WDesc { const float* src; u16* hi; u16* lo; };
struct WPack { WDesc w[13]; };

__global__ __launch_bounds__(256) void transpose_w_kernel(WPack p) {
    WDesc d = p.w[blockIdx.y];
    int idx = blockIdx.x * 256 + threadIdx.x;        // 0..65535
    int e  = idx & 7;
    int l  = (idx >> 3) & 63;
    int ks = (idx >> 9) & 7;
    int f  = idx >> 12;
    int c  = (f << 4) | (l & 15);
    int k  = ks * 32 + ((l >> 4) << 3) + e;
    float v = d.src[k * 256 + c];
    u16 h = f2b(v);
    d.hi[idx] = h;
    d.lo[idx] = f2b(v - b2f(h));
}

// P[c][k] = sum_p qW[k,p]*kW[c,p], packed layout (score fold)
__global__ __launch_bounds__(256) void build_p_kernel(
    const float* __restrict__ qW, const float* __restrict__ kW,
    u16* __restrict__ ph, u16* __restrict__ pl)
{
    int idx = blockIdx.x * 256 + threadIdx.x;        // 65536
    int e  = idx & 7;
    int l  = (idx >> 3) & 63;
    int ks = (idx >> 9) & 7;
    int f  = idx >> 12;
    int c  = (f << 4) | (l & 15);
    int k  = ks * 32 + ((l >> 4) << 3) + e;
    float s = 0.f;
    #pragma unroll 8
    for (int p = 0; p < 128; ++p) s += qW[k * 128 + p] * kW[c * 128 + p];
    u16 h = f2b(s);
    ph[idx] = h;
    pl[idx] = f2b(s - b2f(h));
}

// pb[c] = sum_p q_b[p] * kW[c,p]
__global__ __launch_bounds__(256) void build_pb_kernel(
    const float* __restrict__ qb, const float* __restrict__ kW,
    float* __restrict__ pb)
{
    int c = threadIdx.x;
    float s = 0.f;
    #pragma unroll 8
    for (int p = 0; p < 128; ++p) s += qb[p] * kW[c * 128 + p];
    pb[c] = s;
}

// ------------- f32 -> split bf16 -------------------------------------------
__global__ __launch_bounds__(256) void convert_split_kernel(
    const float* __restrict__ src, u16* __restrict__ hi, u16* __restrict__ lo,
    int n4)
{
    int i = blockIdx.x * 256 + threadIdx.x;
    if (i >= n4) return;
    float4 v = *(const float4*)&src[i * 4];
    ushort4 h, l;
    h.x = f2b(v.x); l.x = f2b(v.x - b2f(h.x));
    h.y = f2b(v.y); l.y = f2b(v.y - b2f(h.y));
    h.z = f2b(v.z); l.z = f2b(v.z - b2f(h.z));
    h.w = f2b(v.w); l.w = f2b(v.w - b2f(h.w));
    *(ushort4*)&hi[i * 4] = h;
    *(ushort4*)&lo[i * 4] = l;
}

// ------------- LDS-staged split GEMM / fused MLP ---------------------------
// 256 thr = 4 waves, 64 rows x 256 cols; A hi+lo staged in 64KB LDS (XOR swz).
// GEMM1 3-term split MFMA (packed W). FUSED: relu(acc+b1) -> H-hi in LDS ->
// GEMM2 2-term + b2 (+split add). Out: split | hi-only | f32.
template<bool FUSED>
__global__ __launch_bounds__(256) void gemm_tile_kernel(
    const u16* __restrict__ Ahi, const u16* __restrict__ Alo,
    const u16* __restrict__ W1h, const u16* __restrict__ W1l,
    const float* __restrict__ b1,
    const u16* __restrict__ W2h, const u16* __restrict__ W2l,
    const float* __restrict__ b2,
    const u16* __restrict__ Adh, const u16* __restrict__ Adl,
    u16* __restrict__ Chi, u16* __restrict__ Clo, float* __restrict__ Cf,
    int N)
{
    __shared__ char smem[65536];          // [0,32K) A-hi / H ; [32K,64K) A-lo

    const int tid  = threadIdx.x;
    const int wave = tid >> 6, lane = tid & 63;
    const int lrow = lane & 15, kg = lane >> 4;
    const int wc   = wave * 64;
    const int brow = blockIdx.x * 64;

    // ---- stage A hi+lo (64 rows x 256 k) into LDS, swizzled ----
    #pragma unroll
    for (int j = 0; j < 8; ++j) {
        int i = tid + j * 256;            // 16B chunk 0..2047
        int row = i >> 5, slot = i & 31;
        int srow = brow + row; srow = srow < N ? srow : N - 1;
        size_t go = (size_t)srow * 256 + slot * 8;
        bf16x8 vh = *(const bf16x8*)&Ahi[go];
        bf16x8 vl = *(const bf16x8*)&Alo[go];
        int db = (row * 512 + slot * 16) ^ ((row & 7) << 4);
        *(bf16x8*)(smem + db) = vh;
        *(bf16x8*)(smem + 32768 + db) = vl;
    }
    __syncthreads();

    // ---- GEMM1: 3-term split ----
    f32x4 acc[4][4] = {};
    #pragma unroll
    for (int ks = 0; ks < 8; ++ks) {
        bf16x8 ah[4], al[4], bh[4], bl[4];
        #pragma unroll
        for (int m = 0; m < 4; ++m) {
            int ab = ((m * 16 + lrow) * 512 + (ks * 4 + kg) * 16) ^ ((lrow & 7) << 4);
            ah[m] = *(const bf16x8*)(smem + ab);
            al[m] = *(const bf16x8*)(smem + 32768 + ab);
        }
        #pragma unroll
        for (int n = 0; n < 4; ++n) {
            size_t o = (size_t)(((wave * 4 + n) * 8 + ks) << 9) + (lane << 3);
            bh[n] = *(const bf16x8*)&W1h[o];
            bl[n] = *(const bf16x8*)&W1l[o];
        }
        #pragma unroll
        for (int m = 0; m < 4; ++m)
            #pragma unroll
            for (int n = 0; n < 4; ++n) {
                acc[m][n] = __builtin_amdgcn_mfma_f32_16x16x32_bf16(
                                ah[m], bh[n], acc[m][n], 0, 0, 0);
                acc[m][n] = __builtin_amdgcn_mfma_f32_16x16x32_bf16(
                                ah[m], bl[n], acc[m][n], 0, 0, 0);
                acc[m][n] = __builtin_amdgcn_mfma_f32_16x16x32_bf16(
                                al[m], bh[n], acc[m][n], 0, 0, 0);
            }
    }

    if (!FUSED) {
        #pragma unroll
        for (int n = 0; n < 4; ++n) {
            int c = wc + n * 16 + lrow;
            float bv = b1[c];
            #pragma unroll
            for (int m = 0; m < 4; ++m)
                #pragma unroll
                for (int j = 0; j < 4; ++j) {
                    int r = brow + m * 16 + kg * 4 + j;
                    if (r >= N) continue;
                    size_t o = (size_t)r * 256 + c;
                    float v = acc[m][n][j] + bv;
                    if (Cf) Cf[o] = v;
                    else {
                        u16 h = f2b(v);
                        Chi[o] = h;
                        if (Clo) Clo[o] = f2b(v - b2f(h));
                    }
                }
        }
        return;
    }

    // ---- fused: H = relu(acc + b1) -> LDS hi region (swizzled) ----
    __syncthreads();
    #pragma unroll
    for (int n = 0; n < 4; ++n) {
        int c = wc + n * 16 + lrow;
        float bv = b1[c];
        #pragma unroll
        for (int m = 0; m < 4; ++m)
            #pragma unroll
            for (int j = 0; j < 4; ++j) {
                int rl = m * 16 + kg * 4 + j;
                float v = fmaxf(acc[m][n][j] + bv, 0.f);
                int hb = (rl * 512 + c * 2) ^ ((rl & 7) << 4);
                *(u16*)(smem + hb) = f2b(v);
            }
    }
    __syncthreads();

    // ---- GEMM2: 2-term (H hi-only) ----
    #pragma unroll
    for (int m = 0; m < 4; ++m)
        #pragma unroll
        for (int n = 0; n < 4; ++n)
            acc[m][n] = f32x4{0.f, 0.f, 0.f, 0.f};
    #pragma unroll
    for (int ks = 0; ks < 8; ++ks) {
        bf16x8 ah[4], bh[4], bl[4];
        #pragma unroll
        for (int m = 0; m < 4; ++m) {
            int ab = ((m * 16 + lrow) * 512 + (ks * 4 + kg) * 16) ^ ((lrow & 7) << 4);
            ah[m] = *(const bf16x8*)(smem + ab);
        }
        #pragma unroll
        for (int n = 0; n < 4; ++n) {
            size_t o = (size_t)(((wave * 4 + n) * 8 + ks) << 9) + (lane << 3);
            bh[n] = *(const bf16x8*)&W2h[o];
            bl[n] = *(const bf16x8*)&W2l[o];
        }
        #pragma unroll
        for (int m = 0; m < 4; ++m)
            #pragma unroll
            for (int n = 0; n < 4; ++n) {
                acc[m][n] = __builtin_amdgcn_mfma_f32_16x16x32_bf16(
                                ah[m], bh[n], acc[m][n], 0, 0, 0);
                acc[m][n] = __builtin_amdgcn_mfma_f32_16x16x32_bf16(
                                ah[m], bl[n], acc[m][n], 0, 0, 0);
            }
    }

    #pragma unroll
    for (int n = 0; n < 4; ++n) {
        int c = wc + n * 16 + lrow;
        float bv = b2[c];
        #pragma unroll
        for (int m = 0; m < 4; ++m)
            #pragma unroll
            for (int j = 0; j < 4; ++j) {
                int r = brow + m * 16 + kg * 4 + j;
                if (r >= N) continue;
                size_t o = (size_t)r * 256 + c;
                float v = acc[m][n][j] + bv;
                if (Adh) v += b2f2(Adh[o], Adl[o]);
                if (Cf) Cf[o] = v;
                else {
                    u16 h = f2b(v);
                    Chi[o] = h;
                    if (Clo) Clo[o] = f2b(v - b2f(h));
                }
            }
    }
}

// ------------- merged scores + softmax + combine ---------------------------
// A = F (staged hi+lo in LDS). GEMM1: qk = F@P (3-term, packed P). Then per
// row: 5 dots (f0 = F from LDS, f1..4 global) -> LDS cross-wave reduce ->
// softmax -> weighted combine -> split out. Deterministic f32 scores.
__global__ __launch_bounds__(256) void score_combine_kernel(
    const u16* __restrict__ Fh, const u16* __restrict__ Fl,
    const u16* __restrict__ Ph, const u16* __restrict__ Pl,
    const float* __restrict__ pb,
    const u16* __restrict__ F1h, const u16* __restrict__ F1l,
    const u16* __restrict__ F2h, const u16* __restrict__ F2l,
    const u16* __restrict__ F3h, const u16* __restrict__ F3l,
    const u16* __restrict__ F4h, const u16* __restrict__ F4l,
    u16* __restrict__ Oh, u16* __restrict__ Ol,
    int N)
{
    __shared__ char smem[65536];
    __shared__ float sred[4][64][5];
    __shared__ float w5[64][5];

    const int tid  = threadIdx.x;
    const int wave = tid >> 6, lane = tid & 63;
    const int lrow = lane & 15, kg = lane >> 4;
    const int wc   = wave * 64;
    const int brow = blockIdx.x * 64;

    #pragma unroll
    for (int j = 0; j < 8; ++j) {
        int i = tid + j * 256;
        int row = i >> 5, slot = i & 31;
        int srow = brow + row; srow = srow < N ? srow : N - 1;
        size_t go = (size_t)srow * 256 + slot * 8;
        bf16x8 vh = *(const bf16x8*)&Fh[go];
        bf16x8 vl = *(const bf16x8*)&Fl[go];
        int db = (row * 512 + slot * 16) ^ ((row & 7) << 4);
        *(bf16x8*)(smem + db) = vh;
        *(bf16x8*)(smem + 32768 + db) = vl;
    }
    __syncthreads();

    f32x4 acc[4][4] = {};
    #pragma unroll
    for (int ks = 0; ks < 8; ++ks) {
        bf16x8 ah[4], al[4], bh[4], bl[4];
        #pragma unroll
        for (int m = 0; m < 4; ++m) {
            int ab = ((m * 16 + lrow) * 512 + (ks * 4 + kg) * 16) ^ ((lrow & 7) << 4);
            ah[m] = *(const bf16x8*)(smem + ab);
            al[m] = *(const bf16x8*)(smem + 32768 + ab);
        }
        #pragma unroll
        for (int n = 0; n < 4; ++n) {
            size_t o = (size_t)(((wave * 4 + n) * 8 + ks) << 9) + (lane << 3);
            bh[n] = *(const bf16x8*)&Ph[o];
            bl[n] = *(const bf16x8*)&Pl[o];
        }
        #pragma unroll
        for (int m = 0; m < 4; ++m)
            #pragma unroll
            for (int n = 0; n < 4; ++n) {
                acc[m][n] = __builtin_amdgcn_mfma_f32_16x16x32_bf16(
                                ah[m], bh[n], acc[m][n], 0, 0, 0);
                acc[m][n] = __builtin_amdgcn_mfma_f32_16x16x32_bf16(
                                ah[m], bl[n], acc[m][n], 0, 0, 0);
                acc[m][n] = __builtin_amdgcn_mfma_f32_16x16x32_bf16(
                                al[m], bh[n], acc[m][n], 0, 0, 0);
            }
    }

    // ---- dot phase: per (m,j) row, 5 partial dots over this wave's 64 cols
    #pragma unroll
    for (int m = 0; m < 4; ++m) {
        #pragma unroll
        for (int j = 0; j < 4; ++j) {
            int rl = m * 16 + kg * 4 + j;
            int r  = brow + rl;
            float p0 = 0.f, p1 = 0.f, p2 = 0.f, p3 = 0.f, p4 = 0.f;
            if (r < N) {
                #pragma unroll
                for (int n = 0; n < 4; ++n) {
                    int c = wc + n * 16 + lrow;
                    float v = acc[m][n][j] + pb[c];
                    int ab = (rl * 512 + c * 2) ^ ((rl & 7) << 4);
                    float f0 = b2f(*(const u16*)(smem + ab))
                             + b2f(*(const u16*)(smem + 32768 + ab));
                    size_t fo = (size_t)r * 256 + c;
                    p0 += v * f0;
                    p1 += v * b2f2(F1h[fo], F1l[fo]);
                    p2 += v * b2f2(F2h[fo], F2l[fo]);
                    p3 += v * b2f2(F3h[fo], F3l[fo]);
                    p4 += v * b2f2(F4h[fo], F4l[fo]);
                }
            }
            #pragma unroll
            for (int d = 1; d < 16; d <<= 1) {
                p0 += __shfl_xor(p0, d, 64);
                p1 += __shfl_xor(p1, d, 64);
                p2 += __shfl_xor(p2, d, 64);
                p3 += __shfl_xor(p3, d, 64);
                p4 += __shfl_xor(p4, d, 64);
            }
            if (lrow == 0) {
                sred[wave][rl][0] = p0; sred[wave][rl][1] = p1;
                sred[wave][rl][2] = p2; sred[wave][rl][3] = p3;
                sred[wave][rl][4] = p4;
            }
        }
    }
    __syncthreads();

    // ---- softmax per row (threads 0..63) ----
    if (tid < 64) {
        float s[5];
        #pragma unroll
        for (int k = 0; k < 5; ++k)
            s[k] = sred[0][tid][k] + sred[1][tid][k] + sred[2][tid][k] + sred[3][tid][k];
        float mx = fmaxf(fmaxf(fmaxf(s[0], s[1]), fmaxf(s[2], s[3])), s[4]);
        float sum = 0.f;
        #pragma unroll
        for (int k = 0; k < 5; ++k) { s[k] = expf(s[k] - mx); sum += s[k]; }
        float inv = 1.f / sum;
        #pragma unroll
        for (int k = 0; k < 5; ++k) w5[tid][k] = s[k] * inv;
    }
    __syncthreads();

    // ---- combine phase ----
    #pragma unroll
    for (int m = 0; m < 4; ++m) {
        #pragma unroll
        for (int j = 0; j < 4; ++j) {
            int rl = m * 16 + kg * 4 + j;
            int r  = brow + rl;
            if (r >= N) continue;
            float w0 = w5[rl][0], w1 = w5[rl][1], w2 = w5[rl][2],
                  w3 = w5[rl][3], w4 = w5[rl][4];
            #pragma unroll
            for (int n = 0; n < 4; ++n) {
                int c = wc + n * 16 + lrow;
                int ab = (rl * 512 + c * 2) ^ ((rl & 7) << 4);
                float f0 = b2f(*(const u16*)(smem + ab))
                         + b2f(*(const u16*)(smem + 32768 + ab));
                size_t fo = (size_t)r * 256 + c;
                float res = w0 * f0
                          + w1 * b2f2(F1h[fo], F1l[fo])
                          + w2 * b2f2(F2h[fo], F2l[fo])
                          + w3 * b2f2(F3h[fo], F3l[fo])
                          + w4 * b2f2(F4h[fo], F4l[fo]);
                u16 h = f2b(res);
                Oh[fo] = h;
                Ol[fo] = f2b(res - b2f(h));
            }
        }
    }
}

// ------------- CSR build ---------------------------------------------------
__global__ __launch_bounds__(256) void count_kernel(
    const int* __restrict__ rows, int* __restrict__ cnt, int E)
{
    int e = blockIdx.x * 256 + threadIdx.x;
    if (e < E) atomicAdd(&cnt[rows[e]], 1);
}

__global__ __launch_bounds__(1024) void scan_kernel(
    const int* __restrict__ cnt, int* __restrict__ off, int N)
{
    __shared__ int part[1024];
    const int t = threadIdx.x;
    const int chunk = (N + 1023) / 1024;
    const int lo = t * chunk;
    const int hi = min(lo + chunk, N);
    int s = 0;
    for (int i = lo; i < hi; ++i) s += cnt[i];
    part[t] = s;
    __syncthreads();
    for (int d = 1; d < 1024; d <<= 1) {
        int u = (t >= d) ? part[t - d] : 0;
        __syncthreads();
        part[t] += u;
        __syncthreads();
    }
    int running = part[t] - s;
    for (int i = lo; i < hi; ++i) { off[i] = running; running += cnt[i]; }
    if (t == 1023) off[N] = part[1023];
}

__global__ __launch_bounds__(256) void scatter_kernel(
    const int* __restrict__ rows, const int* __restrict__ cols,
    const float* __restrict__ vals, const int* __restrict__ off,
    int* __restrict__ cur, int* __restrict__ scol, float* __restrict__ sval,
    int E)
{
    int e = blockIdx.x * 256 + threadIdx.x;
    if (e >= E) return;
    int r = rows[e];
    int p = off[r] + atomicAdd(&cur[r], 1);
    scol[p] = cols[e];
    sval[p] = vals[e];
}

// ------------- SpMM: gather split (f32-exact), split store -----------------
__global__ __launch_bounds__(256) void spmm_csr_kernel(
    const int* __restrict__ off, const int* __restrict__ scol,
    const float* __restrict__ sval,
    const u16* __restrict__ Xh, const u16* __restrict__ Xl,
    u16* __restrict__ Yh, u16* __restrict__ Yl, int N)
{
    int r = blockIdx.x * 4 + (threadIdx.x >> 6);
    if (r >= N) return;
    int lane = threadIdx.x & 63;
    int e0 = off[r], e1 = off[r + 1];
    float a0 = 0.f, a1 = 0.f, a2 = 0.f, a3 = 0.f;
    for (int e = e0; e < e1; ++e) {
        int c = scol[e]; float v = sval[e];
        size_t xo = (size_t)c * DO + lane * 4;
        ushort4 xh = *(const ushort4*)&Xh[xo];
        ushort4 xl = *(const ushort4*)&Xl[xo];
        a0 = fmaf(v, b2f2(xh.x, xl.x), a0); a1 = fmaf(v, b2f2(xh.y, xl.y), a1);
        a2 = fmaf(v, b2f2(xh.z, xl.z), a2); a3 = fmaf(v, b2f2(xh.w, xl.w), a3);
    }
    size_t o = (size_t)r * DO + lane * 4;
    ushort4 h, l;
    h.x = f2b(a0); l.x = f2b(a0 - b2f(h.x));
    h.y = f2b(a1); l.y = f2b(a1 - b2f(h.y));
    h.z = f2b(a2); l.z = f2b(a2 - b2f(h.z));
    h.w = f2b(a3); l.w = f2b(a3 - b2f(h.w));
    *(ushort4*)&Yh[o] = h;
    *(ushort4*)&Yl[o] = l;
}

__global__ __launch_bounds__(256) void spmm_csr_dual_kernel(
    const int* __restrict__ off, const int* __restrict__ scol,
    const float* __restrict__ sval,
    const u16* __restrict__ X1h, const u16* __restrict__ X1l,
    const u16* __restrict__ X2h, const u16* __restrict__ X2l,
    u16* __restrict__ Y1h, u16* __restrict__ Y1l,
    u16* __restrict__ Y2h, u16* __restrict__ Y2l, int N)
{
    int r = blockIdx.x * 4 + (threadIdx.x >> 6);
    if (r >= N) return;
    int lane = threadIdx.x & 63;
    int e0 = off[r], e1 = off[r + 1];
    float a0 = 0.f, a1 = 0.f, a2 = 0.f, a3 = 0.f;
    float b0 = 0.f, b1 = 0.f, b2 = 0.f, b3 = 0.f;
    for (int e = e0; e < e1; ++e) {
        int c = scol[e]; float v = sval[e];
        size_t xo = (size_t)c * DO + lane * 4;
        ushort4 x1h = *(const ushort4*)&X1h[xo];
        ushort4 x1l = *(const ushort4*)&X1l[xo];
        ushort4 x2h = *(const ushort4*)&X2h[xo];
        ushort4 x2l = *(const ushort4*)&X2l[xo];
        a0 = fmaf(v, b2f2(x1h.x, x1l.x), a0); a1 = fmaf(v, b2f2(x1h.y, x1l.y), a1);
        a2 = fmaf(v, b2f2(x1h.z, x1l.z), a2); a3 = fmaf(v, b2f2(x1h.w, x1l.w), a3);
        b0 = fmaf(v, b2f2(x2h.x, x2l.x), b0); b1 = fmaf(v, b2f2(x2h.y, x2l.y), b1);
        b2 = fmaf(v, b2f2(x2h.z, x2l.z), b2); b3 = fmaf(v, b2f2(x2h.w, x2l.w), b3);
    }
    size_t o = (size_t)r * DO + lane * 4;
    ushort4 h, l;
    h.x = f2b(a0); l.x = f2b(a0 - b2f(h.x));
    h.y = f2b(a1); l.y = f2b(a1 - b2f(h.y));
    h.z = f2b(a2); l.z = f2b(a2 - b2f(h.z));
    h.w = f2b(a3); l.w = f2b(a3 - b2f(h.w));
    *(ushort4*)&Y1h[o] = h; *(ushort4*)&Y1l[o] = l;
    h.x = f2b(b0); l.x = f2b(b0 - b2f(h.x));
    h.y = f2b(b1); l.y = f2b(b1 - b2f(h.y));
    h.z = f2b(b2); l.z = f2b(b2 - b2f(h.z));
    h.w = f2b(b3); l.w = f2b(b3 - b2f(h.w));
    *(ushort4*)&Y2h[o] = h; *(ushort4*)&Y2l[o] = l;
}

extern "C" void kernel_launch(void* const* d_in, const int* in_sizes, int n_in,
                              void* d_out, int out_size, void* d_ws, size_t ws_size,
                              hipStream_t stream)
{
    const float* features      = (const float*)d_in[0];
    const float* edge_features = (const float*)d_in[1];
    const int*   adj_idx[4] = {(const int*)d_in[2], (const int*)d_in[4],
                               (const int*)d_in[6], (const int*)d_in[8]};
    const float* adj_val[4] = {(const float*)d_in[3], (const float*)d_in[5],
                               (const float*)d_in[7], (const float*)d_in[9]};
    const int E[4] = {in_sizes[3], in_sizes[5], in_sizes[7], in_sizes[9]};
    const int Emax = max(max(E[0], E[1]), max(E[2], E[3]));

    const float* ft_W = (const float*)d_in[10]; const float* ft_b = (const float*)d_in[11];
    const float* fo_W1 = (const float*)d_in[12]; const float* fo_b1 = (const float*)d_in[13];
    const float* fo_W2 = (const float*)d_in[14]; const float* fo_b2 = (const float*)d_in[15];
    const float* em_W1 = (const float*)d_in[16]; const float* em_b1 = (const float*)d_in[17];
    const float* em_W2 = (const float*)d_in[18]; const float* em_b2 = (const float*)d_in[19];
    const float* so_W1 = (const float*)d_in[20]; const float* so_b1 = (const float*)d_in[21];
    const float* so_W2 = (const float*)d_in[22]; const float* so_b2 = (const float*)d_in[23];
    const float* to_W1 = (const float*)d_in[24]; const float* to_b1 = (const float*)d_in[25];
    const float* to_W2 = (const float*)d_in[26]; const float* to_b2 = (const float*)d_in[27];
    const float* qo_W1 = (const float*)d_in[28]; const float* qo_b1 = (const float*)d_in[29];
    const float* qo_W2 = (const float*)d_in[30]; const float* qo_b2 = (const float*)d_in[31];
    const float* m_W1  = (const float*)d_in[32]; const float* m_b1  = (const float*)d_in[33];
    const float* m_W2  = (const float*)d_in[34]; const float* m_b2  = (const float*)d_in[35];
    const float* q_W   = (const float*)d_in[36]; const float* q_b   = (const float*)d_in[37];
    const float* k_W   = (const float*)d_in[38]; const float* k_b   = (const float*)d_in[39];
    (void)k_b;   // q.k_b is constant across the 5 scores -> softmax-invariant

    const int N = in_sizes[0] / 256;
    const size_t NS = (size_t)N * DO;

    // ---- workspace: CSR zone + 4 split slots + packed WT (~219MB) ---------
    char* base = (char*)d_ws;
    size_t o = 0;
    auto take = [&](size_t bytes) { char* p = base + o; o += (bytes + 63) & ~(size_t)63; return p; };
    const int NP = (N + 64) & ~63;
    int*   cnt  = (int*)take((size_t)(3 * NP + 64) * 4);   // cnt|cur|off
    int*   scol = (int*)take((size_t)Emax * 4);
    float* sval = (float*)take((size_t)Emax * 4);
    u16* B1 = (u16*)take(NS * 4);      // Fin -> agg1/fo -> combined
    u16* B2 = (u16*)take(NS * 4);      // Ein -> aggef -> agg2/so
    u16* B3 = (u16*)take(NS * 4);      // ef -> agg3/to
    u16* B4 = (u16*)take(NS * 4);      // F split (live to combine)
    const size_t WSQ = 65536;
    u16* WTh = (u16*)take(14 * WSQ * 2);   // 13 weights + P (slot 13), packed
    u16* WTl = (u16*)take(14 * WSQ * 2);
    float* pb = (float*)take(256 * 4);
    if (o > ws_size) return;           // graceful guard

    int* cur = cnt + NP;
    int* off = cnt + 2 * NP;
    u16 *B1h = B1, *B1l = B1 + NS;
    u16 *B2h = B2, *B2l = B2 + NS;
    u16 *B3h = B3, *B3l = B3 + NS;
    u16 *Fh  = B4, *Fl  = B4 + NS;
    u16 *OTh = (u16*)d_out, *OTl = (u16*)d_out + NS;   // agg4/qo split slot

    u16 *wh[14], *wl[14];
    for (int i = 0; i < 14; ++i) { wh[i] = WTh + (size_t)i * WSQ; wl[i] = WTl + (size_t)i * WSQ; }

    dim3 blk(256);
    {   // weights: transpose + split + pack (13 square weights)
        WPack p;
        const float* src[13] = {ft_W, fo_W1, fo_W2, em_W1, em_W2, so_W1, so_W2,
                                to_W1, to_W2, qo_W1, qo_W2, m_W1, m_W2};
        for (int i = 0; i < 13; ++i) {
            p.w[i].src = src[i]; p.w[i].hi = wh[i]; p.w[i].lo = wl[i];
        }
        hipLaunchKernelGGL(transpose_w_kernel, dim3(256, 13), blk, 0, stream, p);
    }
    // P = qW @ kW^T (packed, slot 13); pb = q_b @ kW^T
    hipLaunchKernelGGL(build_p_kernel, dim3(256), blk, 0, stream, q_W, k_W, wh[13], wl[13]);
    hipLaunchKernelGGL(build_pb_kernel, dim3(1), blk, 0, stream, q_b, k_W, pb);
    {   // inputs -> split bf16
        int n4 = (int)(NS / 4);
        dim3 g((n4 + 255) / 256);
        hipLaunchKernelGGL(convert_split_kernel, g, blk, 0, stream, features, B1h, B1l, n4);
        hipLaunchKernelGGL(convert_split_kernel, g, blk, 0, stream, edge_features, B2h, B2l, n4);
    }

    dim3 ggrd((N + 63) / 64);
    auto mlp = [&](const u16* ah, const u16* al, int w1, const float* bb1,
                   int w2, const float* bb2, const u16* adh, const u16* adl,
                   u16* ch, u16* cl, float* cf) {
        hipLaunchKernelGGL((gemm_tile_kernel<true>), ggrd, blk, 0, stream,
                           ah, al, wh[w1], wl[w1], bb1, wh[w2], wl[w2], bb2,
                           adh, adl, ch, cl, cf, N);
    };
    auto gemm1 = [&](const u16* ah, const u16* al, int w, const float* bb,
                     u16* ch, u16* cl, float* cf) {
        hipLaunchKernelGGL((gemm_tile_kernel<false>), ggrd, blk, 0, stream,
                           ah, al, wh[w], wl[w], bb, nullptr, nullptr, nullptr,
                           nullptr, nullptr, ch, cl, cf, N);
    };
    auto build_csr = [&](int i) {
        int Ei = E[i];
        hipMemsetAsync(cnt, 0, (size_t)N * sizeof(int), stream);
        hipMemsetAsync(cur, 0, (size_t)N * sizeof(int), stream);
        dim3 egrd((Ei + 255) / 256);
        hipLaunchKernelGGL(count_kernel, egrd, blk, 0, stream, adj_idx[i], cnt, Ei);
        hipLaunchKernelGGL(scan_kernel, dim3(1), dim3(1024), 0, stream, cnt, off, N);
        hipLaunchKernelGGL(scatter_kernel, egrd, blk, 0, stream,
                           adj_idx[i], adj_idx[i] + Ei, adj_val[i], off, cur, scol, sval, Ei);
    };
    dim3 rgrd((N + 3) / 4);
    auto spmm = [&](const u16* xh, const u16* xl, u16* yh, u16* yl) {
        hipLaunchKernelGGL(spmm_csr_kernel, rgrd, blk, 0, stream,
                           off, scol, sval, xh, xl, yh, yl, N);
    };

    // 1. F = features @ ft_W + ft_b -> B4 split
    gemm1(B1h, B1l, 0, ft_b, Fh, Fl, nullptr);
    // 2. ef = MLP2(edge_features, em) -> B3 split
    mlp(B2h, B2l, 3, em_b1, 4, em_b2, nullptr, nullptr, B3h, B3l, nullptr);
    // 3. adj1: agg1 -> B1 (Fin dead), aggef -> B2 (Ein dead)
    build_csr(0);
    hipLaunchKernelGGL(spmm_csr_dual_kernel, rgrd, blk, 0, stream,
                       off, scol, sval, Fh, Fl, B3h, B3l, B1h, B1l, B2h, B2l, N);
    // 4. fo = MLP2(agg1) + aggef -> B1
    mlp(B1h, B1l, 1, fo_b1, 2, fo_b2, B2h, B2l, B1h, B1l, nullptr);
    // 5. so = MLP2(agg2) + agg2 -> B2 (aggef dead)
    build_csr(1); spmm(Fh, Fl, B2h, B2l);
    mlp(B2h, B2l, 5, so_b1, 6, so_b2, B2h, B2l, B2h, B2l, nullptr);
    // 6. to = MLP2(agg3) + agg3 -> B3 (ef dead)
    build_csr(2); spmm(Fh, Fl, B3h, B3l);
    mlp(B3h, B3l, 7, to_b1, 8, to_b2, B3h, B3l, B3h, B3l, nullptr);
    // 7. qo = MLP2(agg4) + agg4 -> d_out slot
    build_csr(3); spmm(Fh, Fl, OTh, OTl);
    mlp(OTh, OTl, 9, qo_b1, 10, qo_b2, OTh, OTl, OTh, OTl, nullptr);

    // 8. merged scores + softmax + combine -> B1 (in-place over fo)
    hipLaunchKernelGGL(score_combine_kernel, ggrd, blk, 0, stream,
                       Fh, Fl, wh[13], wl[13], pb,
                       B1h, B1l, B2h, B2l, B3h, B3l, OTh, OTl,
                       B1h, B1l, N);
    // 9. out = MLP2(combined, m) -> f32 d_out (qo dead)
    mlp(B1h, B1l, 11, m_b1, 12, m_b2, nullptr, nullptr, nullptr, nullptr, (float*)d_out);
}

// Round 11
// 1439.157 us; speedup vs baseline: 10.3489x; 1.5060x over previous
//
#include <hip/hip_runtime.h>

// HigherOrderGINLayer — round 11: all-fp16 storage (ulp = bf16/8), single-term
// f16 MFMA, qk kept f32-in-register (merged score+combine), merged 4-way CSR
// build. Replaces split-bf16 (2x bytes, 3-5 MFMA terms) everywhere.
// Error model: round-4 all-bf16 = 0.476 -> all-fp16 ~ 0.476/8 ~ 0.06.

#define DO 256

typedef unsigned short u16;
typedef _Float16 f16;
typedef __attribute__((ext_vector_type(8))) _Float16 f16x8;
typedef __attribute__((ext_vector_type(4))) _Float16 f16x4;
typedef __attribute__((ext_vector_type(4))) float f32x4;

// Packed weight layout (per 256x256 weight, 65536 elems):
//   idx = ((frag*8 + ks)*64 + lane)*8 + e
//   col c = frag*16 + (lane&15),  k = ks*32 + (lane>>4)*8 + e
// Wave w, fragment n, k-step ks loads 16B/lane coalesced at
//   ((w*4+n)*8 + ks)*512 + lane*8.

// ------------- weights: transpose + fp16 + pack ----------------------------
struct WDesc { const float* src; f16* dst; };
struct WPack { WDesc w[13]; };

__global__ __launch_bounds__(256) void transpose_w_kernel(WPack p) {
    WDesc d = p.w[blockIdx.y];
    int idx = blockIdx.x * 256 + threadIdx.x;        // 0..65535
    int e  = idx & 7;
    int l  = (idx >> 3) & 63;
    int ks = (idx >> 9) & 7;
    int f  = idx >> 12;
    int c  = (f << 4) | (l & 15);
    int k  = ks * 32 + ((l >> 4) << 3) + e;
    d.dst[idx] = (f16)d.src[k * 256 + c];
}

// P[c][k] = sum_p qW[k,p]*kW[c,p] (score fold), packed fp16
__global__ __launch_bounds__(256) void build_p_kernel(
    const float* __restrict__ qW, const float* __restrict__ kW,
    f16* __restrict__ pdst)
{
    int idx = blockIdx.x * 256 + threadIdx.x;        // 65536
    int e  = idx & 7;
    int l  = (idx >> 3) & 63;
    int ks = (idx >> 9) & 7;
    int f  = idx >> 12;
    int c  = (f << 4) | (l & 15);
    int k  = ks * 32 + ((l >> 4) << 3) + e;
    float s = 0.f;
    #pragma unroll 8
    for (int p = 0; p < 128; ++p) s += qW[k * 128 + p] * kW[c * 128 + p];
    pdst[idx] = (f16)s;
}

// pb[c] = sum_p q_b[p] * kW[c,p]
__global__ __launch_bounds__(256) void build_pb_kernel(
    const float* __restrict__ qb, const float* __restrict__ kW,
    float* __restrict__ pb)
{
    int c = threadIdx.x;
    float s = 0.f;
    #pragma unroll 8
    for (int p = 0; p < 128; ++p) s += qb[p] * kW[c * 128 + p];
    pb[c] = s;
}

// ------------- f32 -> fp16 -------------------------------------------------
__global__ __launch_bounds__(256) void convert_kernel(
    const float* __restrict__ src, f16* __restrict__ dst, int n4)
{
    int i = blockIdx.x * 256 + threadIdx.x;
    if (i >= n4) return;
    float4 v = *(const float4*)&src[i * 4];
    f16x4 o = {(f16)v.x, (f16)v.y, (f16)v.z, (f16)v.w};
    *(f16x4*)&dst[i * 4] = o;
}

// ------------- LDS-staged fp16 GEMM / fused MLP ----------------------------
// 256 thr = 4 waves, 64 rows x 256 cols; A staged in 32KB LDS (XOR swz).
// FUSED: relu(acc+b1) -> H in LDS -> GEMM2 + b2 (+add). Out: f16 or f32.
template<bool FUSED>
__global__ __launch_bounds__(256) void gemm_tile_kernel(
    const f16* __restrict__ A,
    const f16* __restrict__ W1, const float* __restrict__ b1,
    const f16* __restrict__ W2, const float* __restrict__ b2,
    const f16* __restrict__ Ad,
    f16* __restrict__ Ch, float* __restrict__ Cf, int N)
{
    __shared__ char smem[32768];          // A, then H (fused)

    const int tid  = threadIdx.x;
    const int wave = tid >> 6, lane = tid & 63;
    const int lrow = lane & 15, kg = lane >> 4;
    const int wc   = wave * 64;
    const int brow = blockIdx.x * 64;

    // ---- stage A (64 rows x 256 k fp16 = 32KB) into LDS, swizzled ----
    #pragma unroll
    for (int j = 0; j < 8; ++j) {
        int i = tid + j * 256;            // 16B chunk 0..2047
        int row = i >> 5, slot = i & 31;
        int srow = brow + row; srow = srow < N ? srow : N - 1;
        f16x8 v = *(const f16x8*)&A[(size_t)srow * 256 + slot * 8];
        int db = (row * 512 + slot * 16) ^ ((row & 7) << 4);
        *(f16x8*)(smem + db) = v;
    }
    __syncthreads();

    // ---- GEMM1 ----
    f32x4 acc[4][4] = {};
    #pragma unroll
    for (int ks = 0; ks < 8; ++ks) {
        f16x8 ah[4], bh[4];
        #pragma unroll
        for (int m = 0; m < 4; ++m) {
            int ab = ((m * 16 + lrow) * 512 + (ks * 4 + kg) * 16) ^ ((lrow & 7) << 4);
            ah[m] = *(const f16x8*)(smem + ab);
        }
        #pragma unroll
        for (int n = 0; n < 4; ++n)
            bh[n] = *(const f16x8*)&W1[(size_t)(((wave * 4 + n) * 8 + ks) << 9) + (lane << 3)];
        #pragma unroll
        for (int m = 0; m < 4; ++m)
            #pragma unroll
            for (int n = 0; n < 4; ++n)
                acc[m][n] = __builtin_amdgcn_mfma_f32_16x16x32_f16(
                                ah[m], bh[n], acc[m][n], 0, 0, 0);
    }

    if (!FUSED) {
        #pragma unroll
        for (int n = 0; n < 4; ++n) {
            int c = wc + n * 16 + lrow;
            float bv = b1[c];
            #pragma unroll
            for (int m = 0; m < 4; ++m)
                #pragma unroll
                for (int j = 0; j < 4; ++j) {
                    int r = brow + m * 16 + kg * 4 + j;
                    if (r >= N) continue;
                    size_t o = (size_t)r * 256 + c;
                    float v = acc[m][n][j] + bv;
                    if (Cf) Cf[o] = v;
                    else    Ch[o] = (f16)v;
                }
        }
        return;
    }

    // ---- fused: H = relu(acc + b1) -> LDS (swizzled) ----
    __syncthreads();
    #pragma unroll
    for (int n = 0; n < 4; ++n) {
        int c = wc + n * 16 + lrow;
        float bv = b1[c];
        #pragma unroll
        for (int m = 0; m < 4; ++m)
            #pragma unroll
            for (int j = 0; j < 4; ++j) {
                int rl = m * 16 + kg * 4 + j;
                float v = fmaxf(acc[m][n][j] + bv, 0.f);
                int hb = (rl * 512 + c * 2) ^ ((rl & 7) << 4);
                *(f16*)(smem + hb) = (f16)v;
            }
    }
    __syncthreads();

    // ---- GEMM2 ----
    #pragma unroll
    for (int m = 0; m < 4; ++m)
        #pragma unroll
        for (int n = 0; n < 4; ++n)
            acc[m][n] = f32x4{0.f, 0.f, 0.f, 0.f};
    #pragma unroll
    for (int ks = 0; ks < 8; ++ks) {
        f16x8 ah[4], bh[4];
        #pragma unroll
        for (int m = 0; m < 4; ++m) {
            int ab = ((m * 16 + lrow) * 512 + (ks * 4 + kg) * 16) ^ ((lrow & 7) << 4);
            ah[m] = *(const f16x8*)(smem + ab);
        }
        #pragma unroll
        for (int n = 0; n < 4; ++n)
            bh[n] = *(const f16x8*)&W2[(size_t)(((wave * 4 + n) * 8 + ks) << 9) + (lane << 3)];
        #pragma unroll
        for (int m = 0; m < 4; ++m)
            #pragma unroll
            for (int n = 0; n < 4; ++n)
                acc[m][n] = __builtin_amdgcn_mfma_f32_16x16x32_f16(
                                ah[m], bh[n], acc[m][n], 0, 0, 0);
    }

    #pragma unroll
    for (int n = 0; n < 4; ++n) {
        int c = wc + n * 16 + lrow;
        float bv = b2[c];
        #pragma unroll
        for (int m = 0; m < 4; ++m)
            #pragma unroll
            for (int j = 0; j < 4; ++j) {
                int r = brow + m * 16 + kg * 4 + j;
                if (r >= N) continue;
                size_t o = (size_t)r * 256 + c;
                float v = acc[m][n][j] + bv;
                if (Ad) v += (float)Ad[o];
                if (Cf) Cf[o] = v;
                else    Ch[o] = (f16)v;
            }
    }
}

// ------------- merged scores + softmax + combine ---------------------------
// qk = F@P + pb computed in-register (f32); 5 dots (f0 from LDS, f1..4
// global fp16) -> LDS cross-wave reduce -> softmax -> weighted combine.
__global__ __launch_bounds__(256) void score_combine_kernel(
    const f16* __restrict__ F, const f16* __restrict__ P,
    const float* __restrict__ pb,
    const f16* __restrict__ F1, const f16* __restrict__ F2,
    const f16* __restrict__ F3, const f16* __restrict__ F4,
    f16* __restrict__ O, int N)
{
    __shared__ char smem[32768];
    __shared__ float sred[4][64][5];
    __shared__ float w5[64][5];

    const int tid  = threadIdx.x;
    const int wave = tid >> 6, lane = tid & 63;
    const int lrow = lane & 15, kg = lane >> 4;
    const int wc   = wave * 64;
    const int brow = blockIdx.x * 64;

    #pragma unroll
    for (int j = 0; j < 8; ++j) {
        int i = tid + j * 256;
        int row = i >> 5, slot = i & 31;
        int srow = brow + row; srow = srow < N ? srow : N - 1;
        f16x8 v = *(const f16x8*)&F[(size_t)srow * 256 + slot * 8];
        int db = (row * 512 + slot * 16) ^ ((row & 7) << 4);
        *(f16x8*)(smem + db) = v;
    }
    __syncthreads();

    f32x4 acc[4][4] = {};
    #pragma unroll
    for (int ks = 0; ks < 8; ++ks) {
        f16x8 ah[4], bh[4];
        #pragma unroll
        for (int m = 0; m < 4; ++m) {
            int ab = ((m * 16 + lrow) * 512 + (ks * 4 + kg) * 16) ^ ((lrow & 7) << 4);
            ah[m] = *(const f16x8*)(smem + ab);
        }
        #pragma unroll
        for (int n = 0; n < 4; ++n)
            bh[n] = *(const f16x8*)&P[(size_t)(((wave * 4 + n) * 8 + ks) << 9) + (lane << 3)];
        #pragma unroll
        for (int m = 0; m < 4; ++m)
            #pragma unroll
            for (int n = 0; n < 4; ++n)
                acc[m][n] = __builtin_amdgcn_mfma_f32_16x16x32_f16(
                                ah[m], bh[n], acc[m][n], 0, 0, 0);
    }

    // ---- dot phase ----
    #pragma unroll
    for (int m = 0; m < 4; ++m) {
        #pragma unroll
        for (int j = 0; j < 4; ++j) {
            int rl = m * 16 + kg * 4 + j;
            int r  = brow + rl;
            float p0 = 0.f, p1 = 0.f, p2 = 0.f, p3 = 0.f, p4 = 0.f;
            if (r < N) {
                #pragma unroll
                for (int n = 0; n < 4; ++n) {
                    int c = wc + n * 16 + lrow;
                    float v = acc[m][n][j] + pb[c];
                    int ab = (rl * 512 + c * 2) ^ ((rl & 7) << 4);
                    float f0 = (float)*(const f16*)(smem + ab);
                    size_t fo = (size_t)r * 256 + c;
                    p0 += v * f0;
                    p1 += v * (float)F1[fo];
                    p2 += v * (float)F2[fo];
                    p3 += v * (float)F3[fo];
                    p4 += v * (float)F4[fo];
                }
            }
            #pragma unroll
            for (int d = 1; d < 16; d <<= 1) {
                p0 += __shfl_xor(p0, d, 64);
                p1 += __shfl_xor(p1, d, 64);
                p2 += __shfl_xor(p2, d, 64);
                p3 += __shfl_xor(p3, d, 64);
                p4 += __shfl_xor(p4, d, 64);
            }
            if (lrow == 0) {
                sred[wave][rl][0] = p0; sred[wave][rl][1] = p1;
                sred[wave][rl][2] = p2; sred[wave][rl][3] = p3;
                sred[wave][rl][4] = p4;
            }
        }
    }
    __syncthreads();

    if (tid < 64) {
        float s[5];
        #pragma unroll
        for (int k = 0; k < 5; ++k)
            s[k] = sred[0][tid][k] + sred[1][tid][k] + sred[2][tid][k] + sred[3][tid][k];
        float mx = fmaxf(fmaxf(fmaxf(s[0], s[1]), fmaxf(s[2], s[3])), s[4]);
        float sum = 0.f;
        #pragma unroll
        for (int k = 0; k < 5; ++k) { s[k] = expf(s[k] - mx); sum += s[k]; }
        float inv = 1.f / sum;
        #pragma unroll
        for (int k = 0; k < 5; ++k) w5[tid][k] = s[k] * inv;
    }
    __syncthreads();

    // ---- combine ----
    #pragma unroll
    for (int m = 0; m < 4; ++m) {
        #pragma unroll
        for (int j = 0; j < 4; ++j) {
            int rl = m * 16 + kg * 4 + j;
            int r  = brow + rl;
            if (r >= N) continue;
            float w0 = w5[rl][0], w1 = w5[rl][1], w2 = w5[rl][2],
                  w3 = w5[rl][3], w4 = w5[rl][4];
            #pragma unroll
            for (int n = 0; n < 4; ++n) {
                int c = wc + n * 16 + lrow;
                int ab = (rl * 512 + c * 2) ^ ((rl & 7) << 4);
                float f0 = (float)*(const f16*)(smem + ab);
                size_t fo = (size_t)r * 256 + c;
                float res = w0 * f0
                          + w1 * (float)F1[fo]
                          + w2 * (float)F2[fo]
                          + w3 * (float)F3[fo]
                          + w4 * (float)F4[fo];
                O[fo] = (f16)res;
            }
        }
    }
}

// ------------- merged CSR build (4 adjacencies) ----------------------------
struct CsrSrc { const int* rows[4]; const int* cols[4]; const float* vals[4]; int E[4]; };

__global__ __launch_bounds__(256) void count4_kernel(CsrSrc s, int* __restrict__ cnt, int NPo) {
    int a = blockIdx.y;
    int e = blockIdx.x * 256 + threadIdx.x;
    if (e < s.E[a]) atomicAdd(&cnt[(size_t)a * NPo + s.rows[a][e]], 1);
}

__global__ __launch_bounds__(1024) void scan4_kernel(
    const int* __restrict__ cnt0, int* __restrict__ off0, int N, int NPo)
{
    const int* cnt = cnt0 + (size_t)blockIdx.x * NPo;
    int* off = off0 + (size_t)blockIdx.x * NPo;
    __shared__ int part[1024];
    const int t = threadIdx.x;
    const int chunk = (N + 1023) / 1024;
    const int lo = t * chunk;
    const int hi = min(lo + chunk, N);
    int s = 0;
    for (int i = lo; i < hi; ++i) s += cnt[i];
    part[t] = s;
    __syncthreads();
    for (int d = 1; d < 1024; d <<= 1) {
        int u = (t >= d) ? part[t - d] : 0;
        __syncthreads();
        part[t] += u;
        __syncthreads();
    }
    int running = part[t] - s;
    for (int i = lo; i < hi; ++i) { off[i] = running; running += cnt[i]; }
    if (t == 1023) off[N] = part[1023];
}

__global__ __launch_bounds__(256) void scatter4_kernel(
    CsrSrc s, const int* __restrict__ off, int* __restrict__ cur,
    int* __restrict__ scol, float* __restrict__ sval, int NPo, int Emax)
{
    int a = blockIdx.y;
    int e = blockIdx.x * 256 + threadIdx.x;
    if (e >= s.E[a]) return;
    int r = s.rows[a][e];
    int p = off[(size_t)a * NPo + r] + atomicAdd(&cur[(size_t)a * NPo + r], 1);
    scol[(size_t)a * Emax + p] = s.cols[a][e];
    sval[(size_t)a * Emax + p] = s.vals[a][e];
}

// ------------- SpMM: gather fp16, f32 accumulate, fp16 store ---------------
__global__ __launch_bounds__(256) void spmm_csr_kernel(
    const int* __restrict__ off, const int* __restrict__ scol,
    const float* __restrict__ sval, const f16* __restrict__ X,
    f16* __restrict__ Y, int N)
{
    int r = blockIdx.x * 4 + (threadIdx.x >> 6);
    if (r >= N) return;
    int lane = threadIdx.x & 63;
    int e0 = off[r], e1 = off[r + 1];
    float a0 = 0.f, a1 = 0.f, a2 = 0.f, a3 = 0.f;
    for (int e = e0; e < e1; ++e) {
        int c = scol[e]; float v = sval[e];
        f16x4 x = *(const f16x4*)&X[(size_t)c * DO + lane * 4];
        a0 = fmaf(v, (float)x[0], a0); a1 = fmaf(v, (float)x[1], a1);
        a2 = fmaf(v, (float)x[2], a2); a3 = fmaf(v, (float)x[3], a3);
    }
    f16x4 o = {(f16)a0, (f16)a1, (f16)a2, (f16)a3};
    *(f16x4*)&Y[(size_t)r * DO + lane * 4] = o;
}

__global__ __launch_bounds__(256) void spmm_csr_dual_kernel(
    const int* __restrict__ off, const int* __restrict__ scol,
    const float* __restrict__ sval,
    const f16* __restrict__ X1, const f16* __restrict__ X2,
    f16* __restrict__ Y1, f16* __restrict__ Y2, int N)
{
    int r = blockIdx.x * 4 + (threadIdx.x >> 6);
    if (r >= N) return;
    int lane = threadIdx.x & 63;
    int e0 = off[r], e1 = off[r + 1];
    float a0 = 0.f, a1 = 0.f, a2 = 0.f, a3 = 0.f;
    float b0 = 0.f, b1 = 0.f, b2 = 0.f, b3 = 0.f;
    for (int e = e0; e < e1; ++e) {
        int c = scol[e]; float v = sval[e];
        size_t xo = (size_t)c * DO + lane * 4;
        f16x4 x1 = *(const f16x4*)&X1[xo];
        f16x4 x2 = *(const f16x4*)&X2[xo];
        a0 = fmaf(v, (float)x1[0], a0); a1 = fmaf(v, (float)x1[1], a1);
        a2 = fmaf(v, (float)x1[2], a2); a3 = fmaf(v, (float)x1[3], a3);
        b0 = fmaf(v, (float)x2[0], b0); b1 = fmaf(v, (float)x2[1], b1);
        b2 = fmaf(v, (float)x2[2], b2); b3 = fmaf(v, (float)x2[3], b3);
    }
    size_t o = (size_t)r * DO + lane * 4;
    f16x4 o1 = {(f16)a0, (f16)a1, (f16)a2, (f16)a3};
    f16x4 o2 = {(f16)b0, (f16)b1, (f16)b2, (f16)b3};
    *(f16x4*)&Y1[o] = o1;
    *(f16x4*)&Y2[o] = o2;
}

extern "C" void kernel_launch(void* const* d_in, const int* in_sizes, int n_in,
                              void* d_out, int out_size, void* d_ws, size_t ws_size,
                              hipStream_t stream)
{
    const float* features      = (const float*)d_in[0];
    const float* edge_features = (const float*)d_in[1];
    CsrSrc cs;
    for (int i = 0; i < 4; ++i) {
        const int* idx = (const int*)d_in[2 + 2 * i];
        cs.E[i]    = in_sizes[3 + 2 * i];
        cs.rows[i] = idx;
        cs.cols[i] = idx + cs.E[i];
        cs.vals[i] = (const float*)d_in[3 + 2 * i];
    }
    const int Emax = max(max(cs.E[0], cs.E[1]), max(cs.E[2], cs.E[3]));

    const float* ft_W = (const float*)d_in[10]; const float* ft_b = (const float*)d_in[11];
    const float* fo_W1 = (const float*)d_in[12]; const float* fo_b1 = (const float*)d_in[13];
    const float* fo_W2 = (const float*)d_in[14]; const float* fo_b2 = (const float*)d_in[15];
    const float* em_W1 = (const float*)d_in[16]; const float* em_b1 = (const float*)d_in[17];
    const float* em_W2 = (const float*)d_in[18]; const float* em_b2 = (const float*)d_in[19];
    const float* so_W1 = (const float*)d_in[20]; const float* so_b1 = (const float*)d_in[21];
    const float* so_W2 = (const float*)d_in[22]; const float* so_b2 = (const float*)d_in[23];
    const float* to_W1 = (const float*)d_in[24]; const float* to_b1 = (const float*)d_in[25];
    const float* to_W2 = (const float*)d_in[26]; const float* to_b2 = (const float*)d_in[27];
    const float* qo_W1 = (const float*)d_in[28]; const float* qo_b1 = (const float*)d_in[29];
    const float* qo_W2 = (const float*)d_in[30]; const float* qo_b2 = (const float*)d_in[31];
    const float* m_W1  = (const float*)d_in[32]; const float* m_b1  = (const float*)d_in[33];
    const float* m_W2  = (const float*)d_in[34]; const float* m_b2  = (const float*)d_in[35];
    const float* q_W   = (const float*)d_in[36]; const float* q_b   = (const float*)d_in[37];
    const float* k_W   = (const float*)d_in[38]; const float* k_b   = (const float*)d_in[39];
    (void)k_b;   // q.k_b constant across the 5 scores -> softmax-invariant

    const int N = in_sizes[0] / 256;
    const size_t NS = (size_t)N * DO;

    // ---- workspace (~133MB): CSR(4) + 4 fp16 slots + packed WT ------------
    char* base = (char*)d_ws;
    size_t o = 0;
    auto take = [&](size_t bytes) { char* p = base + o; o += (bytes + 63) & ~(size_t)63; return p; };
    const int NPo = (N + 64) & ~63;
    int*   cnt  = (int*)take((size_t)4 * NPo * 4);
    int*   cur  = (int*)take((size_t)4 * NPo * 4);
    int*   off  = (int*)take((size_t)4 * NPo * 4);
    int*   scol = (int*)take((size_t)4 * Emax * 4);
    float* sval = (float*)take((size_t)4 * Emax * 4);
    f16* B1 = (f16*)take(NS * 2);      // Fin -> agg1/fo -> combined
    f16* B2 = (f16*)take(NS * 2);      // Ein -> aggef -> agg2/so
    f16* B3 = (f16*)take(NS * 2);      // ef -> agg3/to
    f16* B4 = (f16*)take(NS * 2);      // F (live to combine)
    const size_t WSQ = 65536;
    f16* WT = (f16*)take(14 * WSQ * 2);    // 13 weights + P (slot 13), packed
    float* pb = (float*)take(256 * 4);
    if (o > ws_size) return;           // graceful guard

    f16* F  = B4;
    f16* OT = (f16*)d_out;             // agg4/qo fp16 slot (first NS*2 of d_out)

    f16* w[14];
    for (int i = 0; i < 14; ++i) w[i] = WT + (size_t)i * WSQ;

    dim3 blk(256);
    {   // weights: transpose + fp16 + pack
        WPack p;
        const float* src[13] = {ft_W, fo_W1, fo_W2, em_W1, em_W2, so_W1, so_W2,
                                to_W1, to_W2, qo_W1, qo_W2, m_W1, m_W2};
        for (int i = 0; i < 13; ++i) { p.w[i].src = src[i]; p.w[i].dst = w[i]; }
        hipLaunchKernelGGL(transpose_w_kernel, dim3(256, 13), blk, 0, stream, p);
    }
    hipLaunchKernelGGL(build_p_kernel, dim3(256), blk, 0, stream, q_W, k_W, w[13]);
    hipLaunchKernelGGL(build_pb_kernel, dim3(1), blk, 0, stream, q_b, k_W, pb);
    {   // inputs -> fp16
        int n4 = (int)(NS / 4);
        dim3 g((n4 + 255) / 256);
        hipLaunchKernelGGL(convert_kernel, g, blk, 0, stream, features, B1, n4);
        hipLaunchKernelGGL(convert_kernel, g, blk, 0, stream, edge_features, B2, n4);
    }
    {   // all 4 CSRs up front (3 dispatches)
        hipMemsetAsync(cnt, 0, (size_t)4 * NPo * 4, stream);
        hipMemsetAsync(cur, 0, (size_t)4 * NPo * 4, stream);
        dim3 egrd((Emax + 255) / 256, 4);
        hipLaunchKernelGGL(count4_kernel, egrd, blk, 0, stream, cs, cnt, NPo);
        hipLaunchKernelGGL(scan4_kernel, dim3(4), dim3(1024), 0, stream, cnt, off, N, NPo);
        hipLaunchKernelGGL(scatter4_kernel, egrd, blk, 0, stream, cs, off, cur, scol, sval, NPo, Emax);
    }

    dim3 ggrd((N + 63) / 64);
    auto mlp = [&](const f16* a, int w1, const float* bb1, int w2, const float* bb2,
                   const f16* ad, f16* ch, float* cf) {
        hipLaunchKernelGGL((gemm_tile_kernel<true>), ggrd, blk, 0, stream,
                           a, w[w1], bb1, w[w2], bb2, ad, ch, cf, N);
    };
    dim3 rgrd((N + 3) / 4);
    auto spmm = [&](int i, const f16* x, f16* y) {
        hipLaunchKernelGGL(spmm_csr_kernel, rgrd, blk, 0, stream,
                           off + (size_t)i * NPo, scol + (size_t)i * Emax,
                           sval + (size_t)i * Emax, x, y, N);
    };

    // 1. F = features @ ft_W + ft_b -> B4
    hipLaunchKernelGGL((gemm_tile_kernel<false>), ggrd, blk, 0, stream,
                       B1, w[0], ft_b, nullptr, nullptr, nullptr, F, nullptr, N);
    // 2. ef = MLP2(edge_features, em) -> B3
    mlp(B2, 3, em_b1, 4, em_b2, nullptr, B3, nullptr);
    // 3. adj1: agg1 -> B1 (Fin dead), aggef -> B2 (Ein dead)
    hipLaunchKernelGGL(spmm_csr_dual_kernel, rgrd, blk, 0, stream,
                       off, scol, sval, F, B3, B1, B2, N);
    // 4. fo = MLP2(agg1) + aggef -> B1
    mlp(B1, 1, fo_b1, 2, fo_b2, B2, B1, nullptr);
    // 5. so = MLP2(agg2) + agg2 -> B2 (aggef dead)
    spmm(1, F, B2);
    mlp(B2, 5, so_b1, 6, so_b2, B2, B2, nullptr);
    // 6. to = MLP2(agg3) + agg3 -> B3 (ef dead)
    spmm(2, F, B3);
    mlp(B3, 7, to_b1, 8, to_b2, B3, B3, nullptr);
    // 7. qo = MLP2(agg4) + agg4 -> d_out slot
    spmm(3, F, OT);
    mlp(OT, 9, qo_b1, 10, qo_b2, OT, OT, nullptr);

    // 8. merged scores + softmax + combine -> B1 (in-place over fo)
    hipLaunchKernelGGL(score_combine_kernel, ggrd, blk, 0, stream,
                       F, w[13], pb, B1, B2, B3, OT, B1, N);
    // 9. out = MLP2(combined, m) -> f32 d_out (qo dead)
    mlp(B1, 11, m_b1, 12, m_b2, nullptr, nullptr, (float*)d_out);
}

// Round 12
// 1193.677 us; speedup vs baseline: 12.4772x; 1.2056x over previous
//
#include <hip/hip_runtime.h>

// HigherOrderGINLayer — round 12: packed int2 CSR (halve scatter write-amp),
// all-4-spmm in one dispatch, fo/so/to/qo MLPs in one dispatch, f32->fp16
// conversion fused into ft/em staging. Numerics identical to round 11
// (absmax 0.0605). Round-11 profile: scatter4 204us (328MB writes), GEMM/spmm
// dispatches underfill (782 blocks vs 1280 slots) -> tail-dominated.

#define DO 256

typedef unsigned short u16;
typedef _Float16 f16;
typedef __attribute__((ext_vector_type(8))) _Float16 f16x8;
typedef __attribute__((ext_vector_type(4))) _Float16 f16x4;
typedef __attribute__((ext_vector_type(4))) float f32x4;

// Packed weight layout (per 256x256 weight): idx = ((frag*8+ks)*64+lane)*8+e
//   col c = frag*16+(lane&15), k = ks*32+(lane>>4)*8+e

// ------------- weights: transpose + fp16 + pack ----------------------------
struct WDesc { const float* src; f16* dst; };
struct WPack { WDesc w[13]; };

__global__ __launch_bounds__(256) void transpose_w_kernel(WPack p) {
    WDesc d = p.w[blockIdx.y];
    int idx = blockIdx.x * 256 + threadIdx.x;
    int e  = idx & 7;
    int l  = (idx >> 3) & 63;
    int ks = (idx >> 9) & 7;
    int f  = idx >> 12;
    int c  = (f << 4) | (l & 15);
    int k  = ks * 32 + ((l >> 4) << 3) + e;
    d.dst[idx] = (f16)d.src[k * 256 + c];
}

__global__ __launch_bounds__(256) void build_p_kernel(
    const float* __restrict__ qW, const float* __restrict__ kW,
    f16* __restrict__ pdst)
{
    int idx = blockIdx.x * 256 + threadIdx.x;
    int e  = idx & 7;
    int l  = (idx >> 3) & 63;
    int ks = (idx >> 9) & 7;
    int f  = idx >> 12;
    int c  = (f << 4) | (l & 15);
    int k  = ks * 32 + ((l >> 4) << 3) + e;
    float s = 0.f;
    #pragma unroll 8
    for (int p = 0; p < 128; ++p) s += qW[k * 128 + p] * kW[c * 128 + p];
    pdst[idx] = (f16)s;
}

__global__ __launch_bounds__(256) void build_pb_kernel(
    const float* __restrict__ qb, const float* __restrict__ kW,
    float* __restrict__ pb)
{
    int c = threadIdx.x;
    float s = 0.f;
    #pragma unroll 8
    for (int p = 0; p < 128; ++p) s += qb[p] * kW[c * 128 + p];
    pb[c] = s;
}

// ------------- shared fused-MLP device body --------------------------------
// Block: 4 waves, 64 rows x 256 cols. A staged (f16 or f32-convert) in 32KB
// LDS XOR-swizzled. GEMM1 -> relu -> H in LDS -> GEMM2 + b2 (+add).
static __device__ __forceinline__ void stage_A(
    char* smem, const f16* A, const float* A32, int brow, int N, int tid)
{
    #pragma unroll
    for (int j = 0; j < 8; ++j) {
        int i = tid + j * 256;
        int row = i >> 5, slot = i & 31;
        int srow = brow + row; srow = srow < N ? srow : N - 1;
        f16x8 v;
        if (A32) {
            const float* s = &A32[(size_t)srow * 256 + slot * 8];
            float4 v0 = *(const float4*)s;
            float4 v1 = *(const float4*)(s + 4);
            v = f16x8{(f16)v0.x, (f16)v0.y, (f16)v0.z, (f16)v0.w,
                      (f16)v1.x, (f16)v1.y, (f16)v1.z, (f16)v1.w};
        } else {
            v = *(const f16x8*)&A[(size_t)srow * 256 + slot * 8];
        }
        int db = (row * 512 + slot * 16) ^ ((row & 7) << 4);
        *(f16x8*)(smem + db) = v;
    }
}

static __device__ __forceinline__ void gemm_from_lds(
    const char* smem, const f16* W, f32x4 (&acc)[4][4],
    int wave, int lane, int lrow, int kg)
{
    #pragma unroll
    for (int ks = 0; ks < 8; ++ks) {
        f16x8 ah[4], bh[4];
        #pragma unroll
        for (int m = 0; m < 4; ++m) {
            int ab = ((m * 16 + lrow) * 512 + (ks * 4 + kg) * 16) ^ ((lrow & 7) << 4);
            ah[m] = *(const f16x8*)(smem + ab);
        }
        #pragma unroll
        for (int n = 0; n < 4; ++n)
            bh[n] = *(const f16x8*)&W[(size_t)(((wave * 4 + n) * 8 + ks) << 9) + (lane << 3)];
        #pragma unroll
        for (int m = 0; m < 4; ++m)
            #pragma unroll
            for (int n = 0; n < 4; ++n)
                acc[m][n] = __builtin_amdgcn_mfma_f32_16x16x32_f16(
                                ah[m], bh[n], acc[m][n], 0, 0, 0);
    }
}

static __device__ __forceinline__ void fused_mlp_body(
    char* smem, const f16* A, const float* A32,
    const f16* W1, const float* b1, const f16* W2, const float* b2,
    const f16* Ad, f16* Ch, float* Cf, int N, int brow)
{
    const int tid  = threadIdx.x;
    const int wave = tid >> 6, lane = tid & 63;
    const int lrow = lane & 15, kg = lane >> 4;
    const int wc   = wave * 64;

    stage_A(smem, A, A32, brow, N, tid);
    __syncthreads();

    f32x4 acc[4][4] = {};
    gemm_from_lds(smem, W1, acc, wave, lane, lrow, kg);

    __syncthreads();
    #pragma unroll
    for (int n = 0; n < 4; ++n) {
        int c = wc + n * 16 + lrow;
        float bv = b1[c];
        #pragma unroll
        for (int m = 0; m < 4; ++m)
            #pragma unroll
            for (int j = 0; j < 4; ++j) {
                int rl = m * 16 + kg * 4 + j;
                float v = fmaxf(acc[m][n][j] + bv, 0.f);
                int hb = (rl * 512 + c * 2) ^ ((rl & 7) << 4);
                *(f16*)(smem + hb) = (f16)v;
            }
    }
    __syncthreads();

    #pragma unroll
    for (int m = 0; m < 4; ++m)
        #pragma unroll
        for (int n = 0; n < 4; ++n)
            acc[m][n] = f32x4{0.f, 0.f, 0.f, 0.f};
    gemm_from_lds(smem, W2, acc, wave, lane, lrow, kg);

    #pragma unroll
    for (int n = 0; n < 4; ++n) {
        int c = wc + n * 16 + lrow;
        float bv = b2[c];
        #pragma unroll
        for (int m = 0; m < 4; ++m)
            #pragma unroll
            for (int j = 0; j < 4; ++j) {
                int r = brow + m * 16 + kg * 4 + j;
                if (r >= N) continue;
                size_t o = (size_t)r * 256 + c;
                float v = acc[m][n][j] + bv;
                if (Ad) v += (float)Ad[o];
                if (Cf) Cf[o] = v;
                else    Ch[o] = (f16)v;
            }
    }
}

// single GEMM (ft): A f32-converted, out f16
__global__ __launch_bounds__(256) void gemm1_kernel(
    const float* __restrict__ A32, const f16* __restrict__ W1,
    const float* __restrict__ b1, f16* __restrict__ Ch, int N)
{
    __shared__ char smem[32768];
    const int tid  = threadIdx.x;
    const int wave = tid >> 6, lane = tid & 63;
    const int lrow = lane & 15, kg = lane >> 4;
    const int wc   = wave * 64;
    const int brow = blockIdx.x * 64;

    stage_A(smem, nullptr, A32, brow, N, tid);
    __syncthreads();
    f32x4 acc[4][4] = {};
    gemm_from_lds(smem, W1, acc, wave, lane, lrow, kg);

    #pragma unroll
    for (int n = 0; n < 4; ++n) {
        int c = wc + n * 16 + lrow;
        float bv = b1[c];
        #pragma unroll
        for (int m = 0; m < 4; ++m)
            #pragma unroll
            for (int j = 0; j < 4; ++j) {
                int r = brow + m * 16 + kg * 4 + j;
                if (r >= N) continue;
                acc[m][n][j] += bv;
                Ch[(size_t)r * 256 + c] = (f16)acc[m][n][j];
            }
    }
}

// em MLP (A f32) / final MLP (A f16, out f32)
__global__ __launch_bounds__(256) void mlp_kernel(
    const f16* __restrict__ A, const float* __restrict__ A32,
    const f16* __restrict__ W1, const float* __restrict__ b1,
    const f16* __restrict__ W2, const float* __restrict__ b2,
    const f16* __restrict__ Ad, f16* __restrict__ Ch, float* __restrict__ Cf,
    int N)
{
    __shared__ char smem[32768];
    fused_mlp_body(smem, A, A32, W1, b1, W2, b2, Ad, Ch, Cf, N, blockIdx.x * 64);
}

// 4 residual MLPs (fo/so/to/qo) in one dispatch
struct Mlp4 {
    const f16* a[4]; const f16* ad[4];
    const f16* w1[4]; const f16* w2[4];
    const float* b1[4]; const float* b2[4];
    f16* out[4];
};
__global__ __launch_bounds__(256) void mlp4_kernel(Mlp4 p, int N) {
    __shared__ char smem[32768];
    int y = blockIdx.y;
    fused_mlp_body(smem, p.a[y], nullptr, p.w1[y], p.b1[y], p.w2[y], p.b2[y],
                   p.ad[y], p.out[y], nullptr, N, blockIdx.x * 64);
}

// ------------- merged scores + softmax + combine ---------------------------
__global__ __launch_bounds__(256) void score_combine_kernel(
    const f16* __restrict__ F, const f16* __restrict__ P,
    const float* __restrict__ pb,
    const f16* __restrict__ F1, const f16* __restrict__ F2,
    const f16* __restrict__ F3, const f16* __restrict__ F4,
    f16* __restrict__ O, int N)
{
    __shared__ char smem[32768];
    __shared__ float sred[4][64][5];
    __shared__ float w5[64][5];

    const int tid  = threadIdx.x;
    const int wave = tid >> 6, lane = tid & 63;
    const int lrow = lane & 15, kg = lane >> 4;
    const int wc   = wave * 64;
    const int brow = blockIdx.x * 64;

    stage_A(smem, F, nullptr, brow, N, tid);
    __syncthreads();

    f32x4 acc[4][4] = {};
    gemm_from_lds(smem, P, acc, wave, lane, lrow, kg);

    #pragma unroll
    for (int m = 0; m < 4; ++m) {
        #pragma unroll
        for (int j = 0; j < 4; ++j) {
            int rl = m * 16 + kg * 4 + j;
            int r  = brow + rl;
            float p0 = 0.f, p1 = 0.f, p2 = 0.f, p3 = 0.f, p4 = 0.f;
            if (r < N) {
                #pragma unroll
                for (int n = 0; n < 4; ++n) {
                    int c = wc + n * 16 + lrow;
                    float v = acc[m][n][j] + pb[c];
                    int ab = (rl * 512 + c * 2) ^ ((rl & 7) << 4);
                    float f0 = (float)*(const f16*)(smem + ab);
                    size_t fo = (size_t)r * 256 + c;
                    p0 += v * f0;
                    p1 += v * (float)F1[fo];
                    p2 += v * (float)F2[fo];
                    p3 += v * (float)F3[fo];
                    p4 += v * (float)F4[fo];
                }
            }
            #pragma unroll
            for (int d = 1; d < 16; d <<= 1) {
                p0 += __shfl_xor(p0, d, 64);
                p1 += __shfl_xor(p1, d, 64);
                p2 += __shfl_xor(p2, d, 64);
                p3 += __shfl_xor(p3, d, 64);
                p4 += __shfl_xor(p4, d, 64);
            }
            if (lrow == 0) {
                sred[wave][rl][0] = p0; sred[wave][rl][1] = p1;
                sred[wave][rl][2] = p2; sred[wave][rl][3] = p3;
                sred[wave][rl][4] = p4;
            }
        }
    }
    __syncthreads();

    if (tid < 64) {
        float s[5];
        #pragma unroll
        for (int k = 0; k < 5; ++k)
            s[k] = sred[0][tid][k] + sred[1][tid][k] + sred[2][tid][k] + sred[3][tid][k];
        float mx = fmaxf(fmaxf(fmaxf(s[0], s[1]), fmaxf(s[2], s[3])), s[4]);
        float sum = 0.f;
        #pragma unroll
        for (int k = 0; k < 5; ++k) { s[k] = expf(s[k] - mx); sum += s[k]; }
        float inv = 1.f / sum;
        #pragma unroll
        for (int k = 0; k < 5; ++k) w5[tid][k] = s[k] * inv;
    }
    __syncthreads();

    #pragma unroll
    for (int m = 0; m < 4; ++m) {
        #pragma unroll
        for (int j = 0; j < 4; ++j) {
            int rl = m * 16 + kg * 4 + j;
            int r  = brow + rl;
            if (r >= N) continue;
            float w0 = w5[rl][0], w1 = w5[rl][1], w2 = w5[rl][2],
                  w3 = w5[rl][3], w4 = w5[rl][4];
            #pragma unroll
            for (int n = 0; n < 4; ++n) {
                int c = wc + n * 16 + lrow;
                int ab = (rl * 512 + c * 2) ^ ((rl & 7) << 4);
                float f0 = (float)*(const f16*)(smem + ab);
                size_t fo = (size_t)r * 256 + c;
                float res = w0 * f0
                          + w1 * (float)F1[fo]
                          + w2 * (float)F2[fo]
                          + w3 * (float)F3[fo]
                          + w4 * (float)F4[fo];
                O[fo] = (f16)res;
            }
        }
    }
}

// ------------- merged CSR build (packed int2 edges) ------------------------
struct CsrSrc { const int* rows[4]; const int* cols[4]; const float* vals[4]; int E[4]; };

__global__ __launch_bounds__(256) void count4_kernel(CsrSrc s, int* __restrict__ cnt, int NPo) {
    int a = blockIdx.y;
    int e = blockIdx.x * 256 + threadIdx.x;
    if (e < s.E[a]) atomicAdd(&cnt[(size_t)a * NPo + s.rows[a][e]], 1);
}

__global__ __launch_bounds__(1024) void scan4_kernel(
    const int* __restrict__ cnt0, int* __restrict__ off0, int N, int NPo)
{
    const int* cnt = cnt0 + (size_t)blockIdx.x * NPo;
    int* off = off0 + (size_t)blockIdx.x * NPo;
    __shared__ int part[1024];
    const int t = threadIdx.x;
    const int chunk = (N + 1023) / 1024;
    const int lo = t * chunk;
    const int hi = min(lo + chunk, N);
    int s = 0;
    for (int i = lo; i < hi; ++i) s += cnt[i];
    part[t] = s;
    __syncthreads();
    for (int d = 1; d < 1024; d <<= 1) {
        int u = (t >= d) ? part[t - d] : 0;
        __syncthreads();
        part[t] += u;
        __syncthreads();
    }
    int running = part[t] - s;
    for (int i = lo; i < hi; ++i) { off[i] = running; running += cnt[i]; }
    if (t == 1023) off[N] = part[1023];
}

__global__ __launch_bounds__(256) void scatter4_kernel(
    CsrSrc s, const int* __restrict__ off, int* __restrict__ cur,
    int2* __restrict__ se, int NPo, int Emax)
{
    int a = blockIdx.y;
    int e = blockIdx.x * 256 + threadIdx.x;
    if (e >= s.E[a]) return;
    int r = s.rows[a][e];
    int p = off[(size_t)a * NPo + r] + atomicAdd(&cur[(size_t)a * NPo + r], 1);
    se[(size_t)a * Emax + p] = make_int2(s.cols[a][e],
                                         __float_as_int(s.vals[a][e]));
}

// ------------- all-4 SpMM in one dispatch ----------------------------------
struct Spmm4 {
    const int* off; const int2* se; int NPo; int Emax;
    const f16* F; const f16* ef;
    f16* agg1; f16* aggef; f16* agg2; f16* agg3; f16* agg4;
};
__global__ __launch_bounds__(256) void spmm4_kernel(Spmm4 s, int N) {
    int a = blockIdx.y;
    int r = blockIdx.x * 4 + (threadIdx.x >> 6);
    if (r >= N) return;
    int lane = threadIdx.x & 63;
    const int* off = s.off + (size_t)a * s.NPo;
    const int2* se = s.se + (size_t)a * s.Emax;
    int e0 = off[r], e1 = off[r + 1];
    size_t yo = (size_t)r * DO + lane * 4;

    if (a == 0) {   // dual: agg1 = A1@F, aggef = A1@ef
        float a0 = 0.f, a1 = 0.f, a2 = 0.f, a3 = 0.f;
        float b0 = 0.f, b1 = 0.f, b2 = 0.f, b3 = 0.f;
        for (int e = e0; e < e1; ++e) {
            int2 ev = se[e];
            int c = ev.x; float v = __int_as_float(ev.y);
            size_t xo = (size_t)c * DO + lane * 4;
            f16x4 x1 = *(const f16x4*)&s.F[xo];
            f16x4 x2 = *(const f16x4*)&s.ef[xo];
            a0 = fmaf(v, (float)x1[0], a0); a1 = fmaf(v, (float)x1[1], a1);
            a2 = fmaf(v, (float)x1[2], a2); a3 = fmaf(v, (float)x1[3], a3);
            b0 = fmaf(v, (float)x2[0], b0); b1 = fmaf(v, (float)x2[1], b1);
            b2 = fmaf(v, (float)x2[2], b2); b3 = fmaf(v, (float)x2[3], b3);
        }
        f16x4 o1 = {(f16)a0, (f16)a1, (f16)a2, (f16)a3};
        f16x4 o2 = {(f16)b0, (f16)b1, (f16)b2, (f16)b3};
        *(f16x4*)&s.agg1[yo]  = o1;
        *(f16x4*)&s.aggef[yo] = o2;
    } else {
        f16* Y = (a == 1) ? s.agg2 : (a == 2) ? s.agg3 : s.agg4;
        float a0 = 0.f, a1 = 0.f, a2 = 0.f, a3 = 0.f;
        for (int e = e0; e < e1; ++e) {
            int2 ev = se[e];
            int c = ev.x; float v = __int_as_float(ev.y);
            f16x4 x = *(const f16x4*)&s.F[(size_t)c * DO + lane * 4];
            a0 = fmaf(v, (float)x[0], a0); a1 = fmaf(v, (float)x[1], a1);
            a2 = fmaf(v, (float)x[2], a2); a3 = fmaf(v, (float)x[3], a3);
        }
        f16x4 o = {(f16)a0, (f16)a1, (f16)a2, (f16)a3};
        *(f16x4*)&Y[yo] = o;
    }
}

extern "C" void kernel_launch(void* const* d_in, const int* in_sizes, int n_in,
                              void* d_out, int out_size, void* d_ws, size_t ws_size,
                              hipStream_t stream)
{
    const float* features      = (const float*)d_in[0];
    const float* edge_features = (const float*)d_in[1];
    CsrSrc cs;
    for (int i = 0; i < 4; ++i) {
        const int* idx = (const int*)d_in[2 + 2 * i];
        cs.E[i]    = in_sizes[3 + 2 * i];
        cs.rows[i] = idx;
        cs.cols[i] = idx + cs.E[i];
        cs.vals[i] = (const float*)d_in[3 + 2 * i];
    }
    const int Emax = max(max(cs.E[0], cs.E[1]), max(cs.E[2], cs.E[3]));

    const float* ft_W = (const float*)d_in[10]; const float* ft_b = (const float*)d_in[11];
    const float* fo_W1 = (const float*)d_in[12]; const float* fo_b1 = (const float*)d_in[13];
    const float* fo_W2 = (const float*)d_in[14]; const float* fo_b2 = (const float*)d_in[15];
    const float* em_W1 = (const float*)d_in[16]; const float* em_b1 = (const float*)d_in[17];
    const float* em_W2 = (const float*)d_in[18]; const float* em_b2 = (const float*)d_in[19];
    const float* so_W1 = (const float*)d_in[20]; const float* so_b1 = (const float*)d_in[21];
    const float* so_W2 = (const float*)d_in[22]; const float* so_b2 = (const float*)d_in[23];
    const float* to_W1 = (const float*)d_in[24]; const float* to_b1 = (const float*)d_in[25];
    const float* to_W2 = (const float*)d_in[26]; const float* to_b2 = (const float*)d_in[27];
    const float* qo_W1 = (const float*)d_in[28]; const float* qo_b1 = (const float*)d_in[29];
    const float* qo_W2 = (const float*)d_in[30]; const float* qo_b2 = (const float*)d_in[31];
    const float* m_W1  = (const float*)d_in[32]; const float* m_b1  = (const float*)d_in[33];
    const float* m_W2  = (const float*)d_in[34]; const float* m_b2  = (const float*)d_in[35];
    const float* q_W   = (const float*)d_in[36]; const float* q_b   = (const float*)d_in[37];
    const float* k_W   = (const float*)d_in[38]; const float* k_b   = (const float*)d_in[39];
    (void)k_b;   // q.k_b constant across the 5 scores -> softmax-invariant

    const int N = in_sizes[0] / 256;
    const size_t NS = (size_t)N * DO;

    // ---- workspace (~192MB): CSR(4, packed) + 6 fp16 slots + packed WT ----
    char* base = (char*)d_ws;
    size_t o = 0;
    auto take = [&](size_t bytes) { char* p = base + o; o += (bytes + 63) & ~(size_t)63; return p; };
    const int NPo = (N + 64) & ~63;
    int*  cnt = (int*)take((size_t)4 * NPo * 4);
    int*  cur = (int*)take((size_t)4 * NPo * 4);
    int*  off = (int*)take((size_t)4 * NPo * 4);
    int2* se  = (int2*)take((size_t)4 * Emax * 8);
    f16* B1 = (f16*)take(NS * 2);      // agg1 -> fo -> combined
    f16* B2 = (f16*)take(NS * 2);      // aggef
    f16* B3 = (f16*)take(NS * 2);      // ef
    f16* B4 = (f16*)take(NS * 2);      // F
    f16* B5 = (f16*)take(NS * 2);      // agg2 -> so
    f16* B6 = (f16*)take(NS * 2);      // agg3 -> to
    const size_t WSQ = 65536;
    f16* WT = (f16*)take(14 * WSQ * 2);    // 13 weights + P (slot 13), packed
    float* pb = (float*)take(256 * 4);
    if (o > ws_size) return;           // graceful guard

    f16* F  = B4;
    f16* OT = (f16*)d_out;             // agg4 -> qo (first NS*2 bytes of d_out)

    f16* w[14];
    for (int i = 0; i < 14; ++i) w[i] = WT + (size_t)i * WSQ;

    dim3 blk(256);
    {   // weights: transpose + fp16 + pack
        WPack p;
        const float* src[13] = {ft_W, fo_W1, fo_W2, em_W1, em_W2, so_W1, so_W2,
                                to_W1, to_W2, qo_W1, qo_W2, m_W1, m_W2};
        for (int i = 0; i < 13; ++i) { p.w[i].src = src[i]; p.w[i].dst = w[i]; }
        hipLaunchKernelGGL(transpose_w_kernel, dim3(256, 13), blk, 0, stream, p);
    }
    hipLaunchKernelGGL(build_p_kernel, dim3(256), blk, 0, stream, q_W, k_W, w[13]);
    hipLaunchKernelGGL(build_pb_kernel, dim3(1), blk, 0, stream, q_b, k_W, pb);
    {   // CSR x4 (3 dispatches, packed int2)
        hipMemsetAsync(cnt, 0, (size_t)4 * NPo * 4, stream);
        hipMemsetAsync(cur, 0, (size_t)4 * NPo * 4, stream);
        dim3 egrd((Emax + 255) / 256, 4);
        hipLaunchKernelGGL(count4_kernel, egrd, blk, 0, stream, cs, cnt, NPo);
        hipLaunchKernelGGL(scan4_kernel, dim3(4), dim3(1024), 0, stream, cnt, off, N, NPo);
        hipLaunchKernelGGL(scatter4_kernel, egrd, blk, 0, stream, cs, off, cur, se, NPo, Emax);
    }

    dim3 ggrd((N + 63) / 64);
    dim3 rgrd((N + 3) / 4);

    // 1. F = features @ ft_W + ft_b  (f32 input converted in staging)
    hipLaunchKernelGGL(gemm1_kernel, ggrd, blk, 0, stream, features, w[0], ft_b, F, N);
    // 2. ef = MLP2(edge_features, em) (f32 input)
    hipLaunchKernelGGL(mlp_kernel, ggrd, blk, 0, stream,
                       nullptr, edge_features, w[3], em_b1, w[4], em_b2,
                       nullptr, B3, nullptr, N);
    // 3. all 4 spmms: agg1->B1, aggef->B2, agg2->B5, agg3->B6, agg4->OT
    {
        Spmm4 sp;
        sp.off = off; sp.se = se; sp.NPo = NPo; sp.Emax = Emax;
        sp.F = F; sp.ef = B3;
        sp.agg1 = B1; sp.aggef = B2; sp.agg2 = B5; sp.agg3 = B6; sp.agg4 = OT;
        hipLaunchKernelGGL(spmm4_kernel, dim3((N + 3) / 4, 4), blk, 0, stream, sp, N);
    }
    // 4. fo/so/to/qo MLPs in one dispatch
    {
        Mlp4 p;
        const f16* a[4]  = {B1, B5, B6, OT};
        const f16* ad[4] = {B2, B5, B6, OT};
        f16* out[4]      = {B1, B5, B6, OT};
        int wi1[4] = {1, 5, 7, 9}, wi2[4] = {2, 6, 8, 10};
        const float* bb1[4] = {fo_b1, so_b1, to_b1, qo_b1};
        const float* bb2[4] = {fo_b2, so_b2, to_b2, qo_b2};
        for (int i = 0; i < 4; ++i) {
            p.a[i] = a[i]; p.ad[i] = ad[i]; p.out[i] = out[i];
            p.w1[i] = w[wi1[i]]; p.w2[i] = w[wi2[i]];
            p.b1[i] = bb1[i]; p.b2[i] = bb2[i];
        }
        hipLaunchKernelGGL(mlp4_kernel, dim3((N + 63) / 64, 4), blk, 0, stream, p, N);
    }
    // 5. merged scores + softmax + combine -> B1 (in-place over fo)
    hipLaunchKernelGGL(score_combine_kernel, ggrd, blk, 0, stream,
                       F, w[13], pb, B1, B5, B6, OT, B1, N);
    // 6. out = MLP2(combined, m) -> f32 d_out (qo dead)
    hipLaunchKernelGGL(mlp_kernel, ggrd, blk, 0, stream,
                       B1, nullptr, w[11], m_b1, w[12], m_b2,
                       nullptr, nullptr, (float*)d_out, N);
}

// Round 13
// 1111.630 us; speedup vs baseline: 13.3981x; 1.0738x over previous
//
#include <hip/hip_runtime.h>

// HigherOrderGINLayer — round 13: y-split über-kernels to hide the CSR build
// (count4 ∥ weight-prep; scatter4 ∥ ft/em GEMMs) + 2-way unrolled spmm4.
// Numerics identical to rounds 11/12 (absmax 0.0605). Round-12 profile:
// spmm4 366us (≈gather bound), CSR build ~300us serialized with compute.

#define DO 256

typedef unsigned short u16;
typedef _Float16 f16;
typedef __attribute__((ext_vector_type(8))) _Float16 f16x8;
typedef __attribute__((ext_vector_type(4))) _Float16 f16x4;
typedef __attribute__((ext_vector_type(4))) float f32x4;

// Packed weight layout (per 256x256 weight): idx = ((frag*8+ks)*64+lane)*8+e
//   col c = frag*16+(lane&15), k = ks*32+(lane>>4)*8+e

struct WDesc { const float* src; f16* dst; };
struct WPack { WDesc w[13]; };
struct CsrSrc { const int* rows[4]; const int* cols[4]; const float* vals[4]; int E[4]; };

// ------------- prep: count4 ∥ weight transpose ∥ build_P ∥ build_pb --------
__global__ __launch_bounds__(256) void prep_kernel(
    CsrSrc cs, int* __restrict__ cnt, int NPo, WPack wp,
    const float* __restrict__ qW, const float* __restrict__ kW,
    const float* __restrict__ qb, f16* __restrict__ pdst, float* __restrict__ pb)
{
    int y = blockIdx.y;
    if (y < 4) {                       // count
        int e = blockIdx.x * 256 + threadIdx.x;
        if (e < cs.E[y]) atomicAdd(&cnt[(size_t)y * NPo + cs.rows[y][e]], 1);
        return;
    }
    if (y < 17) {                      // transpose+pack weight y-4
        if (blockIdx.x >= 256) return;
        WDesc d = wp.w[y - 4];
        int idx = blockIdx.x * 256 + threadIdx.x;
        int e  = idx & 7;
        int l  = (idx >> 3) & 63;
        int ks = (idx >> 9) & 7;
        int f  = idx >> 12;
        int c  = (f << 4) | (l & 15);
        int k  = ks * 32 + ((l >> 4) << 3) + e;
        d.dst[idx] = (f16)d.src[k * 256 + c];
        return;
    }
    if (y == 17) {                     // P = qW @ kW^T, packed
        if (blockIdx.x >= 256) return;
        int idx = blockIdx.x * 256 + threadIdx.x;
        int e  = idx & 7;
        int l  = (idx >> 3) & 63;
        int ks = (idx >> 9) & 7;
        int f  = idx >> 12;
        int c  = (f << 4) | (l & 15);
        int k  = ks * 32 + ((l >> 4) << 3) + e;
        float s = 0.f;
        #pragma unroll 8
        for (int p = 0; p < 128; ++p) s += qW[k * 128 + p] * kW[c * 128 + p];
        pdst[idx] = (f16)s;
        return;
    }
    // y == 18: pb
    if (blockIdx.x != 0) return;
    int c = threadIdx.x;
    float s = 0.f;
    #pragma unroll 8
    for (int p = 0; p < 128; ++p) s += qb[p] * kW[c * 128 + p];
    pb[c] = s;
}

__global__ __launch_bounds__(1024) void scan4_kernel(
    const int* __restrict__ cnt0, int* __restrict__ off0, int N, int NPo)
{
    const int* cnt = cnt0 + (size_t)blockIdx.x * NPo;
    int* off = off0 + (size_t)blockIdx.x * NPo;
    __shared__ int part[1024];
    const int t = threadIdx.x;
    const int chunk = (N + 1023) / 1024;
    const int lo = t * chunk;
    const int hi = min(lo + chunk, N);
    int s = 0;
    for (int i = lo; i < hi; ++i) s += cnt[i];
    part[t] = s;
    __syncthreads();
    for (int d = 1; d < 1024; d <<= 1) {
        int u = (t >= d) ? part[t - d] : 0;
        __syncthreads();
        part[t] += u;
        __syncthreads();
    }
    int running = part[t] - s;
    for (int i = lo; i < hi; ++i) { off[i] = running; running += cnt[i]; }
    if (t == 1023) off[N] = part[1023];
}

// ------------- shared GEMM device pieces -----------------------------------
static __device__ __forceinline__ void stage_A(
    char* smem, const f16* A, const float* A32, int brow, int N, int tid)
{
    #pragma unroll
    for (int j = 0; j < 8; ++j) {
        int i = tid + j * 256;
        int row = i >> 5, slot = i & 31;
        int srow = brow + row; srow = srow < N ? srow : N - 1;
        f16x8 v;
        if (A32) {
            const float* s = &A32[(size_t)srow * 256 + slot * 8];
            float4 v0 = *(const float4*)s;
            float4 v1 = *(const float4*)(s + 4);
            v = f16x8{(f16)v0.x, (f16)v0.y, (f16)v0.z, (f16)v0.w,
                      (f16)v1.x, (f16)v1.y, (f16)v1.z, (f16)v1.w};
        } else {
            v = *(const f16x8*)&A[(size_t)srow * 256 + slot * 8];
        }
        int db = (row * 512 + slot * 16) ^ ((row & 7) << 4);
        *(f16x8*)(smem + db) = v;
    }
}

static __device__ __forceinline__ void gemm_from_lds(
    const char* smem, const f16* W, f32x4 (&acc)[4][4],
    int wave, int lane, int lrow, int kg)
{
    #pragma unroll
    for (int ks = 0; ks < 8; ++ks) {
        f16x8 ah[4], bh[4];
        #pragma unroll
        for (int m = 0; m < 4; ++m) {
            int ab = ((m * 16 + lrow) * 512 + (ks * 4 + kg) * 16) ^ ((lrow & 7) << 4);
            ah[m] = *(const f16x8*)(smem + ab);
        }
        #pragma unroll
        for (int n = 0; n < 4; ++n)
            bh[n] = *(const f16x8*)&W[(size_t)(((wave * 4 + n) * 8 + ks) << 9) + (lane << 3)];
        #pragma unroll
        for (int m = 0; m < 4; ++m)
            #pragma unroll
            for (int n = 0; n < 4; ++n)
                acc[m][n] = __builtin_amdgcn_mfma_f32_16x16x32_f16(
                                ah[m], bh[n], acc[m][n], 0, 0, 0);
    }
}

static __device__ __forceinline__ void fused_mlp_body(
    char* smem, const f16* A, const float* A32,
    const f16* W1, const float* b1, const f16* W2, const float* b2,
    const f16* Ad, f16* Ch, float* Cf, int N, int brow)
{
    const int tid  = threadIdx.x;
    const int wave = tid >> 6, lane = tid & 63;
    const int lrow = lane & 15, kg = lane >> 4;
    const int wc   = wave * 64;

    stage_A(smem, A, A32, brow, N, tid);
    __syncthreads();

    f32x4 acc[4][4] = {};
    gemm_from_lds(smem, W1, acc, wave, lane, lrow, kg);

    __syncthreads();
    #pragma unroll
    for (int n = 0; n < 4; ++n) {
        int c = wc + n * 16 + lrow;
        float bv = b1[c];
        #pragma unroll
        for (int m = 0; m < 4; ++m)
            #pragma unroll
            for (int j = 0; j < 4; ++j) {
                int rl = m * 16 + kg * 4 + j;
                float v = fmaxf(acc[m][n][j] + bv, 0.f);
                int hb = (rl * 512 + c * 2) ^ ((rl & 7) << 4);
                *(f16*)(smem + hb) = (f16)v;
            }
    }
    __syncthreads();

    #pragma unroll
    for (int m = 0; m < 4; ++m)
        #pragma unroll
        for (int n = 0; n < 4; ++n)
            acc[m][n] = f32x4{0.f, 0.f, 0.f, 0.f};
    gemm_from_lds(smem, W2, acc, wave, lane, lrow, kg);

    #pragma unroll
    for (int n = 0; n < 4; ++n) {
        int c = wc + n * 16 + lrow;
        float bv = b2[c];
        #pragma unroll
        for (int m = 0; m < 4; ++m)
            #pragma unroll
            for (int j = 0; j < 4; ++j) {
                int r = brow + m * 16 + kg * 4 + j;
                if (r >= N) continue;
                size_t o = (size_t)r * 256 + c;
                float v = acc[m][n][j] + bv;
                if (Ad) v += (float)Ad[o];
                if (Cf) Cf[o] = v;
                else    Ch[o] = (f16)v;
            }
    }
}

static __device__ __forceinline__ void gemm1_body(
    char* smem, const float* A32, const f16* W1, const float* b1,
    f16* Ch, int N, int brow)
{
    const int tid  = threadIdx.x;
    const int wave = tid >> 6, lane = tid & 63;
    const int lrow = lane & 15, kg = lane >> 4;
    const int wc   = wave * 64;

    stage_A(smem, nullptr, A32, brow, N, tid);
    __syncthreads();
    f32x4 acc[4][4] = {};
    gemm_from_lds(smem, W1, acc, wave, lane, lrow, kg);

    #pragma unroll
    for (int n = 0; n < 4; ++n) {
        int c = wc + n * 16 + lrow;
        float bv = b1[c];
        #pragma unroll
        for (int m = 0; m < 4; ++m)
            #pragma unroll
            for (int j = 0; j < 4; ++j) {
                int r = brow + m * 16 + kg * 4 + j;
                if (r >= N) continue;
                Ch[(size_t)r * 256 + c] = (f16)(acc[m][n][j] + bv);
            }
    }
}

// ------------- stage2: scatter4 ∥ ft-GEMM ∥ em-MLP -------------------------
__global__ __launch_bounds__(256) void stage2_kernel(
    CsrSrc cs, const int* __restrict__ off, int* __restrict__ cur,
    int2* __restrict__ se, int NPo, int Emax,
    const float* __restrict__ features, const float* __restrict__ edge_features,
    const f16* __restrict__ w_ft, const float* __restrict__ ft_b,
    const f16* __restrict__ w_em1, const float* __restrict__ em_b1,
    const f16* __restrict__ w_em2, const float* __restrict__ em_b2,
    f16* __restrict__ F, f16* __restrict__ ef, int N)
{
    __shared__ char smem[32768];
    int y = blockIdx.y;
    if (y < 4) {                       // scatter (packed int2)
        int e = blockIdx.x * 256 + threadIdx.x;
        if (e >= cs.E[y]) return;
        int r = cs.rows[y][e];
        int p = off[(size_t)y * NPo + r] + atomicAdd(&cur[(size_t)y * NPo + r], 1);
        se[(size_t)y * Emax + p] = make_int2(cs.cols[y][e],
                                             __float_as_int(cs.vals[y][e]));
        return;
    }
    int gx = blockIdx.x;
    if (gx >= (N + 63) / 64) return;
    if (y == 4)
        gemm1_body(smem, features, w_ft, ft_b, F, N, gx * 64);
    else
        fused_mlp_body(smem, nullptr, edge_features, w_em1, em_b1, w_em2, em_b2,
                       nullptr, ef, nullptr, N, gx * 64);
}

// ------------- all-4 SpMM in one dispatch (2-way unrolled) -----------------
struct Spmm4 {
    const int* off; const int2* se; int NPo; int Emax;
    const f16* F; const f16* ef;
    f16* agg1; f16* aggef; f16* agg2; f16* agg3; f16* agg4;
};
__global__ __launch_bounds__(256) void spmm4_kernel(Spmm4 s, int N) {
    int a = blockIdx.y;
    int r = blockIdx.x * 4 + (threadIdx.x >> 6);
    if (r >= N) return;
    int lane = threadIdx.x & 63;
    const int* off = s.off + (size_t)a * s.NPo;
    const int2* se = s.se + (size_t)a * s.Emax;
    int e0 = off[r], e1 = off[r + 1];
    size_t yo = (size_t)r * DO + lane * 4;

    if (a == 0) {   // dual: agg1 = A1@F, aggef = A1@ef
        float a0 = 0.f, a1 = 0.f, a2 = 0.f, a3 = 0.f;
        float b0 = 0.f, b1 = 0.f, b2 = 0.f, b3 = 0.f;
        for (int e = e0; e < e1; ++e) {
            int2 ev = se[e];
            int c = ev.x; float v = __int_as_float(ev.y);
            size_t xo = (size_t)c * DO + lane * 4;
            f16x4 x1 = *(const f16x4*)&s.F[xo];
            f16x4 x2 = *(const f16x4*)&s.ef[xo];
            a0 = fmaf(v, (float)x1[0], a0); a1 = fmaf(v, (float)x1[1], a1);
            a2 = fmaf(v, (float)x1[2], a2); a3 = fmaf(v, (float)x1[3], a3);
            b0 = fmaf(v, (float)x2[0], b0); b1 = fmaf(v, (float)x2[1], b1);
            b2 = fmaf(v, (float)x2[2], b2); b3 = fmaf(v, (float)x2[3], b3);
        }
        f16x4 o1 = {(f16)a0, (f16)a1, (f16)a2, (f16)a3};
        f16x4 o2 = {(f16)b0, (f16)b1, (f16)b2, (f16)b3};
        *(f16x4*)&s.agg1[yo]  = o1;
        *(f16x4*)&s.aggef[yo] = o2;
    } else {
        f16* Y = (a == 1) ? s.agg2 : (a == 2) ? s.agg3 : s.agg4;
        float a0 = 0.f, a1 = 0.f, a2 = 0.f, a3 = 0.f;
        int e = e0;
        for (; e + 1 < e1; e += 2) {   // 2 outstanding gathers
            int2 ev0 = se[e], ev1 = se[e + 1];
            float v0 = __int_as_float(ev0.y), v1 = __int_as_float(ev1.y);
            f16x4 x0 = *(const f16x4*)&s.F[(size_t)ev0.x * DO + lane * 4];
            f16x4 x1 = *(const f16x4*)&s.F[(size_t)ev1.x * DO + lane * 4];
            a0 = fmaf(v0, (float)x0[0], a0); a1 = fmaf(v0, (float)x0[1], a1);
            a2 = fmaf(v0, (float)x0[2], a2); a3 = fmaf(v0, (float)x0[3], a3);
            a0 = fmaf(v1, (float)x1[0], a0); a1 = fmaf(v1, (float)x1[1], a1);
            a2 = fmaf(v1, (float)x1[2], a2); a3 = fmaf(v1, (float)x1[3], a3);
        }
        if (e < e1) {
            int2 ev = se[e];
            float v = __int_as_float(ev.y);
            f16x4 x = *(const f16x4*)&s.F[(size_t)ev.x * DO + lane * 4];
            a0 = fmaf(v, (float)x[0], a0); a1 = fmaf(v, (float)x[1], a1);
            a2 = fmaf(v, (float)x[2], a2); a3 = fmaf(v, (float)x[3], a3);
        }
        f16x4 o = {(f16)a0, (f16)a1, (f16)a2, (f16)a3};
        *(f16x4*)&Y[yo] = o;
    }
}

// ------------- 4 residual MLPs in one dispatch -----------------------------
struct Mlp4 {
    const f16* a[4]; const f16* ad[4];
    const f16* w1[4]; const f16* w2[4];
    const float* b1[4]; const float* b2[4];
    f16* out[4];
};
__global__ __launch_bounds__(256) void mlp4_kernel(Mlp4 p, int N) {
    __shared__ char smem[32768];
    int y = blockIdx.y;
    fused_mlp_body(smem, p.a[y], nullptr, p.w1[y], p.b1[y], p.w2[y], p.b2[y],
                   p.ad[y], p.out[y], nullptr, N, blockIdx.x * 64);
}

// final MLP (A f16, out f32)
__global__ __launch_bounds__(256) void mlp_kernel(
    const f16* __restrict__ A,
    const f16* __restrict__ W1, const float* __restrict__ b1,
    const f16* __restrict__ W2, const float* __restrict__ b2,
    float* __restrict__ Cf, int N)
{
    __shared__ char smem[32768];
    fused_mlp_body(smem, A, nullptr, W1, b1, W2, b2, nullptr, nullptr, Cf, N,
                   blockIdx.x * 64);
}

// ------------- merged scores + softmax + combine ---------------------------
__global__ __launch_bounds__(256) void score_combine_kernel(
    const f16* __restrict__ F, const f16* __restrict__ P,
    const float* __restrict__ pb,
    const f16* __restrict__ F1, const f16* __restrict__ F2,
    const f16* __restrict__ F3, const f16* __restrict__ F4,
    f16* __restrict__ O, int N)
{
    __shared__ char smem[32768];
    __shared__ float sred[4][64][5];
    __shared__ float w5[64][5];

    const int tid  = threadIdx.x;
    const int wave = tid >> 6, lane = tid & 63;
    const int lrow = lane & 15, kg = lane >> 4;
    const int wc   = wave * 64;
    const int brow = blockIdx.x * 64;

    stage_A(smem, F, nullptr, brow, N, tid);
    __syncthreads();

    f32x4 acc[4][4] = {};
    gemm_from_lds(smem, P, acc, wave, lane, lrow, kg);

    #pragma unroll
    for (int m = 0; m < 4; ++m) {
        #pragma unroll
        for (int j = 0; j < 4; ++j) {
            int rl = m * 16 + kg * 4 + j;
            int r  = brow + rl;
            float p0 = 0.f, p1 = 0.f, p2 = 0.f, p3 = 0.f, p4 = 0.f;
            if (r < N) {
                #pragma unroll
                for (int n = 0; n < 4; ++n) {
                    int c = wc + n * 16 + lrow;
                    float v = acc[m][n][j] + pb[c];
                    int ab = (rl * 512 + c * 2) ^ ((rl & 7) << 4);
                    float f0 = (float)*(const f16*)(smem + ab);
                    size_t fo = (size_t)r * 256 + c;
                    p0 += v * f0;
                    p1 += v * (float)F1[fo];
                    p2 += v * (float)F2[fo];
                    p3 += v * (float)F3[fo];
                    p4 += v * (float)F4[fo];
                }
            }
            #pragma unroll
            for (int d = 1; d < 16; d <<= 1) {
                p0 += __shfl_xor(p0, d, 64);
                p1 += __shfl_xor(p1, d, 64);
                p2 += __shfl_xor(p2, d, 64);
                p3 += __shfl_xor(p3, d, 64);
                p4 += __shfl_xor(p4, d, 64);
            }
            if (lrow == 0) {
                sred[wave][rl][0] = p0; sred[wave][rl][1] = p1;
                sred[wave][rl][2] = p2; sred[wave][rl][3] = p3;
                sred[wave][rl][4] = p4;
            }
        }
    }
    __syncthreads();

    if (tid < 64) {
        float s[5];
        #pragma unroll
        for (int k = 0; k < 5; ++k)
            s[k] = sred[0][tid][k] + sred[1][tid][k] + sred[2][tid][k] + sred[3][tid][k];
        float mx = fmaxf(fmaxf(fmaxf(s[0], s[1]), fmaxf(s[2], s[3])), s[4]);
        float sum = 0.f;
        #pragma unroll
        for (int k = 0; k < 5; ++k) { s[k] = expf(s[k] - mx); sum += s[k]; }
        float inv = 1.f / sum;
        #pragma unroll
        for (int k = 0; k < 5; ++k) w5[tid][k] = s[k] * inv;
    }
    __syncthreads();

    #pragma unroll
    for (int m = 0; m < 4; ++m) {
        #pragma unroll
        for (int j = 0; j < 4; ++j) {
            int rl = m * 16 + kg * 4 + j;
            int r  = brow + rl;
            if (r >= N) continue;
            float w0 = w5[rl][0], w1 = w5[rl][1], w2 = w5[rl][2],
                  w3 = w5[rl][3], w4 = w5[rl][4];
            #pragma unroll
            for (int n = 0; n < 4; ++n) {
                int c = wc + n * 16 + lrow;
                int ab = (rl * 512 + c * 2) ^ ((rl & 7) << 4);
                float f0 = (float)*(const f16*)(smem + ab);
                size_t fo = (size_t)r * 256 + c;
                float res = w0 * f0
                          + w1 * (float)F1[fo]
                          + w2 * (float)F2[fo]
                          + w3 * (float)F3[fo]
                          + w4 * (float)F4[fo];
                O[fo] = (f16)res;
            }
        }
    }
}

extern "C" void kernel_launch(void* const* d_in, const int* in_sizes, int n_in,
                              void* d_out, int out_size, void* d_ws, size_t ws_size,
                              hipStream_t stream)
{
    const float* features      = (const float*)d_in[0];
    const float* edge_features = (const float*)d_in[1];
    CsrSrc cs;
    for (int i = 0; i < 4; ++i) {
        const int* idx = (const int*)d_in[2 + 2 * i];
        cs.E[i]    = in_sizes[3 + 2 * i];
        cs.rows[i] = idx;
        cs.cols[i] = idx + cs.E[i];
        cs.vals[i] = (const float*)d_in[3 + 2 * i];
    }
    const int Emax = max(max(cs.E[0], cs.E[1]), max(cs.E[2], cs.E[3]));

    const float* ft_W = (const float*)d_in[10]; const float* ft_b = (const float*)d_in[11];
    const float* fo_W1 = (const float*)d_in[12]; const float* fo_b1 = (const float*)d_in[13];
    const float* fo_W2 = (const float*)d_in[14]; const float* fo_b2 = (const float*)d_in[15];
    const float* em_W1 = (const float*)d_in[16]; const float* em_b1 = (const float*)d_in[17];
    const float* em_W2 = (const float*)d_in[18]; const float* em_b2 = (const float*)d_in[19];
    const float* so_W1 = (const float*)d_in[20]; const float* so_b1 = (const float*)d_in[21];
    const float* so_W2 = (const float*)d_in[22]; const float* so_b2 = (const float*)d_in[23];
    const float* to_W1 = (const float*)d_in[24]; const float* to_b1 = (const float*)d_in[25];
    const float* to_W2 = (const float*)d_in[26]; const float* to_b2 = (const float*)d_in[27];
    const float* qo_W1 = (const float*)d_in[28]; const float* qo_b1 = (const float*)d_in[29];
    const float* qo_W2 = (const float*)d_in[30]; const float* qo_b2 = (const float*)d_in[31];
    const float* m_W1  = (const float*)d_in[32]; const float* m_b1  = (const float*)d_in[33];
    const float* m_W2  = (const float*)d_in[34]; const float* m_b2  = (const float*)d_in[35];
    const float* q_W   = (const float*)d_in[36]; const float* q_b   = (const float*)d_in[37];
    const float* k_W   = (const float*)d_in[38]; const float* k_b   = (const float*)d_in[39];
    (void)k_b;   // q.k_b constant across the 5 scores -> softmax-invariant

    const int N = in_sizes[0] / 256;
    const size_t NS = (size_t)N * DO;

    // ---- workspace: CSR(4, packed) + 6 fp16 slots + packed WT -------------
    char* base = (char*)d_ws;
    size_t o = 0;
    auto take = [&](size_t bytes) { char* p = base + o; o += (bytes + 63) & ~(size_t)63; return p; };
    const int NPo = (N + 64) & ~63;
    int*  cnt = (int*)take((size_t)4 * NPo * 4);
    int*  cur = (int*)take((size_t)4 * NPo * 4);   // contiguous with cnt
    int*  off = (int*)take((size_t)4 * NPo * 4);
    int2* se  = (int2*)take((size_t)4 * Emax * 8);
    f16* B1 = (f16*)take(NS * 2);      // agg1 -> fo -> combined
    f16* B2 = (f16*)take(NS * 2);      // aggef
    f16* B3 = (f16*)take(NS * 2);      // ef
    f16* B4 = (f16*)take(NS * 2);      // F
    f16* B5 = (f16*)take(NS * 2);      // agg2 -> so
    f16* B6 = (f16*)take(NS * 2);      // agg3 -> to
    const size_t WSQ = 65536;
    f16* WT = (f16*)take(14 * WSQ * 2);    // 13 weights + P (slot 13), packed
    float* pb = (float*)take(256 * 4);
    if (o > ws_size) return;           // graceful guard

    f16* F  = B4;
    f16* OT = (f16*)d_out;             // agg4 -> qo (first NS*2 bytes of d_out)

    f16* w[14];
    for (int i = 0; i < 14; ++i) w[i] = WT + (size_t)i * WSQ;

    dim3 blk(256);
    const int EG = (Emax + 255) / 256;     // 3125
    const int GG = (N + 63) / 64;          // 782

    // 0. zero cnt+cur (contiguous)
    hipMemsetAsync(cnt, 0, (size_t)8 * NPo * 4, stream);

    // 1. prep: count4 ∥ transpose13 ∥ build_P ∥ build_pb
    {
        WPack wp;
        const float* src[13] = {ft_W, fo_W1, fo_W2, em_W1, em_W2, so_W1, so_W2,
                                to_W1, to_W2, qo_W1, qo_W2, m_W1, m_W2};
        for (int i = 0; i < 13; ++i) { wp.w[i].src = src[i]; wp.w[i].dst = w[i]; }
        hipLaunchKernelGGL(prep_kernel, dim3(EG, 19), blk, 0, stream,
                           cs, cnt, NPo, wp, q_W, k_W, q_b, w[13], pb);
    }
    // 2. scan4
    hipLaunchKernelGGL(scan4_kernel, dim3(4), dim3(1024), 0, stream, cnt, off, N, NPo);
    // 3. stage2: scatter4 ∥ ft-GEMM ∥ em-MLP
    hipLaunchKernelGGL(stage2_kernel, dim3(EG, 6), blk, 0, stream,
                       cs, off, cur, se, NPo, Emax,
                       features, edge_features,
                       w[0], ft_b, w[3], em_b1, w[4], em_b2, F, B3, N);
    // 4. all 4 spmms: agg1->B1, aggef->B2, agg2->B5, agg3->B6, agg4->OT
    {
        Spmm4 sp;
        sp.off = off; sp.se = se; sp.NPo = NPo; sp.Emax = Emax;
        sp.F = F; sp.ef = B3;
        sp.agg1 = B1; sp.aggef = B2; sp.agg2 = B5; sp.agg3 = B6; sp.agg4 = OT;
        hipLaunchKernelGGL(spmm4_kernel, dim3((N + 3) / 4, 4), blk, 0, stream, sp, N);
    }
    // 5. fo/so/to/qo MLPs in one dispatch
    {
        Mlp4 p;
        const f16* a[4]  = {B1, B5, B6, OT};
        const f16* ad[4] = {B2, B5, B6, OT};
        f16* out[4]      = {B1, B5, B6, OT};
        int wi1[4] = {1, 5, 7, 9}, wi2[4] = {2, 6, 8, 10};
        const float* bb1[4] = {fo_b1, so_b1, to_b1, qo_b1};
        const float* bb2[4] = {fo_b2, so_b2, to_b2, qo_b2};
        for (int i = 0; i < 4; ++i) {
            p.a[i] = a[i]; p.ad[i] = ad[i]; p.out[i] = out[i];
            p.w1[i] = w[wi1[i]]; p.w2[i] = w[wi2[i]];
            p.b1[i] = bb1[i]; p.b2[i] = bb2[i];
        }
        hipLaunchKernelGGL(mlp4_kernel, dim3(GG, 4), blk, 0, stream, p, N);
    }
    // 6. merged scores + softmax + combine -> B1 (in-place over fo)
    hipLaunchKernelGGL(score_combine_kernel, dim3(GG), blk, 0, stream,
                       F, w[13], pb, B1, B5, B6, OT, B1, N);
    // 7. out = MLP2(combined, m) -> f32 d_out (qo dead)
    hipLaunchKernelGGL(mlp_kernel, dim3(GG), blk, 0, stream,
                       B1, w[11], m_b1, w[12], m_b2, (float*)d_out, N);
}

// Round 15
// 1075.045 us; speedup vs baseline: 13.8541x; 1.0340x over previous
//
#include <hip/hip_runtime.h>

// HigherOrderGINLayer — round 15: round-14 structure with the aliasing fix.
// Round-14 failed (absmax 17919): the fused score+combine+final-MLP kernel
// read qo from d_out (fp16) while concurrently writing f32 output rows to
// d_out — cross-block read/write race. Fix: qo lives in workspace slot B7;
// d_out is write-only. Numerics identical to rounds 11-13 (absmax 0.0605).

#define DO 256

typedef unsigned short u16;
typedef _Float16 f16;
typedef __attribute__((ext_vector_type(8))) _Float16 f16x8;
typedef __attribute__((ext_vector_type(4))) _Float16 f16x4;
typedef __attribute__((ext_vector_type(4))) float f32x4;

// Packed weight layout (per 256x256 weight): idx = ((frag*8+ks)*64+lane)*8+e
//   col c = frag*16+(lane&15), k = ks*32+(lane>>4)*8+e

struct WDesc { const float* src; f16* dst; };
struct WPack { WDesc w[13]; };
struct CsrSrc { const int* rows[4]; const int* cols[4]; const float* vals[4]; int E[4]; };

// ------------- prep: count4 ∥ weight transpose ∥ build_P ∥ build_pb --------
__global__ __launch_bounds__(256) void prep_kernel(
    CsrSrc cs, int* __restrict__ cnt, int NPo, WPack wp,
    const float* __restrict__ qW, const float* __restrict__ kW,
    const float* __restrict__ qb, f16* __restrict__ pdst, float* __restrict__ pb)
{
    int y = blockIdx.y;
    if (y < 4) {                       // count
        int e = blockIdx.x * 256 + threadIdx.x;
        if (e < cs.E[y]) atomicAdd(&cnt[(size_t)y * NPo + cs.rows[y][e]], 1);
        return;
    }
    if (y < 17) {                      // transpose+pack weight y-4
        if (blockIdx.x >= 256) return;
        WDesc d = wp.w[y - 4];
        int idx = blockIdx.x * 256 + threadIdx.x;
        int e  = idx & 7;
        int l  = (idx >> 3) & 63;
        int ks = (idx >> 9) & 7;
        int f  = idx >> 12;
        int c  = (f << 4) | (l & 15);
        int k  = ks * 32 + ((l >> 4) << 3) + e;
        d.dst[idx] = (f16)d.src[k * 256 + c];
        return;
    }
    if (y == 17) {                     // P = qW @ kW^T, packed
        if (blockIdx.x >= 256) return;
        int idx = blockIdx.x * 256 + threadIdx.x;
        int e  = idx & 7;
        int l  = (idx >> 3) & 63;
        int ks = (idx >> 9) & 7;
        int f  = idx >> 12;
        int c  = (f << 4) | (l & 15);
        int k  = ks * 32 + ((l >> 4) << 3) + e;
        float s = 0.f;
        #pragma unroll 8
        for (int p = 0; p < 128; ++p) s += qW[k * 128 + p] * kW[c * 128 + p];
        pdst[idx] = (f16)s;
        return;
    }
    // y == 18: pb
    if (blockIdx.x != 0) return;
    int c = threadIdx.x;
    float s = 0.f;
    #pragma unroll 8
    for (int p = 0; p < 128; ++p) s += qb[p] * kW[c * 128 + p];
    pb[c] = s;
}

__global__ __launch_bounds__(1024) void scan4_kernel(
    const int* __restrict__ cnt0, int* __restrict__ off0, int N, int NPo)
{
    const int* cnt = cnt0 + (size_t)blockIdx.x * NPo;
    int* off = off0 + (size_t)blockIdx.x * NPo;
    __shared__ int part[1024];
    const int t = threadIdx.x;
    const int chunk = (N + 1023) / 1024;
    const int lo = t * chunk;
    const int hi = min(lo + chunk, N);
    int s = 0;
    for (int i = lo; i < hi; ++i) s += cnt[i];
    part[t] = s;
    __syncthreads();
    for (int d = 1; d < 1024; d <<= 1) {
        int u = (t >= d) ? part[t - d] : 0;
        __syncthreads();
        part[t] += u;
        __syncthreads();
    }
    int running = part[t] - s;
    for (int i = lo; i < hi; ++i) { off[i] = running; running += cnt[i]; }
    if (t == 1023) off[N] = part[1023];
}

// ------------- shared GEMM device pieces -----------------------------------
static __device__ __forceinline__ void stage_A(
    char* smem, const f16* A, const float* A32, int brow, int N, int tid)
{
    #pragma unroll
    for (int j = 0; j < 8; ++j) {
        int i = tid + j * 256;
        int row = i >> 5, slot = i & 31;
        int srow = brow + row; srow = srow < N ? srow : N - 1;
        f16x8 v;
        if (A32) {
            const float* s = &A32[(size_t)srow * 256 + slot * 8];
            float4 v0 = *(const float4*)s;
            float4 v1 = *(const float4*)(s + 4);
            v = f16x8{(f16)v0.x, (f16)v0.y, (f16)v0.z, (f16)v0.w,
                      (f16)v1.x, (f16)v1.y, (f16)v1.z, (f16)v1.w};
        } else {
            v = *(const f16x8*)&A[(size_t)srow * 256 + slot * 8];
        }
        int db = (row * 512 + slot * 16) ^ ((row & 7) << 4);
        *(f16x8*)(smem + db) = v;
    }
}

static __device__ __forceinline__ void gemm_from_lds(
    const char* smem, const f16* W, f32x4 (&acc)[4][4],
    int wave, int lane, int lrow, int kg)
{
    #pragma unroll
    for (int ks = 0; ks < 8; ++ks) {
        f16x8 ah[4], bh[4];
        #pragma unroll
        for (int m = 0; m < 4; ++m) {
            int ab = ((m * 16 + lrow) * 512 + (ks * 4 + kg) * 16) ^ ((lrow & 7) << 4);
            ah[m] = *(const f16x8*)(smem + ab);
        }
        #pragma unroll
        for (int n = 0; n < 4; ++n)
            bh[n] = *(const f16x8*)&W[(size_t)(((wave * 4 + n) * 8 + ks) << 9) + (lane << 3)];
        #pragma unroll
        for (int m = 0; m < 4; ++m)
            #pragma unroll
            for (int n = 0; n < 4; ++n)
                acc[m][n] = __builtin_amdgcn_mfma_f32_16x16x32_f16(
                                ah[m], bh[n], acc[m][n], 0, 0, 0);
    }
}

// GEMM1+relu -> H(LDS, overwrites A region) -> GEMM2; A already staged.
static __device__ __forceinline__ void mlp_from_lds(
    char* smem, const f16* W1, const float* b1, const f16* W2,
    f32x4 (&acc)[4][4], int wave, int lane, int lrow, int kg)
{
    const int wc = wave * 64;
    gemm_from_lds(smem, W1, acc, wave, lane, lrow, kg);
    __syncthreads();
    #pragma unroll
    for (int n = 0; n < 4; ++n) {
        int c = wc + n * 16 + lrow;
        float bv = b1[c];
        #pragma unroll
        for (int m = 0; m < 4; ++m)
            #pragma unroll
            for (int j = 0; j < 4; ++j) {
                int rl = m * 16 + kg * 4 + j;
                float v = fmaxf(acc[m][n][j] + bv, 0.f);
                int hb = (rl * 512 + c * 2) ^ ((rl & 7) << 4);
                *(f16*)(smem + hb) = (f16)v;
            }
    }
    __syncthreads();
    #pragma unroll
    for (int m = 0; m < 4; ++m)
        #pragma unroll
        for (int n = 0; n < 4; ++n)
            acc[m][n] = f32x4{0.f, 0.f, 0.f, 0.f};
    gemm_from_lds(smem, W2, acc, wave, lane, lrow, kg);
}

static __device__ __forceinline__ void fused_mlp_body(
    char* smem, const f16* A, const float* A32,
    const f16* W1, const float* b1, const f16* W2, const float* b2,
    const f16* Ad, f16* Ch, float* Cf, int N, int brow)
{
    const int tid  = threadIdx.x;
    const int wave = tid >> 6, lane = tid & 63;
    const int lrow = lane & 15, kg = lane >> 4;
    const int wc   = wave * 64;

    stage_A(smem, A, A32, brow, N, tid);
    __syncthreads();

    f32x4 acc[4][4] = {};
    mlp_from_lds(smem, W1, b1, W2, acc, wave, lane, lrow, kg);

    #pragma unroll
    for (int n = 0; n < 4; ++n) {
        int c = wc + n * 16 + lrow;
        float bv = b2[c];
        #pragma unroll
        for (int m = 0; m < 4; ++m)
            #pragma unroll
            for (int j = 0; j < 4; ++j) {
                int r = brow + m * 16 + kg * 4 + j;
                if (r >= N) continue;
                size_t o = (size_t)r * 256 + c;
                float v = acc[m][n][j] + bv;
                if (Ad) v += (float)Ad[o];
                if (Cf) Cf[o] = v;
                else    Ch[o] = (f16)v;
            }
    }
}

static __device__ __forceinline__ void gemm1_body(
    char* smem, const float* A32, const f16* W1, const float* b1,
    f16* Ch, int N, int brow)
{
    const int tid  = threadIdx.x;
    const int wave = tid >> 6, lane = tid & 63;
    const int lrow = lane & 15, kg = lane >> 4;
    const int wc   = wave * 64;

    stage_A(smem, nullptr, A32, brow, N, tid);
    __syncthreads();
    f32x4 acc[4][4] = {};
    gemm_from_lds(smem, W1, acc, wave, lane, lrow, kg);

    #pragma unroll
    for (int n = 0; n < 4; ++n) {
        int c = wc + n * 16 + lrow;
        float bv = b1[c];
        #pragma unroll
        for (int m = 0; m < 4; ++m)
            #pragma unroll
            for (int j = 0; j < 4; ++j) {
                int r = brow + m * 16 + kg * 4 + j;
                if (r >= N) continue;
                Ch[(size_t)r * 256 + c] = (f16)(acc[m][n][j] + bv);
            }
    }
}

// ------------- stage2: scatter4 ∥ ft-GEMM ∥ em-MLP -------------------------
__global__ __launch_bounds__(256) void stage2_kernel(
    CsrSrc cs, const int* __restrict__ off, int* __restrict__ cur,
    int2* __restrict__ se, int NPo, int Emax,
    const float* __restrict__ features, const float* __restrict__ edge_features,
    const f16* __restrict__ w_ft, const float* __restrict__ ft_b,
    const f16* __restrict__ w_em1, const float* __restrict__ em_b1,
    const f16* __restrict__ w_em2, const float* __restrict__ em_b2,
    f16* __restrict__ F, f16* __restrict__ ef, int N)
{
    __shared__ char smem[32768];
    int y = blockIdx.y;
    if (y < 4) {                       // scatter (packed int2)
        int e = blockIdx.x * 256 + threadIdx.x;
        if (e >= cs.E[y]) return;
        int r = cs.rows[y][e];
        int p = off[(size_t)y * NPo + r] + atomicAdd(&cur[(size_t)y * NPo + r], 1);
        se[(size_t)y * Emax + p] = make_int2(cs.cols[y][e],
                                             __float_as_int(cs.vals[y][e]));
        return;
    }
    int gx = blockIdx.x;
    if (gx >= (N + 63) / 64) return;
    if (y == 4)
        gemm1_body(smem, features, w_ft, ft_b, F, N, gx * 64);
    else
        fused_mlp_body(smem, nullptr, edge_features, w_em1, em_b1, w_em2, em_b2,
                       nullptr, ef, nullptr, N, gx * 64);
}

// ------------- all 5 SpMM streams in one dispatch (4-way unrolled) ---------
struct Spmm5 {
    const int* off; const int2* se; int NPo; int Emax;
    const f16* F; const f16* ef;
    f16* out[5];   // agg1, aggef, agg2, agg3, agg4
};
__global__ __launch_bounds__(256) void spmm5_kernel(Spmm5 s, int N) {
    int y = blockIdx.y;
    int r = blockIdx.x * 4 + (threadIdx.x >> 6);
    if (r >= N) return;
    int lane = threadIdx.x & 63;
    int a = (y <= 1) ? 0 : y - 1;
    const int* off = s.off + (size_t)a * s.NPo;
    const int2* se = s.se + (size_t)a * s.Emax;
    const f16* X = (y == 1) ? s.ef : s.F;
    f16* Y = s.out[y];
    int e0 = off[r], e1 = off[r + 1];

    float a0 = 0.f, a1 = 0.f, a2 = 0.f, a3 = 0.f;
    int e = e0;
    for (; e + 3 < e1; e += 4) {       // 4 outstanding row gathers
        int2 ev0 = se[e], ev1 = se[e + 1], ev2 = se[e + 2], ev3 = se[e + 3];
        f16x4 x0 = *(const f16x4*)&X[(size_t)ev0.x * DO + lane * 4];
        f16x4 x1 = *(const f16x4*)&X[(size_t)ev1.x * DO + lane * 4];
        f16x4 x2 = *(const f16x4*)&X[(size_t)ev2.x * DO + lane * 4];
        f16x4 x3 = *(const f16x4*)&X[(size_t)ev3.x * DO + lane * 4];
        float v0 = __int_as_float(ev0.y), v1 = __int_as_float(ev1.y);
        float v2 = __int_as_float(ev2.y), v3 = __int_as_float(ev3.y);
        a0 = fmaf(v0, (float)x0[0], a0); a1 = fmaf(v0, (float)x0[1], a1);
        a2 = fmaf(v0, (float)x0[2], a2); a3 = fmaf(v0, (float)x0[3], a3);
        a0 = fmaf(v1, (float)x1[0], a0); a1 = fmaf(v1, (float)x1[1], a1);
        a2 = fmaf(v1, (float)x1[2], a2); a3 = fmaf(v1, (float)x1[3], a3);
        a0 = fmaf(v2, (float)x2[0], a0); a1 = fmaf(v2, (float)x2[1], a1);
        a2 = fmaf(v2, (float)x2[2], a2); a3 = fmaf(v2, (float)x2[3], a3);
        a0 = fmaf(v3, (float)x3[0], a0); a1 = fmaf(v3, (float)x3[1], a1);
        a2 = fmaf(v3, (float)x3[2], a2); a3 = fmaf(v3, (float)x3[3], a3);
    }
    for (; e < e1; ++e) {
        int2 ev = se[e];
        float v = __int_as_float(ev.y);
        f16x4 x = *(const f16x4*)&X[(size_t)ev.x * DO + lane * 4];
        a0 = fmaf(v, (float)x[0], a0); a1 = fmaf(v, (float)x[1], a1);
        a2 = fmaf(v, (float)x[2], a2); a3 = fmaf(v, (float)x[3], a3);
    }
    f16x4 o = {(f16)a0, (f16)a1, (f16)a2, (f16)a3};
    *(f16x4*)&Y[(size_t)r * DO + lane * 4] = o;
}

// ------------- 4 residual MLPs in one dispatch -----------------------------
struct Mlp4 {
    const f16* a[4]; const f16* ad[4];
    const f16* w1[4]; const f16* w2[4];
    const float* b1[4]; const float* b2[4];
    f16* out[4];
};
__global__ __launch_bounds__(256) void mlp4_kernel(Mlp4 p, int N) {
    __shared__ char smem[32768];
    int y = blockIdx.y;
    fused_mlp_body(smem, p.a[y], nullptr, p.w1[y], p.b1[y], p.w2[y], p.b2[y],
                   p.ad[y], p.out[y], nullptr, N, blockIdx.x * 64);
}

// ------------- scores + softmax + combine + final MLP ----------------------
// combined overwrites the F LDS tile in place, then GEMM1(m_W1)+relu -> H ->
// GEMM2(m_W2) -> f32 d_out. d_out is WRITE-ONLY here (qo lives in workspace).
__global__ __launch_bounds__(256) void score_combine_mlp_kernel(
    const f16* __restrict__ F, const f16* __restrict__ P,
    const float* __restrict__ pb,
    const f16* __restrict__ F1, const f16* __restrict__ F2,
    const f16* __restrict__ F3, const f16* __restrict__ F4,
    const f16* __restrict__ mW1, const float* __restrict__ mb1,
    const f16* __restrict__ mW2, const float* __restrict__ mb2,
    float* __restrict__ Out, int N)
{
    __shared__ char smem[32768];
    __shared__ float sred[4][64][5];
    __shared__ float w5[64][5];

    const int tid  = threadIdx.x;
    const int wave = tid >> 6, lane = tid & 63;
    const int lrow = lane & 15, kg = lane >> 4;
    const int wc   = wave * 64;
    const int brow = blockIdx.x * 64;

    stage_A(smem, F, nullptr, brow, N, tid);
    __syncthreads();

    f32x4 acc[4][4] = {};
    gemm_from_lds(smem, P, acc, wave, lane, lrow, kg);

    // ---- dot phase ----
    #pragma unroll
    for (int m = 0; m < 4; ++m) {
        #pragma unroll
        for (int j = 0; j < 4; ++j) {
            int rl = m * 16 + kg * 4 + j;
            int r  = brow + rl;
            float p0 = 0.f, p1 = 0.f, p2 = 0.f, p3 = 0.f, p4 = 0.f;
            if (r < N) {
                #pragma unroll
                for (int n = 0; n < 4; ++n) {
                    int c = wc + n * 16 + lrow;
                    float v = acc[m][n][j] + pb[c];
                    int ab = (rl * 512 + c * 2) ^ ((rl & 7) << 4);
                    float f0 = (float)*(const f16*)(smem + ab);
                    size_t fo = (size_t)r * 256 + c;
                    p0 += v * f0;
                    p1 += v * (float)F1[fo];
                    p2 += v * (float)F2[fo];
                    p3 += v * (float)F3[fo];
                    p4 += v * (float)F4[fo];
                }
            }
            #pragma unroll
            for (int d = 1; d < 16; d <<= 1) {
                p0 += __shfl_xor(p0, d, 64);
                p1 += __shfl_xor(p1, d, 64);
                p2 += __shfl_xor(p2, d, 64);
                p3 += __shfl_xor(p3, d, 64);
                p4 += __shfl_xor(p4, d, 64);
            }
            if (lrow == 0) {
                sred[wave][rl][0] = p0; sred[wave][rl][1] = p1;
                sred[wave][rl][2] = p2; sred[wave][rl][3] = p3;
                sred[wave][rl][4] = p4;
            }
        }
    }
    __syncthreads();

    if (tid < 64) {
        float s[5];
        #pragma unroll
        for (int k = 0; k < 5; ++k)
            s[k] = sred[0][tid][k] + sred[1][tid][k] + sred[2][tid][k] + sred[3][tid][k];
        float mx = fmaxf(fmaxf(fmaxf(s[0], s[1]), fmaxf(s[2], s[3])), s[4]);
        float sum = 0.f;
        #pragma unroll
        for (int k = 0; k < 5; ++k) { s[k] = expf(s[k] - mx); sum += s[k]; }
        float inv = 1.f / sum;
        #pragma unroll
        for (int k = 0; k < 5; ++k) w5[tid][k] = s[k] * inv;
    }
    __syncthreads();

    // ---- combine: write fp16 combined back into the F tile (in place;
    //      each (row,col) element read+written by exactly one thread) ----
    #pragma unroll
    for (int m = 0; m < 4; ++m) {
        #pragma unroll
        for (int j = 0; j < 4; ++j) {
            int rl = m * 16 + kg * 4 + j;
            int r  = brow + rl;
            float w0 = w5[rl][0], w1 = w5[rl][1], w2 = w5[rl][2],
                  w3 = w5[rl][3], w4 = w5[rl][4];
            #pragma unroll
            for (int n = 0; n < 4; ++n) {
                int c = wc + n * 16 + lrow;
                int ab = (rl * 512 + c * 2) ^ ((rl & 7) << 4);
                float f0 = (float)*(const f16*)(smem + ab);
                float res = f0;
                if (r < N) {
                    size_t fo = (size_t)r * 256 + c;
                    res = w0 * f0
                        + w1 * (float)F1[fo]
                        + w2 * (float)F2[fo]
                        + w3 * (float)F3[fo]
                        + w4 * (float)F4[fo];
                }
                *(f16*)(smem + ab) = (f16)res;
            }
        }
    }
    __syncthreads();

    // ---- final MLP from LDS(combined) ----
    #pragma unroll
    for (int m = 0; m < 4; ++m)
        #pragma unroll
        for (int n = 0; n < 4; ++n)
            acc[m][n] = f32x4{0.f, 0.f, 0.f, 0.f};
    mlp_from_lds(smem, mW1, mb1, mW2, acc, wave, lane, lrow, kg);

    #pragma unroll
    for (int n = 0; n < 4; ++n) {
        int c = wc + n * 16 + lrow;
        float bv = mb2[c];
        #pragma unroll
        for (int m = 0; m < 4; ++m)
            #pragma unroll
            for (int j = 0; j < 4; ++j) {
                int r = brow + m * 16 + kg * 4 + j;
                if (r >= N) continue;
                Out[(size_t)r * 256 + c] = acc[m][n][j] + bv;
            }
    }
}

extern "C" void kernel_launch(void* const* d_in, const int* in_sizes, int n_in,
                              void* d_out, int out_size, void* d_ws, size_t ws_size,
                              hipStream_t stream)
{
    const float* features      = (const float*)d_in[0];
    const float* edge_features = (const float*)d_in[1];
    CsrSrc cs;
    for (int i = 0; i < 4; ++i) {
        const int* idx = (const int*)d_in[2 + 2 * i];
        cs.E[i]    = in_sizes[3 + 2 * i];
        cs.rows[i] = idx;
        cs.cols[i] = idx + cs.E[i];
        cs.vals[i] = (const float*)d_in[3 + 2 * i];
    }
    const int Emax = max(max(cs.E[0], cs.E[1]), max(cs.E[2], cs.E[3]));

    const float* ft_W = (const float*)d_in[10]; const float* ft_b = (const float*)d_in[11];
    const float* fo_W1 = (const float*)d_in[12]; const float* fo_b1 = (const float*)d_in[13];
    const float* fo_W2 = (const float*)d_in[14]; const float* fo_b2 = (const float*)d_in[15];
    const float* em_W1 = (const float*)d_in[16]; const float* em_b1 = (const float*)d_in[17];
    const float* em_W2 = (const float*)d_in[18]; const float* em_b2 = (const float*)d_in[19];
    const float* so_W1 = (const float*)d_in[20]; const float* so_b1 = (const float*)d_in[21];
    const float* so_W2 = (const float*)d_in[22]; const float* so_b2 = (const float*)d_in[23];
    const float* to_W1 = (const float*)d_in[24]; const float* to_b1 = (const float*)d_in[25];
    const float* to_W2 = (const float*)d_in[26]; const float* to_b2 = (const float*)d_in[27];
    const float* qo_W1 = (const float*)d_in[28]; const float* qo_b1 = (const float*)d_in[29];
    const float* qo_W2 = (const float*)d_in[30]; const float* qo_b2 = (const float*)d_in[31];
    const float* m_W1  = (const float*)d_in[32]; const float* m_b1  = (const float*)d_in[33];
    const float* m_W2  = (const float*)d_in[34]; const float* m_b2  = (const float*)d_in[35];
    const float* q_W   = (const float*)d_in[36]; const float* q_b   = (const float*)d_in[37];
    const float* k_W   = (const float*)d_in[38]; const float* k_b   = (const float*)d_in[39];
    (void)k_b;   // q.k_b constant across the 5 scores -> softmax-invariant

    const int N = in_sizes[0] / 256;
    const size_t NS = (size_t)N * DO;

    // ---- workspace (~211MB): CSR(4, packed) + 7 fp16 slots + packed WT ----
    char* base = (char*)d_ws;
    size_t o = 0;
    auto take = [&](size_t bytes) { char* p = base + o; o += (bytes + 63) & ~(size_t)63; return p; };
    const int NPo = (N + 64) & ~63;
    int*  cnt = (int*)take((size_t)4 * NPo * 4);
    int*  cur = (int*)take((size_t)4 * NPo * 4);   // contiguous with cnt
    int*  off = (int*)take((size_t)4 * NPo * 4);
    int2* se  = (int2*)take((size_t)4 * Emax * 8);
    f16* B1 = (f16*)take(NS * 2);      // agg1 -> fo
    f16* B2 = (f16*)take(NS * 2);      // aggef
    f16* B3 = (f16*)take(NS * 2);      // ef
    f16* B4 = (f16*)take(NS * 2);      // F
    f16* B5 = (f16*)take(NS * 2);      // agg2 -> so
    f16* B6 = (f16*)take(NS * 2);      // agg3 -> to
    f16* B7 = (f16*)take(NS * 2);      // agg4 -> qo  (NOT d_out — round-14 fix)
    const size_t WSQ = 65536;
    f16* WT = (f16*)take(14 * WSQ * 2);    // 13 weights + P (slot 13), packed
    float* pb = (float*)take(256 * 4);
    if (o > ws_size) return;           // graceful guard

    f16* F = B4;

    f16* w[14];
    for (int i = 0; i < 14; ++i) w[i] = WT + (size_t)i * WSQ;

    dim3 blk(256);
    const int EG = (Emax + 255) / 256;
    const int GG = (N + 63) / 64;

    // 0. zero cnt+cur (contiguous)
    hipMemsetAsync(cnt, 0, (size_t)8 * NPo * 4, stream);

    // 1. prep: count4 ∥ transpose13 ∥ build_P ∥ build_pb
    {
        WPack wp;
        const float* src[13] = {ft_W, fo_W1, fo_W2, em_W1, em_W2, so_W1, so_W2,
                                to_W1, to_W2, qo_W1, qo_W2, m_W1, m_W2};
        for (int i = 0; i < 13; ++i) { wp.w[i].src = src[i]; wp.w[i].dst = w[i]; }
        hipLaunchKernelGGL(prep_kernel, dim3(EG, 19), blk, 0, stream,
                           cs, cnt, NPo, wp, q_W, k_W, q_b, w[13], pb);
    }
    // 2. scan4
    hipLaunchKernelGGL(scan4_kernel, dim3(4), dim3(1024), 0, stream, cnt, off, N, NPo);
    // 3. stage2: scatter4 ∥ ft-GEMM ∥ em-MLP
    hipLaunchKernelGGL(stage2_kernel, dim3(EG, 6), blk, 0, stream,
                       cs, off, cur, se, NPo, Emax,
                       features, edge_features,
                       w[0], ft_b, w[3], em_b1, w[4], em_b2, F, B3, N);
    // 4. all 5 spmm streams: agg1->B1, aggef->B2, agg2->B5, agg3->B6, agg4->B7
    {
        Spmm5 sp;
        sp.off = off; sp.se = se; sp.NPo = NPo; sp.Emax = Emax;
        sp.F = F; sp.ef = B3;
        sp.out[0] = B1; sp.out[1] = B2; sp.out[2] = B5; sp.out[3] = B6; sp.out[4] = B7;
        hipLaunchKernelGGL(spmm5_kernel, dim3((N + 3) / 4, 5), blk, 0, stream, sp, N);
    }
    // 5. fo/so/to/qo MLPs in one dispatch
    {
        Mlp4 p;
        const f16* a[4]  = {B1, B5, B6, B7};
        const f16* ad[4] = {B2, B5, B6, B7};
        f16* out[4]      = {B1, B5, B6, B7};
        int wi1[4] = {1, 5, 7, 9}, wi2[4] = {2, 6, 8, 10};
        const float* bb1[4] = {fo_b1, so_b1, to_b1, qo_b1};
        const float* bb2[4] = {fo_b2, so_b2, to_b2, qo_b2};
        for (int i = 0; i < 4; ++i) {
            p.a[i] = a[i]; p.ad[i] = ad[i]; p.out[i] = out[i];
            p.w1[i] = w[wi1[i]]; p.w2[i] = w[wi2[i]];
            p.b1[i] = bb1[i]; p.b2[i] = bb2[i];
        }
        hipLaunchKernelGGL(mlp4_kernel, dim3(GG, 4), blk, 0, stream, p, N);
    }
    // 6. scores + softmax + combine + final MLP -> f32 d_out (write-only)
    hipLaunchKernelGGL(score_combine_mlp_kernel, dim3(GG), blk, 0, stream,
                       F, w[13], pb, B1, B5, B6, B7,
                       w[11], m_b1, w[12], m_b2, (float*)d_out, N);
}